// Round 1
// baseline (1028.441 us; speedup 1.0000x reference)
//
#include <hip/hip_runtime.h>

// ---------------- problem constants ----------------
constexpr int CB   = 8;      // batch
constexpr int CN   = 1369;   // tokens (37*37)
constexpr int CDIN = 768;
constexpr int CS   = 7;      // slots
constexpr int CD   = 256;
constexpr int CITERS = 3;
constexpr int CRES = 37;
constexpr float CSIGMA = 5.0f;
constexpr int CBS = CB * CS;        // 56
constexpr int CBN = CB * CN;        // 10952 rows for initial mlp
constexpr int CKV = 2 * CD;         // interleaved KX|VX row stride
constexpr float LNEPS = 1e-5f;
constexpr float ATTN_EPS = 1e-8f;

typedef unsigned short u16;
typedef short bs8 __attribute__((ext_vector_type(8)));   // 8 bf16 (bit pattern in shorts)
typedef float f4 __attribute__((ext_vector_type(4)));

// ---------------- helpers ----------------
__device__ __forceinline__ float ag_x(int n) { return -1.f + (float)(n % CRES) * (2.f / 36.f); }
__device__ __forceinline__ float ag_y(int n) { return -1.f + (float)(n / CRES) * (2.f / 36.f); }

__device__ __forceinline__ u16 bf_rne(float f) {
    unsigned u = __float_as_uint(f);
    return (u16)((u + 0x7FFFu + ((u >> 16) & 1u)) >> 16);
}
__device__ __forceinline__ float bf_to_f(u16 h) { return __uint_as_float(((unsigned)h) << 16); }

__device__ __forceinline__ void split2b(float v, u16& h, u16& m) {
    h = bf_rne(v);
    m = bf_rne(v - bf_to_f(h));
}

// async global->LDS, 16B per lane (dest = wave-uniform base + lane*16)
__device__ __forceinline__ void async16(const u16* g, u16* l) {
    __builtin_amdgcn_global_load_lds(
        (const __attribute__((address_space(1))) unsigned int*)g,
        (__attribute__((address_space(3))) unsigned int*)l, 16, 0, 0);
}

// 256-thread block sum
__device__ __forceinline__ float block_reduce_sum(float v, float* sbuf) {
    #pragma unroll
    for (int off = 32; off > 0; off >>= 1) v += __shfl_down(v, off, 64);
    if ((threadIdx.x & 63) == 0) sbuf[threadIdx.x >> 6] = v;
    __syncthreads();
    if (threadIdx.x == 0) sbuf[0] = sbuf[0] + sbuf[1] + sbuf[2] + sbuf[3];
    __syncthreads();
    float r = sbuf[0];
    __syncthreads();
    return r;
}

// ---------------- layernorm -> split-2 bf16 planes ----------------
__global__ __launch_bounds__(256) void ln_planes_kernel(const float* __restrict__ in,
        u16* __restrict__ Yh, u16* __restrict__ Ym,
        const float* __restrict__ g, const float* __restrict__ b, int d) {
    __shared__ float sbuf[8];
    int row = blockIdx.x;
    const float* x = in + (size_t)row * d;
    float s = 0.f;
    for (int i = threadIdx.x; i < d; i += 256) s += x[i];
    float mean = block_reduce_sum(s, sbuf) / d;
    float v = 0.f;
    for (int i = threadIdx.x; i < d; i += 256) { float t = x[i] - mean; v += t * t; }
    float var = block_reduce_sum(v, sbuf) / d;
    float rstd = rsqrtf(var + LNEPS);
    for (int i = threadIdx.x; i < d; i += 256) {
        float y = (x[i] - mean) * rstd * g[i] + b[i];
        u16 h, m; split2b(y, h, m);
        Yh[(size_t)row * d + i] = h;
        Ym[(size_t)row * d + i] = m;
    }
}

// ---------------- transpose fp32 W[K][N] -> 2 bf16 planes Wt[N][K] ----------------
__global__ __launch_bounds__(256) void transpose_split2_kernel(const float* __restrict__ W,
        u16* __restrict__ Th, u16* __restrict__ Tm, int K, int N) {
    __shared__ float tile[32][33];
    int nb = blockIdx.x * 32, kb = blockIdx.y * 32;
    int tx = threadIdx.x & 31, ty = threadIdx.x >> 5;   // ty 0..7
    #pragma unroll
    for (int i = 0; i < 32; i += 8)
        tile[ty + i][tx] = W[(size_t)(kb + ty + i) * N + nb + tx];
    __syncthreads();
    #pragma unroll
    for (int i = 0; i < 32; i += 8) {
        float v = tile[tx][ty + i];
        u16 h, m; split2b(v, h, m);
        size_t idx = (size_t)(nb + ty + i) * K + kb + tx;
        Th[idx] = h; Tm[idx] = m;
    }
}

// ---------------- fp32 transpose W[K][N] -> T[N][K] ----------------
__global__ __launch_bounds__(256) void transpose32_kernel(const float* __restrict__ W,
        float* __restrict__ T, int K, int N) {
    __shared__ float tile[32][33];
    int nb = blockIdx.x * 32, kb = blockIdx.y * 32;
    int tx = threadIdx.x & 31, ty = threadIdx.x >> 5;
    #pragma unroll
    for (int i = 0; i < 32; i += 8)
        tile[ty + i][tx] = W[(size_t)(kb + ty + i) * N + nb + tx];
    __syncthreads();
    #pragma unroll
    for (int i = 0; i < 32; i += 8)
        T[(size_t)(nb + ty + i) * K + kb + tx] = tile[tx][ty + i];
}

// ---------------- P[k][n] = sum_j A[k][j]*B[j][n], A [256][256], B [256][N] ----------------
__global__ __launch_bounds__(256) void wprodN_kernel(const float* __restrict__ A,
        const float* __restrict__ B, float* __restrict__ P, int N) {
    __shared__ float arow[CD];
    int k = blockIdx.x;
    arow[threadIdx.x] = A[k * CD + threadIdx.x];
    __syncthreads();
    int n = blockIdx.y * 256 + threadIdx.x;
    if (n >= N) return;
    float acc = 0.f;
    for (int j = 0; j < CD; j++) acc += arow[j] * B[(size_t)j * N + n];
    P[(size_t)k * N + n] = acc;
}

// G2[g][n] = sum_j g_w[g][j]*f_w1[j][n];  gb1[n] = sum_j g_b[j]*f_w1[j][n] + f_b1[n]
__global__ __launch_bounds__(256) void g2_kernel(const float* __restrict__ g_w,
        const float* __restrict__ g_b, const float* __restrict__ f_w1,
        const float* __restrict__ f_b1, float* __restrict__ G2, float* __restrict__ gb1) {
    int n = threadIdx.x;
    float a0 = 0.f, a1 = 0.f, ab = 0.f;
    for (int j = 0; j < CD; j++) {
        float w = f_w1[j * CD + n];
        a0 += g_w[j] * w;
        a1 += g_w[CD + j] * w;
        ab += g_b[j] * w;
    }
    G2[n] = a0; G2[CD + n] = a1; gb1[n] = ab + f_b1[n];
}

// bg[n] = sum_c f_b2[c]*wih[c][n] + bih[n]   (N=768)
__global__ __launch_bounds__(256) void bg_kernel(const float* __restrict__ f_b2,
        const float* __restrict__ wih, const float* __restrict__ bih,
        float* __restrict__ bg, int N) {
    int n = blockIdx.x * 256 + threadIdx.x;
    if (n >= N) return;
    float s = bih[n];
    for (int c = 0; c < CD; c++) s += f_b2[c] * wih[(size_t)c * N + n];
    bg[n] = s;
}

// wqb[j] = sum_c Wq[j][c] * f_b2[c]
__global__ __launch_bounds__(256) void wqb_kernel(const float* __restrict__ Wq,
        const float* __restrict__ f_b2, float* __restrict__ wqb) {
    int j = threadIdx.x;
    float s = 0.f;
    for (int c = 0; c < CD; c++) s += Wq[j * CD + c] * f_b2[c];
    wqb[j] = s;
}

// ---------------- bf16x3 plane GEMM with global_load_lds staging ----------------
// A planes Ah/Am [M][K], B planes Bh/Bm [N][K]; K%32==0, N%128==0.
// LDS linear [4 planes][128 rows][32 k] u16 (32 KB). XOR chunk swizzle c' = c ^ (r&3):
// applied via inverse-permuted GLOBAL source on the write side (global_load_lds writes
// linearly) + the same XOR on the ds_read side (guideline 21: both-sides-or-neither).
__global__ __launch_bounds__(256)
void hgemm2(const u16* __restrict__ Ah, const u16* __restrict__ Am,
            const u16* __restrict__ Bh, const u16* __restrict__ Bm,
            int M, int N, int K, const float* __restrict__ bias, int relu,
            float* __restrict__ Cf, u16* __restrict__ Ch, u16* __restrict__ Cm) {
    __shared__ u16 smem[4 * 128 * 32];   // 32 KB
    const int tid = threadIdx.x;
    const int m0 = blockIdx.y * 128, n0 = blockIdx.x * 128;
    const int w = tid >> 6, lane = tid & 63;
    const int wm = w & 1, wn = w >> 1;
    const int l15 = lane & 15, l4 = lane >> 4;

    // 8 issues/thread/k-step; issue i covers LDS chunks q = i*256 + tid (16B chunks).
    const u16* srcp[8];
    u16* dstp[8];
    #pragma unroll
    for (int i = 0; i < 8; i++) {
        int q = i * 256 + tid;
        int qq = q & 511;
        int r = qq >> 2;
        int c = (qq & 3) ^ (r & 3);      // inverse swizzle on the source
        int plane = i >> 1;              // 0:Ah 1:Am 2:Bh 3:Bm (compile-time per unrolled i)
        const u16* bp; int row;
        if (plane == 0)      { bp = Ah; row = m0 + r; row = row < M ? row : M - 1; }
        else if (plane == 1) { bp = Am; row = m0 + r; row = row < M ? row : M - 1; }
        else if (plane == 2) { bp = Bh; row = n0 + r; }
        else                 { bp = Bm; row = n0 + r; }
        srcp[i] = bp + (size_t)row * K + c * 8;
        dstp[i] = smem + i * 2048 + w * 512;   // wave-uniform; HW adds lane*16B
    }

    f4 acc[4][4];
    #pragma unroll
    for (int i = 0; i < 4; i++)
        #pragma unroll
        for (int j = 0; j < 4; j++) acc[i][j] = (f4){0.f, 0.f, 0.f, 0.f};

    const int cx8 = (l4 ^ (l15 & 3)) * 8;     // swizzled k-chunk for fragment reads

    for (int k0 = 0; k0 < K; k0 += 32) {
        #pragma unroll
        for (int i = 0; i < 8; i++)
            async16(srcp[i] + k0, dstp[i]);
        __syncthreads();                       // compiler drains vmcnt before s_barrier
        bs8 ah[4], am[4], bh[4], bm[4];
        #pragma unroll
        for (int f = 0; f < 4; f++) {
            int oa = (wm * 64 + f * 16 + l15) * 32 + cx8;
            ah[f] = *(const bs8*)(smem + oa);
            am[f] = *(const bs8*)(smem + 4096 + oa);
            int ob = (wn * 64 + f * 16 + l15) * 32 + cx8;
            bh[f] = *(const bs8*)(smem + 8192 + ob);
            bm[f] = *(const bs8*)(smem + 12288 + ob);
        }
        #pragma unroll
        for (int mf = 0; mf < 4; mf++)
            #pragma unroll
            for (int nf = 0; nf < 4; nf++) {
                acc[mf][nf] = __builtin_amdgcn_mfma_f32_16x16x32_bf16(am[mf], bh[nf], acc[mf][nf], 0, 0, 0);
                acc[mf][nf] = __builtin_amdgcn_mfma_f32_16x16x32_bf16(ah[mf], bm[nf], acc[mf][nf], 0, 0, 0);
                acc[mf][nf] = __builtin_amdgcn_mfma_f32_16x16x32_bf16(ah[mf], bh[nf], acc[mf][nf], 0, 0, 0);
            }
        __syncthreads();
    }

    #pragma unroll
    for (int mf = 0; mf < 4; mf++)
        #pragma unroll
        for (int i = 0; i < 4; i++) {
            int grow = m0 + wm * 64 + mf * 16 + l4 * 4 + i;
            if (grow < M) {
                #pragma unroll
                for (int nf = 0; nf < 4; nf++) {
                    int col = n0 + wn * 64 + nf * 16 + l15;
                    float v = acc[mf][nf][i] + (bias ? bias[col] : 0.f);
                    if (relu) v = fmaxf(v, 0.f);
                    if (Cf) Cf[(size_t)grow * N + col] = v;
                    else {
                        u16 h, m; split2b(v, h, m);
                        Ch[(size_t)grow * N + col] = h;
                        Cm[(size_t)grow * N + col] = m;
                    }
                }
            }
        }
}

// ---------------- thin fp32 row-GEMV ----------------
__global__ __launch_bounds__(128) void rowgemm_kernel(const float* __restrict__ A,
        const float* __restrict__ W, const float* __restrict__ bias,
        float* __restrict__ C, int N, int K, int relu,
        const float* __restrict__ resid, const float* __restrict__ resb) {
    __shared__ float sA[1024];
    int r = blockIdx.x;
    int c = blockIdx.y * 128 + threadIdx.x;
    for (int i = threadIdx.x; i < K; i += 128) sA[i] = A[(size_t)r * K + i];
    __syncthreads();
    float a0 = 0.f, a1 = 0.f, a2 = 0.f, a3 = 0.f;
    #pragma unroll 4
    for (int k = 0; k < K; k += 4) {
        a0 += sA[k]     * W[(size_t)k * N + c];
        a1 += sA[k + 1] * W[(size_t)(k + 1) * N + c];
        a2 += sA[k + 2] * W[(size_t)(k + 2) * N + c];
        a3 += sA[k + 3] * W[(size_t)(k + 3) * N + c];
    }
    float v = (a0 + a1) + (a2 + a3) + (bias ? bias[c] : 0.f);
    if (relu) v = fmaxf(v, 0.f);
    if (resid) v += resid[(size_t)r * N + c] + resb[c];
    C[(size_t)r * N + c] = v;
}

// gi/gh pair in one launch via blockIdx.z
__global__ __launch_bounds__(128) void rowgemmG_kernel(
        const float* __restrict__ A0, const float* __restrict__ W0,
        const float* __restrict__ b0, float* __restrict__ C0,
        const float* __restrict__ A1, const float* __restrict__ W1,
        const float* __restrict__ b1, float* __restrict__ C1,
        int N, int K) {
    __shared__ float sA[256];
    const float* A = blockIdx.z ? A1 : A0;
    const float* W = blockIdx.z ? W1 : W0;
    const float* B = blockIdx.z ? b1 : b0;
    float* C = blockIdx.z ? C1 : C0;
    int r = blockIdx.x;
    int c = blockIdx.y * 128 + threadIdx.x;
    for (int i = threadIdx.x; i < K; i += 128) sA[i] = A[(size_t)r * K + i];
    __syncthreads();
    float a0 = 0.f, a1 = 0.f, a2 = 0.f, a3 = 0.f;
    #pragma unroll 4
    for (int k = 0; k < K; k += 4) {
        a0 += sA[k]     * W[(size_t)k * N + c];
        a1 += sA[k + 1] * W[(size_t)(k + 1) * N + c];
        a2 += sA[k + 2] * W[(size_t)(k + 2) * N + c];
        a3 += sA[k + 3] * W[(size_t)(k + 3) * N + c];
    }
    C[(size_t)r * N + c] = (a0 + a1) + (a2 + a3) + B[c];
}

// ---------------- small kernels ----------------
__global__ __launch_bounds__(256) void init_kernel(const float* __restrict__ slots_init_p,
        const float* __restrict__ S_s0, const float* __restrict__ S_p0,
        float* __restrict__ slots, float* __restrict__ S_s, float* __restrict__ S_p) {
    int bs = blockIdx.x, t = threadIdx.x;
    int s = bs % CS;
    slots[bs * CD + t] = slots_init_p[s * CD + t];
    if (t < 2) { S_s[bs * 2 + t] = S_s0[s * 2 + t]; S_p[bs * 2 + t] = S_p0[s * 2 + t]; }
}

// LN(slots) + qb0 + qw = sn @ Pq (fused GEMV)
__global__ __launch_bounds__(256) void ln_slots_q_kernel(const float* __restrict__ slots,
        const float* __restrict__ ln_g, const float* __restrict__ ln_b,
        const float* __restrict__ wqb, const float* __restrict__ Pq,
        float* __restrict__ qwb, float* __restrict__ qb0) {
    __shared__ float sbuf[8];
    __shared__ float sN[CD];
    int row = blockIdx.x, t = threadIdx.x;
    float x = slots[row * CD + t];
    float mean = block_reduce_sum(x, sbuf) / CD;
    float d0 = x - mean;
    float var = block_reduce_sum(d0 * d0, sbuf) / CD;
    float sn = d0 * rsqrtf(var + LNEPS) * ln_g[t] + ln_b[t];
    sN[t] = sn;
    float qb = block_reduce_sum(sn * wqb[t], sbuf);
    if (t == 0) qb0[row] = qb;
    __syncthreads();
    float acc = 0.f;
    #pragma unroll 4
    for (int k = 0; k < CD; k++) acc += sN[k] * Pq[(size_t)k * CD + t];
    qwb[row * CD + t] = acc;
}

// dots + softmax-over-slots fused
__global__ __launch_bounds__(256) void dots_kernel(const float* __restrict__ KVX,
        const float* __restrict__ S_p, const float* __restrict__ S_s,
        const float* __restrict__ G2, const float* __restrict__ gb1,
        const float* __restrict__ qw, const float* __restrict__ qb0,
        float* __restrict__ attn) {
    int b = blockIdx.x;
    int w = threadIdx.x >> 6, l = threadIdx.x & 63;
    int k4 = l * 4;
    float4 g0 = *(const float4*)(G2 + k4);
    float4 g1 = *(const float4*)(G2 + CD + k4);
    float4 gb = *(const float4*)(gb1 + k4);
    float4 qwv[CS]; float px[CS], py[CS], ix[CS], iy[CS], q0[CS];
    #pragma unroll
    for (int s = 0; s < CS; s++) {
        int bs = b * CS + s;
        qwv[s] = *(const float4*)(qw + bs * CD + k4);
        px[s] = S_p[2 * bs]; py[s] = S_p[2 * bs + 1];
        ix[s] = 1.f / (S_s[2 * bs] * CSIGMA); iy[s] = 1.f / (S_s[2 * bs + 1] * CSIGMA);
        q0[s] = qb0[bs];
    }
    int nbase = blockIdx.y * 32 + w * 8;
    #pragma unroll 2
    for (int i = 0; i < 8; i++) {
        int n = nbase + i;
        int nc = n < CN ? n : CN - 1;
        float4 kx = *(const float4*)(KVX + (size_t)(b * CN + nc) * CKV + k4);
        float ax = ag_x(nc), ay = ag_y(nc);
        float dsv[CS];
        #pragma unroll
        for (int s = 0; s < CS; s++) {
            float r0 = (ax - px[s]) * ix[s];
            float r1 = (ay - py[s]) * iy[s];
            float v0 = fmaxf(kx.x + r0 * g0.x + r1 * g1.x + gb.x, 0.f);
            float v1 = fmaxf(kx.y + r0 * g0.y + r1 * g1.y + gb.y, 0.f);
            float v2 = fmaxf(kx.z + r0 * g0.z + r1 * g1.z + gb.z, 0.f);
            float v3 = fmaxf(kx.w + r0 * g0.w + r1 * g1.w + gb.w, 0.f);
            float d = v0 * qwv[s].x + v1 * qwv[s].y + v2 * qwv[s].z + v3 * qwv[s].w;
            #pragma unroll
            for (int off = 32; off > 0; off >>= 1) d += __shfl_down(d, off, 64);
            dsv[s] = 0.0625f * (d + q0[s]);
        }
        if (l == 0 && n < CN) {
            float mx = -1e30f;
            #pragma unroll
            for (int s = 0; s < CS; s++) mx = fmaxf(mx, dsv[s]);
            float sum = 0.f;
            #pragma unroll
            for (int s = 0; s < CS; s++) { dsv[s] = __expf(dsv[s] - mx); sum += dsv[s]; }
            float inv = 1.f / sum;
            #pragma unroll
            for (int s = 0; s < CS; s++)
                attn[(size_t)(b * CS + s) * CN + n] = dsv[s] * inv + ATTN_EPS;
        }
    }
}

// Wacc[bs][k] += sum_n attn[bs,n] * relu(VX[b,n,k] + r0*G2[0][k] + r1*G2[1][k] + gb1[k])
__global__ __launch_bounds__(256) void vsum_kernel(const float* __restrict__ VXW1,
        const float* __restrict__ S_p, const float* __restrict__ S_s,
        const float* __restrict__ G2, const float* __restrict__ gb1,
        const float* __restrict__ attn, float* __restrict__ Wacc) {
    __shared__ float sred[4 * CD];
    int b = blockIdx.x;
    int w = threadIdx.x >> 6, l = threadIdx.x & 63;
    int k4 = l * 4;
    float4 g0 = *(const float4*)(G2 + k4);
    float4 g1 = *(const float4*)(G2 + CD + k4);
    float4 gb = *(const float4*)(gb1 + k4);
    float px[CS], py[CS], ix[CS], iy[CS];
    #pragma unroll
    for (int s = 0; s < CS; s++) {
        int bs = b * CS + s;
        px[s] = S_p[2 * bs]; py[s] = S_p[2 * bs + 1];
        ix[s] = 1.f / (S_s[2 * bs] * CSIGMA); iy[s] = 1.f / (S_s[2 * bs + 1] * CSIGMA);
    }
    float4 acc[CS];
    #pragma unroll
    for (int s = 0; s < CS; s++) acc[s] = make_float4(0.f, 0.f, 0.f, 0.f);
    int nbase = blockIdx.y * 32 + w * 8;
    #pragma unroll 2
    for (int i = 0; i < 8; i++) {
        int n = nbase + i;
        int nc = n < CN ? n : CN - 1;
        float4 vx = *(const float4*)(VXW1 + (size_t)(b * CN + nc) * CKV + k4);
        float ax = ag_x(nc), ay = ag_y(nc);
        #pragma unroll
        for (int s = 0; s < CS; s++) {
            float r0 = (ax - px[s]) * ix[s];
            float r1 = (ay - py[s]) * iy[s];
            float a = (n < CN) ? attn[(size_t)(b * CS + s) * CN + n] : 0.f;
            acc[s].x += a * fmaxf(vx.x + r0 * g0.x + r1 * g1.x + gb.x, 0.f);
            acc[s].y += a * fmaxf(vx.y + r0 * g0.y + r1 * g1.y + gb.y, 0.f);
            acc[s].z += a * fmaxf(vx.z + r0 * g0.z + r1 * g1.z + gb.z, 0.f);
            acc[s].w += a * fmaxf(vx.w + r0 * g0.w + r1 * g1.w + gb.w, 0.f);
        }
    }
    for (int s = 0; s < CS; s++) {
        ((float4*)sred)[w * 64 + l] = acc[s];
        __syncthreads();
        if (threadIdx.x < CD) {
            float v = sred[threadIdx.x] + sred[CD + threadIdx.x]
                    + sred[2 * CD + threadIdx.x] + sred[3 * CD + threadIdx.x];
            atomicAdd(&Wacc[(size_t)(b * CS + s) * CD + threadIdx.x], v);
        }
        __syncthreads();
    }
}

__global__ __launch_bounds__(256) void attn_moments_kernel(float* __restrict__ u,
        float* __restrict__ S_p, float* __restrict__ S_s) {
    __shared__ float sbuf[8];
    int bs = blockIdx.x;
    float* up = u + (size_t)bs * CN;
    float m0 = 0, m1x = 0, m1y = 0, m2x = 0, m2y = 0;
    for (int n = threadIdx.x; n < CN; n += 256) {
        float uu = up[n];
        float ax = ag_x(n), ay = ag_y(n);
        m0 += uu; m1x += uu * ax; m1y += uu * ay; m2x += uu * ax * ax; m2y += uu * ay * ay;
    }
    m0  = block_reduce_sum(m0, sbuf);
    m1x = block_reduce_sum(m1x, sbuf);
    m1y = block_reduce_sum(m1y, sbuf);
    m2x = block_reduce_sum(m2x, sbuf);
    m2y = block_reduce_sum(m2y, sbuf);
    float px = m1x / m0, py = m1y / m0;
    if (threadIdx.x == 0) {
        S_p[2 * bs] = px; S_p[2 * bs + 1] = py;
        S_s[2 * bs]     = sqrtf(fmaxf(m2x / m0 - px * px, 0.f));
        S_s[2 * bs + 1] = sqrtf(fmaxf(m2y / m0 - py * py, 0.f));
    }
    float inv = 1.f / m0;
    for (int n = threadIdx.x; n < CN; n += 256) up[n] = up[n] * inv;
}

// GRU gates + LN + first MLP GEMV fused: h1 = relu(sM @ mlp_w1 + mlp_b1)
__global__ __launch_bounds__(256) void gate_mlp1_kernel(const float* __restrict__ giRaw,
        const float* __restrict__ ghRaw, const float* __restrict__ slots,
        const float* __restrict__ mg, const float* __restrict__ mb,
        const float* __restrict__ mlp_w1, const float* __restrict__ mlp_b1,
        float* __restrict__ snewb, float* __restrict__ h1b) {
    __shared__ float sbuf[8];
    __shared__ float sM[CD];
    int row = blockIdx.x, t = threadIdx.x;
    float gi0 = giRaw[row * 3 * CD + t];
    float gi1 = giRaw[row * 3 * CD + CD + t];
    float gi2 = giRaw[row * 3 * CD + 2 * CD + t];
    float gh0 = ghRaw[row * 3 * CD + t];
    float gh1 = ghRaw[row * 3 * CD + CD + t];
    float gh2 = ghRaw[row * 3 * CD + 2 * CD + t];
    float r = 1.f / (1.f + expf(-(gi0 + gh0)));
    float z = 1.f / (1.f + expf(-(gi1 + gh1)));
    float nn = tanhf(gi2 + r * gh2);
    float snew = (1.f - z) * nn + z * slots[row * CD + t];
    snewb[row * CD + t] = snew;
    float mean = block_reduce_sum(snew, sbuf) / CD;
    float dv = snew - mean;
    float var = block_reduce_sum(dv * dv, sbuf) / CD;
    sM[t] = dv * rsqrtf(var + LNEPS) * mg[t] + mb[t];
    __syncthreads();
    #pragma unroll
    for (int j = 0; j < 4; j++) {
        int c = j * 256 + t;
        float a = 0.f;
        #pragma unroll 4
        for (int k = 0; k < CD; k++) a += sM[k] * mlp_w1[(size_t)k * (4 * CD) + c];
        h1b[(size_t)row * (4 * CD) + c] = fmaxf(a + mlp_b1[c], 0.f);
    }
}

// ---------------- launcher ----------------
extern "C" void kernel_launch(void* const* d_in, const int* in_sizes, int n_in,
                              void* d_out, int out_size, void* d_ws, size_t ws_size,
                              hipStream_t stream) {
    (void)in_sizes; (void)n_in; (void)out_size;
    const float* inputs       = (const float*)d_in[0];
    const float* slots_init_p = (const float*)d_in[1];
    const float* S_s0         = (const float*)d_in[2];
    const float* S_p0         = (const float*)d_in[3];
    const float* im_ln1_g = (const float*)d_in[4];
    const float* im_ln1_b = (const float*)d_in[5];
    const float* im_w1    = (const float*)d_in[6];
    const float* im_b1    = (const float*)d_in[7];
    const float* im_w2    = (const float*)d_in[8];
    const float* im_b2    = (const float*)d_in[9];
    const float* im_ln2_g = (const float*)d_in[10];
    const float* im_ln2_b = (const float*)d_in[11];
    const float* Wq  = (const float*)d_in[12];
    const float* Wk  = (const float*)d_in[13];
    const float* Wv  = (const float*)d_in[14];
    const float* g_w = (const float*)d_in[15];
    const float* g_b = (const float*)d_in[16];
    const float* f_w1 = (const float*)d_in[17];
    const float* f_b1 = (const float*)d_in[18];
    const float* f_w2 = (const float*)d_in[19];
    const float* f_b2 = (const float*)d_in[20];
    const float* ln_g = (const float*)d_in[21];
    const float* ln_b = (const float*)d_in[22];
    const float* gru_wih = (const float*)d_in[23];
    const float* gru_whh = (const float*)d_in[24];
    const float* gru_bih = (const float*)d_in[25];
    const float* gru_bhh = (const float*)d_in[26];
    const float* mlp_ln_g = (const float*)d_in[27];
    const float* mlp_ln_b = (const float*)d_in[28];
    const float* mlp_w1 = (const float*)d_in[29];
    const float* mlp_b1 = (const float*)d_in[30];
    const float* mlp_w2 = (const float*)d_in[31];
    const float* mlp_b2 = (const float*)d_in[32];
    const float* fin_w = (const float*)d_in[33];
    const float* fin_b = (const float*)d_in[34];

    char* base = (char*)d_ws;
    size_t off = 0;
    auto take = [&](size_t bytes) { void* p = base + off; off += (bytes + 255) & ~(size_t)255; return p; };

    float* R1 = (float*)take((size_t)CBN * CDIN * 4);  // xln planes -> xD | xDn planes
    float* R2 = (float*)take((size_t)CBN * CDIN * 4);  // X1 planes -> KVX
    u16* w1th = (u16*)take((size_t)CDIN * CDIN * 2);
    u16* w1tm = (u16*)take((size_t)CDIN * CDIN * 2);
    u16* w2th = (u16*)take((size_t)CDIN * CD * 2);
    u16* w2tm = (u16*)take((size_t)CDIN * CD * 2);
    float* Pk   = (float*)take((size_t)CD * CD * 4);
    float* Pv   = (float*)take((size_t)CD * CD * 4);
    u16* kvth = (u16*)take((size_t)CKV * CD * 2);      // [512][256]: PkT | PvT
    u16* kvtm = (u16*)take((size_t)CKV * CD * 2);
    float* G2b  = (float*)take((size_t)2 * CD * 4);
    float* gb1b = (float*)take((size_t)CD * 4);
    float* fw2T = (float*)take((size_t)CD * CD * 4);
    float* Pq   = (float*)take((size_t)CD * CD * 4);
    float* Pg   = (float*)take((size_t)CD * 3 * CD * 4);
    float* bgv  = (float*)take((size_t)3 * CD * 4);
    float* wqbb = (float*)take((size_t)CD * 4);
    float* qwb   = (float*)take((size_t)CBS * CD * 4);
    float* qb0b  = (float*)take((size_t)CBS * 4);
    float* Wacc  = (float*)take((size_t)CBS * CD * 4);
    float* giRaw = (float*)take((size_t)CBS * 3 * CD * 4);
    float* ghRaw = (float*)take((size_t)CBS * 3 * CD * 4);
    float* snewb = (float*)take((size_t)CBS * CD * 4);
    float* h1b   = (float*)take((size_t)CBS * 4 * CD * 4);
    float* S_pA  = (float*)take((size_t)CBS * 2 * 4);
    float* S_sA  = (float*)take((size_t)CBS * 2 * 4);
    float* S_pB  = (float*)take((size_t)CBS * 2 * 4);
    float* S_sB  = (float*)take((size_t)CBS * 2 * 4);
    float* slots = (float*)take((size_t)CBS * CD * 4);
    if (ws_size < off) return;

    // plane/buffer aliasing (lifetimes disjoint):
    u16* xlnh = (u16*)R1;                                  // [CBN][768] planes
    u16* xlnm = xlnh + (size_t)CBN * CDIN;
    u16* X1h  = (u16*)R2;                                  // [CBN][768] planes
    u16* X1m  = X1h + (size_t)CBN * CDIN;
    float* xD = R1;                                        // [CBN][256] fp32 (xln dead)
    u16* xDnh = (u16*)(R1 + (size_t)CBN * CD);             // [CBN][256] planes
    u16* xDnm = xDnh + (size_t)CBN * CD;
    float* KVX = R2;                                       // [CBN][512] fp32 (X1 dead)

    float* out0 = (float*)d_out;            // [CBS,CD]
    float* attnb = out0 + CBS * CD;         // [CBS,CN]

    dim3 blk(256);
    const int gM_bn = (CBN + 127) / 128;    // 86
    dim3 gridBN(CB, (CN + 31) / 32);        // 8 x 43

    // ---- weight prep ----
    transpose_split2_kernel<<<dim3(CDIN/32, CDIN/32), blk, 0, stream>>>(im_w1, w1th, w1tm, CDIN, CDIN);
    transpose_split2_kernel<<<dim3(CD/32,   CDIN/32), blk, 0, stream>>>(im_w2, w2th, w2tm, CDIN, CD);
    wprodN_kernel<<<dim3(CD, 1), blk, 0, stream>>>(Wk, f_w1, Pk, CD);
    wprodN_kernel<<<dim3(CD, 1), blk, 0, stream>>>(Wv, f_w1, Pv, CD);
    transpose_split2_kernel<<<dim3(CD/32, CD/32), blk, 0, stream>>>(Pk, kvth, kvtm, CD, CD);
    transpose_split2_kernel<<<dim3(CD/32, CD/32), blk, 0, stream>>>(Pv,
        kvth + (size_t)CD * CD, kvtm + (size_t)CD * CD, CD, CD);
    g2_kernel<<<1, blk, 0, stream>>>(g_w, g_b, f_w1, f_b1, G2b, gb1b);
    transpose32_kernel<<<dim3(CD/32, CD/32), blk, 0, stream>>>(f_w2, fw2T, CD, CD);
    wprodN_kernel<<<dim3(CD, 1), blk, 0, stream>>>(Wq, fw2T, Pq, CD);
    wprodN_kernel<<<dim3(CD, 3), blk, 0, stream>>>(f_w2, gru_wih, Pg, 3 * CD);
    bg_kernel<<<3, blk, 0, stream>>>(f_b2, gru_wih, gru_bih, bgv, 3 * CD);
    wqb_kernel<<<1, blk, 0, stream>>>(Wq, f_b2, wqbb);

    // ---- initial mlp (planes end-to-end) ----
    ln_planes_kernel<<<CBN, blk, 0, stream>>>(inputs, xlnh, xlnm, im_ln1_g, im_ln1_b, CDIN);
    hgemm2<<<dim3(CDIN/128, gM_bn), blk, 0, stream>>>(xlnh, xlnm, w1th, w1tm,
        CBN, CDIN, CDIN, im_b1, 1, nullptr, X1h, X1m);
    hgemm2<<<dim3(CD/128, gM_bn), blk, 0, stream>>>(X1h, X1m, w2th, w2tm,
        CBN, CD, CDIN, im_b2, 0, xD, nullptr, nullptr);
    ln_planes_kernel<<<CBN, blk, 0, stream>>>(xD, xDnh, xDnm, im_ln2_g, im_ln2_b, CD);
    hgemm2<<<dim3(CKV/128, gM_bn), blk, 0, stream>>>(xDnh, xDnm, kvth, kvtm,
        CBN, CKV, CD, nullptr, 0, KVX, nullptr, nullptr);
    init_kernel<<<CBS, blk, 0, stream>>>(slots_init_p, S_s0, S_p0, slots, S_sA, S_pA);

    for (int t = 0; t <= CITERS; t++) {
        float* Sp_cur = (t & 1) ? S_pB : S_pA;
        float* Ss_cur = (t & 1) ? S_sB : S_sA;
        float* Sp_nxt = (t & 1) ? S_pA : S_pB;
        float* Ss_nxt = (t & 1) ? S_sA : S_sB;
        ln_slots_q_kernel<<<CBS, blk, 0, stream>>>(slots, ln_g, ln_b, wqbb, Pq, qwb, qb0b);
        dots_kernel<<<gridBN, blk, 0, stream>>>(KVX, Sp_cur, Ss_cur, G2b, gb1b, qwb, qb0b, attnb);
        attn_moments_kernel<<<CBS, blk, 0, stream>>>(attnb, Sp_nxt, Ss_nxt);
        if (t < CITERS) {
            hipMemsetAsync(Wacc, 0, (size_t)CBS * CD * sizeof(float), stream);
            vsum_kernel<<<gridBN, blk, 0, stream>>>(KVX + CD, Sp_cur, Ss_cur, G2b, gb1b, attnb, Wacc);
            rowgemmG_kernel<<<dim3(CBS, 3*CD/128, 2), dim3(128), 0, stream>>>(
                Wacc, Pg, bgv, giRaw, slots, gru_whh, gru_bhh, ghRaw, 3 * CD, CD);
            gate_mlp1_kernel<<<CBS, blk, 0, stream>>>(giRaw, ghRaw, slots,
                mlp_ln_g, mlp_ln_b, mlp_w1, mlp_b1, snewb, h1b);
            rowgemm_kernel<<<dim3(CBS, CD/128), dim3(128), 0, stream>>>(h1b, mlp_w2, nullptr,
                slots, CD, 4 * CD, 0, snewb, mlp_b2);
        }
    }
    // out0 = slots @ fin_w + fin_b
    rowgemm_kernel<<<dim3(CBS, CD/128), dim3(128), 0, stream>>>(slots, fin_w, fin_b,
        out0, CD, CD, 0, nullptr, nullptr);
}

// Round 2
// 786.857 us; speedup vs baseline: 1.3070x; 1.3070x over previous
//
#include <hip/hip_runtime.h>

// ---------------- problem constants ----------------
constexpr int CB   = 8;      // batch
constexpr int CN   = 1369;   // tokens (37*37)
constexpr int CDIN = 768;
constexpr int CS   = 7;      // slots
constexpr int CD   = 256;
constexpr int CITERS = 3;
constexpr int CRES = 37;
constexpr float CSIGMA = 5.0f;
constexpr int CBS = CB * CS;        // 56
constexpr int CBN = CB * CN;        // 10952 rows for initial mlp
constexpr int CKV = 2 * CD;         // interleaved KX|VX row stride
constexpr float LNEPS = 1e-5f;
constexpr float ATTN_EPS = 1e-8f;

typedef unsigned short u16;
typedef short bs8 __attribute__((ext_vector_type(8)));   // 8 bf16 (bit pattern in shorts)
typedef float f4 __attribute__((ext_vector_type(4)));

// ---------------- helpers ----------------
__device__ __forceinline__ float ag_x(int n) { return -1.f + (float)(n % CRES) * (2.f / 36.f); }
__device__ __forceinline__ float ag_y(int n) { return -1.f + (float)(n / CRES) * (2.f / 36.f); }

__device__ __forceinline__ u16 bf_rne(float f) {
    unsigned u = __float_as_uint(f);
    return (u16)((u + 0x7FFFu + ((u >> 16) & 1u)) >> 16);
}
__device__ __forceinline__ float bf_to_f(u16 h) { return __uint_as_float(((unsigned)h) << 16); }

__device__ __forceinline__ void split2b(float v, u16& h, u16& m) {
    h = bf_rne(v);
    m = bf_rne(v - bf_to_f(h));
}

// async global->LDS, 16B per lane (dest = wave-uniform base + lane*16)
__device__ __forceinline__ void async16(const u16* g, u16* l) {
    __builtin_amdgcn_global_load_lds(
        (const __attribute__((address_space(1))) unsigned int*)g,
        (__attribute__((address_space(3))) unsigned int*)l, 16, 0, 0);
}

// 256-thread block sum
__device__ __forceinline__ float block_reduce_sum(float v, float* sbuf) {
    #pragma unroll
    for (int off = 32; off > 0; off >>= 1) v += __shfl_down(v, off, 64);
    if ((threadIdx.x & 63) == 0) sbuf[threadIdx.x >> 6] = v;
    __syncthreads();
    if (threadIdx.x == 0) sbuf[0] = sbuf[0] + sbuf[1] + sbuf[2] + sbuf[3];
    __syncthreads();
    float r = sbuf[0];
    __syncthreads();
    return r;
}

// ---------------- layernorm -> split-2 bf16 planes ----------------
__global__ __launch_bounds__(256) void ln_planes_kernel(const float* __restrict__ in,
        u16* __restrict__ Yh, u16* __restrict__ Ym,
        const float* __restrict__ g, const float* __restrict__ b, int d) {
    __shared__ float sbuf[8];
    int row = blockIdx.x;
    const float* x = in + (size_t)row * d;
    float s = 0.f;
    for (int i = threadIdx.x; i < d; i += 256) s += x[i];
    float mean = block_reduce_sum(s, sbuf) / d;
    float v = 0.f;
    for (int i = threadIdx.x; i < d; i += 256) { float t = x[i] - mean; v += t * t; }
    float var = block_reduce_sum(v, sbuf) / d;
    float rstd = rsqrtf(var + LNEPS);
    for (int i = threadIdx.x; i < d; i += 256) {
        float y = (x[i] - mean) * rstd * g[i] + b[i];
        u16 h, m; split2b(y, h, m);
        Yh[(size_t)row * d + i] = h;
        Ym[(size_t)row * d + i] = m;
    }
}

// ---------------- transpose fp32 W[K][N] -> 2 bf16 planes Wt[N][K] ----------------
__global__ __launch_bounds__(256) void transpose_split2_kernel(const float* __restrict__ W,
        u16* __restrict__ Th, u16* __restrict__ Tm, int K, int N) {
    __shared__ float tile[32][33];
    int nb = blockIdx.x * 32, kb = blockIdx.y * 32;
    int tx = threadIdx.x & 31, ty = threadIdx.x >> 5;   // ty 0..7
    #pragma unroll
    for (int i = 0; i < 32; i += 8)
        tile[ty + i][tx] = W[(size_t)(kb + ty + i) * N + nb + tx];
    __syncthreads();
    #pragma unroll
    for (int i = 0; i < 32; i += 8) {
        float v = tile[tx][ty + i];
        u16 h, m; split2b(v, h, m);
        size_t idx = (size_t)(nb + ty + i) * K + kb + tx;
        Th[idx] = h; Tm[idx] = m;
    }
}

// ---------------- fp32 transpose W[K][N] -> T[N][K] ----------------
__global__ __launch_bounds__(256) void transpose32_kernel(const float* __restrict__ W,
        float* __restrict__ T, int K, int N) {
    __shared__ float tile[32][33];
    int nb = blockIdx.x * 32, kb = blockIdx.y * 32;
    int tx = threadIdx.x & 31, ty = threadIdx.x >> 5;
    #pragma unroll
    for (int i = 0; i < 32; i += 8)
        tile[ty + i][tx] = W[(size_t)(kb + ty + i) * N + nb + tx];
    __syncthreads();
    #pragma unroll
    for (int i = 0; i < 32; i += 8)
        T[(size_t)(nb + ty + i) * K + kb + tx] = tile[tx][ty + i];
}

// ---------------- P[k][n] = sum_j A[k][j]*B[j][n], A [256][256], B [256][N] ----------------
__global__ __launch_bounds__(256) void wprodN_kernel(const float* __restrict__ A,
        const float* __restrict__ B, float* __restrict__ P, int N) {
    __shared__ float arow[CD];
    int k = blockIdx.x;
    arow[threadIdx.x] = A[k * CD + threadIdx.x];
    __syncthreads();
    int n = blockIdx.y * 256 + threadIdx.x;
    if (n >= N) return;
    float acc = 0.f;
    for (int j = 0; j < CD; j++) acc += arow[j] * B[(size_t)j * N + n];
    P[(size_t)k * N + n] = acc;
}

// G2[g][n] = sum_j g_w[g][j]*f_w1[j][n];  gb1[n] = sum_j g_b[j]*f_w1[j][n] + f_b1[n]
__global__ __launch_bounds__(256) void g2_kernel(const float* __restrict__ g_w,
        const float* __restrict__ g_b, const float* __restrict__ f_w1,
        const float* __restrict__ f_b1, float* __restrict__ G2, float* __restrict__ gb1) {
    int n = threadIdx.x;
    float a0 = 0.f, a1 = 0.f, ab = 0.f;
    for (int j = 0; j < CD; j++) {
        float w = f_w1[j * CD + n];
        a0 += g_w[j] * w;
        a1 += g_w[CD + j] * w;
        ab += g_b[j] * w;
    }
    G2[n] = a0; G2[CD + n] = a1; gb1[n] = ab + f_b1[n];
}

// bg[n] = sum_c f_b2[c]*wih[c][n] + bih[n]   (N=768)
__global__ __launch_bounds__(256) void bg_kernel(const float* __restrict__ f_b2,
        const float* __restrict__ wih, const float* __restrict__ bih,
        float* __restrict__ bg, int N) {
    int n = blockIdx.x * 256 + threadIdx.x;
    if (n >= N) return;
    float s = bih[n];
    for (int c = 0; c < CD; c++) s += f_b2[c] * wih[(size_t)c * N + n];
    bg[n] = s;
}

// wqb[j] = sum_c Wq[j][c] * f_b2[c]
__global__ __launch_bounds__(256) void wqb_kernel(const float* __restrict__ Wq,
        const float* __restrict__ f_b2, float* __restrict__ wqb) {
    int j = threadIdx.x;
    float s = 0.f;
    for (int c = 0; c < CD; c++) s += Wq[j * CD + c] * f_b2[c];
    wqb[j] = s;
}

// ---------------- bf16x3 plane GEMM, global_load_lds + 2-phase double buffer ----------------
// A planes Ah/Am [M][K], B planes Bh/Bm [N][K]; K%32==0, N%128==0.
// LDS 2 x [4 planes][128 rows][32 k] u16 (64 KB). XOR chunk swizzle c' = c ^ (r&3):
// inverse-permuted GLOBAL source on the write side (global_load_lds writes linearly)
// + same XOR on the ds_read side (guideline 21: both-sides-or-neither).
// T3-minimum pipeline: issue next tile's global_load_lds BEFORE current tile's
// ds_read+MFMA; single vmcnt-drain barrier per K-step (latency hides under compute).
__global__ __launch_bounds__(256)
void hgemm2(const u16* __restrict__ Ah, const u16* __restrict__ Am,
            const u16* __restrict__ Bh, const u16* __restrict__ Bm,
            int M, int N, int K, const float* __restrict__ bias, int relu,
            float* __restrict__ Cf, u16* __restrict__ Ch, u16* __restrict__ Cm) {
    __shared__ u16 smem[2][4 * 128 * 32];   // 2 x 32 KB
    const int tid = threadIdx.x;
    const int m0 = blockIdx.y * 128, n0 = blockIdx.x * 128;
    const int w = tid >> 6, lane = tid & 63;
    const int wm = w & 1, wn = w >> 1;
    const int l15 = lane & 15, l4 = lane >> 4;

    // 8 issues/thread/k-step; issue i covers LDS chunks q = i*256 + tid (16B chunks).
    const u16* srcp[8];
    int dsto[8];
    #pragma unroll
    for (int i = 0; i < 8; i++) {
        int q = i * 256 + tid;
        int qq = q & 511;
        int r = qq >> 2;
        int c = (qq & 3) ^ (r & 3);      // inverse swizzle on the source
        int plane = i >> 1;              // 0:Ah 1:Am 2:Bh 3:Bm (compile-time per unrolled i)
        const u16* bp; int row;
        if (plane == 0)      { bp = Ah; row = m0 + r; row = row < M ? row : M - 1; }
        else if (plane == 1) { bp = Am; row = m0 + r; row = row < M ? row : M - 1; }
        else if (plane == 2) { bp = Bh; row = n0 + r; }
        else                 { bp = Bm; row = n0 + r; }
        srcp[i] = bp + (size_t)row * K + c * 8;
        dsto[i] = i * 2048 + w * 512;    // wave-uniform; HW adds lane*16B
    }

    f4 acc[4][4];
    #pragma unroll
    for (int i = 0; i < 4; i++)
        #pragma unroll
        for (int j = 0; j < 4; j++) acc[i][j] = (f4){0.f, 0.f, 0.f, 0.f};

    const int cx8 = (l4 ^ (l15 & 3)) * 8;     // swizzled k-chunk for fragment reads

    // prologue: stage tile 0
    #pragma unroll
    for (int i = 0; i < 8; i++) async16(srcp[i], &smem[0][dsto[i]]);
    __syncthreads();

    int cur = 0;
    for (int k0 = 0; k0 < K; k0 += 32) {
        // issue next tile's loads into the other buffer (overlaps with MFMA below)
        if (k0 + 32 < K) {
            #pragma unroll
            for (int i = 0; i < 8; i++) async16(srcp[i] + k0 + 32, &smem[cur ^ 1][dsto[i]]);
        }
        const u16* sm = smem[cur];
        bs8 ah[4], am[4], bh[4], bm[4];
        #pragma unroll
        for (int f = 0; f < 4; f++) {
            int oa = (wm * 64 + f * 16 + l15) * 32 + cx8;
            ah[f] = *(const bs8*)(sm + oa);
            am[f] = *(const bs8*)(sm + 4096 + oa);
            int ob = (wn * 64 + f * 16 + l15) * 32 + cx8;
            bh[f] = *(const bs8*)(sm + 8192 + ob);
            bm[f] = *(const bs8*)(sm + 12288 + ob);
        }
        #pragma unroll
        for (int mf = 0; mf < 4; mf++)
            #pragma unroll
            for (int nf = 0; nf < 4; nf++) {
                acc[mf][nf] = __builtin_amdgcn_mfma_f32_16x16x32_bf16(am[mf], bh[nf], acc[mf][nf], 0, 0, 0);
                acc[mf][nf] = __builtin_amdgcn_mfma_f32_16x16x32_bf16(ah[mf], bm[nf], acc[mf][nf], 0, 0, 0);
                acc[mf][nf] = __builtin_amdgcn_mfma_f32_16x16x32_bf16(ah[mf], bh[nf], acc[mf][nf], 0, 0, 0);
            }
        __syncthreads();   // drains vmcnt for the prefetched tile + syncs buffer swap
        cur ^= 1;
    }

    #pragma unroll
    for (int mf = 0; mf < 4; mf++)
        #pragma unroll
        for (int i = 0; i < 4; i++) {
            int grow = m0 + wm * 64 + mf * 16 + l4 * 4 + i;
            if (grow < M) {
                #pragma unroll
                for (int nf = 0; nf < 4; nf++) {
                    int col = n0 + wn * 64 + nf * 16 + l15;
                    float v = acc[mf][nf][i] + (bias ? bias[col] : 0.f);
                    if (relu) v = fmaxf(v, 0.f);
                    if (Cf) Cf[(size_t)grow * N + col] = v;
                    else {
                        u16 h, m; split2b(v, h, m);
                        Ch[(size_t)grow * N + col] = h;
                        Cm[(size_t)grow * N + col] = m;
                    }
                }
            }
        }
}

// ---------------- thin fp32 row-GEMV ----------------
__global__ __launch_bounds__(128) void rowgemm_kernel(const float* __restrict__ A,
        const float* __restrict__ W, const float* __restrict__ bias,
        float* __restrict__ C, int N, int K, int relu,
        const float* __restrict__ resid, const float* __restrict__ resb) {
    __shared__ float sA[1024];
    int r = blockIdx.x;
    int c = blockIdx.y * 128 + threadIdx.x;
    for (int i = threadIdx.x; i < K; i += 128) sA[i] = A[(size_t)r * K + i];
    __syncthreads();
    float a0 = 0.f, a1 = 0.f, a2 = 0.f, a3 = 0.f;
    #pragma unroll 4
    for (int k = 0; k < K; k += 4) {
        a0 += sA[k]     * W[(size_t)k * N + c];
        a1 += sA[k + 1] * W[(size_t)(k + 1) * N + c];
        a2 += sA[k + 2] * W[(size_t)(k + 2) * N + c];
        a3 += sA[k + 3] * W[(size_t)(k + 3) * N + c];
    }
    float v = (a0 + a1) + (a2 + a3) + (bias ? bias[c] : 0.f);
    if (relu) v = fmaxf(v, 0.f);
    if (resid) v += resid[(size_t)r * N + c] + resb[c];
    C[(size_t)r * N + c] = v;
}

// gi/gh pair in one launch via blockIdx.z
__global__ __launch_bounds__(128) void rowgemmG_kernel(
        const float* __restrict__ A0, const float* __restrict__ W0,
        const float* __restrict__ b0, float* __restrict__ C0,
        const float* __restrict__ A1, const float* __restrict__ W1,
        const float* __restrict__ b1, float* __restrict__ C1,
        int N, int K) {
    __shared__ float sA[256];
    const float* A = blockIdx.z ? A1 : A0;
    const float* W = blockIdx.z ? W1 : W0;
    const float* B = blockIdx.z ? b1 : b0;
    float* C = blockIdx.z ? C1 : C0;
    int r = blockIdx.x;
    int c = blockIdx.y * 128 + threadIdx.x;
    for (int i = threadIdx.x; i < K; i += 128) sA[i] = A[(size_t)r * K + i];
    __syncthreads();
    float a0 = 0.f, a1 = 0.f, a2 = 0.f, a3 = 0.f;
    #pragma unroll 4
    for (int k = 0; k < K; k += 4) {
        a0 += sA[k]     * W[(size_t)k * N + c];
        a1 += sA[k + 1] * W[(size_t)(k + 1) * N + c];
        a2 += sA[k + 2] * W[(size_t)(k + 2) * N + c];
        a3 += sA[k + 3] * W[(size_t)(k + 3) * N + c];
    }
    C[(size_t)r * N + c] = (a0 + a1) + (a2 + a3) + B[c];
}

// ---------------- small kernels ----------------
__global__ __launch_bounds__(256) void init_kernel(const float* __restrict__ slots_init_p,
        const float* __restrict__ S_s0, const float* __restrict__ S_p0,
        float* __restrict__ slots, float* __restrict__ S_s, float* __restrict__ S_p) {
    int bs = blockIdx.x, t = threadIdx.x;
    int s = bs % CS;
    slots[bs * CD + t] = slots_init_p[s * CD + t];
    if (t < 2) { S_s[bs * 2 + t] = S_s0[s * 2 + t]; S_p[bs * 2 + t] = S_p0[s * 2 + t]; }
}

// LN(slots) + qb0 + qw = sn @ Pq (fused GEMV)
__global__ __launch_bounds__(256) void ln_slots_q_kernel(const float* __restrict__ slots,
        const float* __restrict__ ln_g, const float* __restrict__ ln_b,
        const float* __restrict__ wqb, const float* __restrict__ Pq,
        float* __restrict__ qwb, float* __restrict__ qb0) {
    __shared__ float sbuf[8];
    __shared__ float sN[CD];
    int row = blockIdx.x, t = threadIdx.x;
    float x = slots[row * CD + t];
    float mean = block_reduce_sum(x, sbuf) / CD;
    float d0 = x - mean;
    float var = block_reduce_sum(d0 * d0, sbuf) / CD;
    float sn = d0 * rsqrtf(var + LNEPS) * ln_g[t] + ln_b[t];
    sN[t] = sn;
    float qb = block_reduce_sum(sn * wqb[t], sbuf);
    if (t == 0) qb0[row] = qb;
    __syncthreads();
    float acc = 0.f;
    #pragma unroll 4
    for (int k = 0; k < CD; k++) acc += sN[k] * Pq[(size_t)k * CD + t];
    qwb[row * CD + t] = acc;
}

// dots + softmax-over-slots fused
__global__ __launch_bounds__(256) void dots_kernel(const float* __restrict__ KVX,
        const float* __restrict__ S_p, const float* __restrict__ S_s,
        const float* __restrict__ G2, const float* __restrict__ gb1,
        const float* __restrict__ qw, const float* __restrict__ qb0,
        float* __restrict__ attn) {
    int b = blockIdx.x;
    int w = threadIdx.x >> 6, l = threadIdx.x & 63;
    int k4 = l * 4;
    float4 g0 = *(const float4*)(G2 + k4);
    float4 g1 = *(const float4*)(G2 + CD + k4);
    float4 gb = *(const float4*)(gb1 + k4);
    float4 qwv[CS]; float px[CS], py[CS], ix[CS], iy[CS], q0[CS];
    #pragma unroll
    for (int s = 0; s < CS; s++) {
        int bs = b * CS + s;
        qwv[s] = *(const float4*)(qw + bs * CD + k4);
        px[s] = S_p[2 * bs]; py[s] = S_p[2 * bs + 1];
        ix[s] = 1.f / (S_s[2 * bs] * CSIGMA); iy[s] = 1.f / (S_s[2 * bs + 1] * CSIGMA);
        q0[s] = qb0[bs];
    }
    int nbase = blockIdx.y * 32 + w * 8;
    #pragma unroll 2
    for (int i = 0; i < 8; i++) {
        int n = nbase + i;
        int nc = n < CN ? n : CN - 1;
        float4 kx = *(const float4*)(KVX + (size_t)(b * CN + nc) * CKV + k4);
        float ax = ag_x(nc), ay = ag_y(nc);
        float dsv[CS];
        #pragma unroll
        for (int s = 0; s < CS; s++) {
            float r0 = (ax - px[s]) * ix[s];
            float r1 = (ay - py[s]) * iy[s];
            float v0 = fmaxf(kx.x + r0 * g0.x + r1 * g1.x + gb.x, 0.f);
            float v1 = fmaxf(kx.y + r0 * g0.y + r1 * g1.y + gb.y, 0.f);
            float v2 = fmaxf(kx.z + r0 * g0.z + r1 * g1.z + gb.z, 0.f);
            float v3 = fmaxf(kx.w + r0 * g0.w + r1 * g1.w + gb.w, 0.f);
            float d = v0 * qwv[s].x + v1 * qwv[s].y + v2 * qwv[s].z + v3 * qwv[s].w;
            #pragma unroll
            for (int off = 32; off > 0; off >>= 1) d += __shfl_down(d, off, 64);
            dsv[s] = 0.0625f * (d + q0[s]);
        }
        if (l == 0 && n < CN) {
            float mx = -1e30f;
            #pragma unroll
            for (int s = 0; s < CS; s++) mx = fmaxf(mx, dsv[s]);
            float sum = 0.f;
            #pragma unroll
            for (int s = 0; s < CS; s++) { dsv[s] = __expf(dsv[s] - mx); sum += dsv[s]; }
            float inv = 1.f / sum;
            #pragma unroll
            for (int s = 0; s < CS; s++)
                attn[(size_t)(b * CS + s) * CN + n] = dsv[s] * inv + ATTN_EPS;
        }
    }
}

// Wacc[bs][k] += sum_n attn[bs,n] * relu(VX[b,n,k] + r0*G2[0][k] + r1*G2[1][k] + gb1[k])
__global__ __launch_bounds__(256) void vsum_kernel(const float* __restrict__ VXW1,
        const float* __restrict__ S_p, const float* __restrict__ S_s,
        const float* __restrict__ G2, const float* __restrict__ gb1,
        const float* __restrict__ attn, float* __restrict__ Wacc) {
    __shared__ float sred[4 * CD];
    int b = blockIdx.x;
    int w = threadIdx.x >> 6, l = threadIdx.x & 63;
    int k4 = l * 4;
    float4 g0 = *(const float4*)(G2 + k4);
    float4 g1 = *(const float4*)(G2 + CD + k4);
    float4 gb = *(const float4*)(gb1 + k4);
    float px[CS], py[CS], ix[CS], iy[CS];
    #pragma unroll
    for (int s = 0; s < CS; s++) {
        int bs = b * CS + s;
        px[s] = S_p[2 * bs]; py[s] = S_p[2 * bs + 1];
        ix[s] = 1.f / (S_s[2 * bs] * CSIGMA); iy[s] = 1.f / (S_s[2 * bs + 1] * CSIGMA);
    }
    float4 acc[CS];
    #pragma unroll
    for (int s = 0; s < CS; s++) acc[s] = make_float4(0.f, 0.f, 0.f, 0.f);
    int nbase = blockIdx.y * 32 + w * 8;
    #pragma unroll 2
    for (int i = 0; i < 8; i++) {
        int n = nbase + i;
        int nc = n < CN ? n : CN - 1;
        float4 vx = *(const float4*)(VXW1 + (size_t)(b * CN + nc) * CKV + k4);
        float ax = ag_x(nc), ay = ag_y(nc);
        #pragma unroll
        for (int s = 0; s < CS; s++) {
            float r0 = (ax - px[s]) * ix[s];
            float r1 = (ay - py[s]) * iy[s];
            float a = (n < CN) ? attn[(size_t)(b * CS + s) * CN + n] : 0.f;
            acc[s].x += a * fmaxf(vx.x + r0 * g0.x + r1 * g1.x + gb.x, 0.f);
            acc[s].y += a * fmaxf(vx.y + r0 * g0.y + r1 * g1.y + gb.y, 0.f);
            acc[s].z += a * fmaxf(vx.z + r0 * g0.z + r1 * g1.z + gb.z, 0.f);
            acc[s].w += a * fmaxf(vx.w + r0 * g0.w + r1 * g1.w + gb.w, 0.f);
        }
    }
    for (int s = 0; s < CS; s++) {
        ((float4*)sred)[w * 64 + l] = acc[s];
        __syncthreads();
        if (threadIdx.x < CD) {
            float v = sred[threadIdx.x] + sred[CD + threadIdx.x]
                    + sred[2 * CD + threadIdx.x] + sred[3 * CD + threadIdx.x];
            atomicAdd(&Wacc[(size_t)(b * CS + s) * CD + threadIdx.x], v);
        }
        __syncthreads();
    }
}

__global__ __launch_bounds__(256) void attn_moments_kernel(float* __restrict__ u,
        float* __restrict__ S_p, float* __restrict__ S_s) {
    __shared__ float sbuf[8];
    int bs = blockIdx.x;
    float* up = u + (size_t)bs * CN;
    float m0 = 0, m1x = 0, m1y = 0, m2x = 0, m2y = 0;
    for (int n = threadIdx.x; n < CN; n += 256) {
        float uu = up[n];
        float ax = ag_x(n), ay = ag_y(n);
        m0 += uu; m1x += uu * ax; m1y += uu * ay; m2x += uu * ax * ax; m2y += uu * ay * ay;
    }
    m0  = block_reduce_sum(m0, sbuf);
    m1x = block_reduce_sum(m1x, sbuf);
    m1y = block_reduce_sum(m1y, sbuf);
    m2x = block_reduce_sum(m2x, sbuf);
    m2y = block_reduce_sum(m2y, sbuf);
    float px = m1x / m0, py = m1y / m0;
    if (threadIdx.x == 0) {
        S_p[2 * bs] = px; S_p[2 * bs + 1] = py;
        S_s[2 * bs]     = sqrtf(fmaxf(m2x / m0 - px * px, 0.f));
        S_s[2 * bs + 1] = sqrtf(fmaxf(m2y / m0 - py * py, 0.f));
    }
    float inv = 1.f / m0;
    for (int n = threadIdx.x; n < CN; n += 256) up[n] = up[n] * inv;
}

// gates + LN (biases already folded into giRaw/ghRaw)
__global__ __launch_bounds__(256) void gate_ln_kernel(const float* __restrict__ giRaw,
        const float* __restrict__ ghRaw, const float* __restrict__ slots,
        const float* __restrict__ mg, const float* __restrict__ mb,
        float* __restrict__ snewb, float* __restrict__ sMb) {
    __shared__ float sbuf[8];
    int row = blockIdx.x, t = threadIdx.x;
    float gi0 = giRaw[row * 3 * CD + t];
    float gi1 = giRaw[row * 3 * CD + CD + t];
    float gi2 = giRaw[row * 3 * CD + 2 * CD + t];
    float gh0 = ghRaw[row * 3 * CD + t];
    float gh1 = ghRaw[row * 3 * CD + CD + t];
    float gh2 = ghRaw[row * 3 * CD + 2 * CD + t];
    float r = 1.f / (1.f + expf(-(gi0 + gh0)));
    float z = 1.f / (1.f + expf(-(gi1 + gh1)));
    float nn = tanhf(gi2 + r * gh2);
    float snew = (1.f - z) * nn + z * slots[row * CD + t];
    snewb[row * CD + t] = snew;
    float mean = block_reduce_sum(snew, sbuf) / CD;
    float dv = snew - mean;
    float var = block_reduce_sum(dv * dv, sbuf) / CD;
    sMb[row * CD + t] = dv * rsqrtf(var + LNEPS) * mg[t] + mb[t];
}

// ---------------- launcher ----------------
extern "C" void kernel_launch(void* const* d_in, const int* in_sizes, int n_in,
                              void* d_out, int out_size, void* d_ws, size_t ws_size,
                              hipStream_t stream) {
    (void)in_sizes; (void)n_in; (void)out_size;
    const float* inputs       = (const float*)d_in[0];
    const float* slots_init_p = (const float*)d_in[1];
    const float* S_s0         = (const float*)d_in[2];
    const float* S_p0         = (const float*)d_in[3];
    const float* im_ln1_g = (const float*)d_in[4];
    const float* im_ln1_b = (const float*)d_in[5];
    const float* im_w1    = (const float*)d_in[6];
    const float* im_b1    = (const float*)d_in[7];
    const float* im_w2    = (const float*)d_in[8];
    const float* im_b2    = (const float*)d_in[9];
    const float* im_ln2_g = (const float*)d_in[10];
    const float* im_ln2_b = (const float*)d_in[11];
    const float* Wq  = (const float*)d_in[12];
    const float* Wk  = (const float*)d_in[13];
    const float* Wv  = (const float*)d_in[14];
    const float* g_w = (const float*)d_in[15];
    const float* g_b = (const float*)d_in[16];
    const float* f_w1 = (const float*)d_in[17];
    const float* f_b1 = (const float*)d_in[18];
    const float* f_w2 = (const float*)d_in[19];
    const float* f_b2 = (const float*)d_in[20];
    const float* ln_g = (const float*)d_in[21];
    const float* ln_b = (const float*)d_in[22];
    const float* gru_wih = (const float*)d_in[23];
    const float* gru_whh = (const float*)d_in[24];
    const float* gru_bih = (const float*)d_in[25];
    const float* gru_bhh = (const float*)d_in[26];
    const float* mlp_ln_g = (const float*)d_in[27];
    const float* mlp_ln_b = (const float*)d_in[28];
    const float* mlp_w1 = (const float*)d_in[29];
    const float* mlp_b1 = (const float*)d_in[30];
    const float* mlp_w2 = (const float*)d_in[31];
    const float* mlp_b2 = (const float*)d_in[32];
    const float* fin_w = (const float*)d_in[33];
    const float* fin_b = (const float*)d_in[34];

    char* base = (char*)d_ws;
    size_t off = 0;
    auto take = [&](size_t bytes) { void* p = base + off; off += (bytes + 255) & ~(size_t)255; return p; };

    float* R1 = (float*)take((size_t)CBN * CDIN * 4);  // xln planes -> xD | xDn planes
    float* R2 = (float*)take((size_t)CBN * CDIN * 4);  // X1 planes -> KVX
    u16* w1th = (u16*)take((size_t)CDIN * CDIN * 2);
    u16* w1tm = (u16*)take((size_t)CDIN * CDIN * 2);
    u16* w2th = (u16*)take((size_t)CDIN * CD * 2);
    u16* w2tm = (u16*)take((size_t)CDIN * CD * 2);
    float* Pk   = (float*)take((size_t)CD * CD * 4);
    float* Pv   = (float*)take((size_t)CD * CD * 4);
    u16* kvth = (u16*)take((size_t)CKV * CD * 2);      // [512][256]: PkT | PvT
    u16* kvtm = (u16*)take((size_t)CKV * CD * 2);
    float* G2b  = (float*)take((size_t)2 * CD * 4);
    float* gb1b = (float*)take((size_t)CD * 4);
    float* fw2T = (float*)take((size_t)CD * CD * 4);
    float* Pq   = (float*)take((size_t)CD * CD * 4);
    float* Pg   = (float*)take((size_t)CD * 3 * CD * 4);
    float* bgv  = (float*)take((size_t)3 * CD * 4);
    float* wqbb = (float*)take((size_t)CD * 4);
    float* qwb   = (float*)take((size_t)CBS * CD * 4);
    float* qb0b  = (float*)take((size_t)CBS * 4);
    float* Wacc  = (float*)take((size_t)CBS * CD * 4);
    float* giRaw = (float*)take((size_t)CBS * 3 * CD * 4);
    float* ghRaw = (float*)take((size_t)CBS * 3 * CD * 4);
    float* snewb = (float*)take((size_t)CBS * CD * 4);
    float* sMb   = (float*)take((size_t)CBS * CD * 4);
    float* h1b   = (float*)take((size_t)CBS * 4 * CD * 4);
    float* S_pA  = (float*)take((size_t)CBS * 2 * 4);
    float* S_sA  = (float*)take((size_t)CBS * 2 * 4);
    float* S_pB  = (float*)take((size_t)CBS * 2 * 4);
    float* S_sB  = (float*)take((size_t)CBS * 2 * 4);
    float* slots = (float*)take((size_t)CBS * CD * 4);
    if (ws_size < off) return;

    // plane/buffer aliasing (lifetimes disjoint):
    u16* xlnh = (u16*)R1;                                  // [CBN][768] planes
    u16* xlnm = xlnh + (size_t)CBN * CDIN;
    u16* X1h  = (u16*)R2;                                  // [CBN][768] planes
    u16* X1m  = X1h + (size_t)CBN * CDIN;
    float* xD = R1;                                        // [CBN][256] fp32 (xln dead)
    u16* xDnh = (u16*)(R1 + (size_t)CBN * CD);             // [CBN][256] planes
    u16* xDnm = xDnh + (size_t)CBN * CD;
    float* KVX = R2;                                       // [CBN][512] fp32 (X1 dead)

    float* out0 = (float*)d_out;            // [CBS,CD]
    float* attnb = out0 + CBS * CD;         // [CBS,CN]

    dim3 blk(256);
    const int gM_bn = (CBN + 127) / 128;    // 86
    dim3 gridBN(CB, (CN + 31) / 32);        // 8 x 43

    // ---- weight prep ----
    transpose_split2_kernel<<<dim3(CDIN/32, CDIN/32), blk, 0, stream>>>(im_w1, w1th, w1tm, CDIN, CDIN);
    transpose_split2_kernel<<<dim3(CD/32,   CDIN/32), blk, 0, stream>>>(im_w2, w2th, w2tm, CDIN, CD);
    wprodN_kernel<<<dim3(CD, 1), blk, 0, stream>>>(Wk, f_w1, Pk, CD);
    wprodN_kernel<<<dim3(CD, 1), blk, 0, stream>>>(Wv, f_w1, Pv, CD);
    transpose_split2_kernel<<<dim3(CD/32, CD/32), blk, 0, stream>>>(Pk, kvth, kvtm, CD, CD);
    transpose_split2_kernel<<<dim3(CD/32, CD/32), blk, 0, stream>>>(Pv,
        kvth + (size_t)CD * CD, kvtm + (size_t)CD * CD, CD, CD);
    g2_kernel<<<1, blk, 0, stream>>>(g_w, g_b, f_w1, f_b1, G2b, gb1b);
    transpose32_kernel<<<dim3(CD/32, CD/32), blk, 0, stream>>>(f_w2, fw2T, CD, CD);
    wprodN_kernel<<<dim3(CD, 1), blk, 0, stream>>>(Wq, fw2T, Pq, CD);
    wprodN_kernel<<<dim3(CD, 3), blk, 0, stream>>>(f_w2, gru_wih, Pg, 3 * CD);
    bg_kernel<<<3, blk, 0, stream>>>(f_b2, gru_wih, gru_bih, bgv, 3 * CD);
    wqb_kernel<<<1, blk, 0, stream>>>(Wq, f_b2, wqbb);

    // ---- initial mlp (planes end-to-end) ----
    ln_planes_kernel<<<CBN, blk, 0, stream>>>(inputs, xlnh, xlnm, im_ln1_g, im_ln1_b, CDIN);
    hgemm2<<<dim3(CDIN/128, gM_bn), blk, 0, stream>>>(xlnh, xlnm, w1th, w1tm,
        CBN, CDIN, CDIN, im_b1, 1, nullptr, X1h, X1m);
    hgemm2<<<dim3(CD/128, gM_bn), blk, 0, stream>>>(X1h, X1m, w2th, w2tm,
        CBN, CD, CDIN, im_b2, 0, xD, nullptr, nullptr);
    ln_planes_kernel<<<CBN, blk, 0, stream>>>(xD, xDnh, xDnm, im_ln2_g, im_ln2_b, CD);
    hgemm2<<<dim3(CKV/128, gM_bn), blk, 0, stream>>>(xDnh, xDnm, kvth, kvtm,
        CBN, CKV, CD, nullptr, 0, KVX, nullptr, nullptr);
    init_kernel<<<CBS, blk, 0, stream>>>(slots_init_p, S_s0, S_p0, slots, S_sA, S_pA);

    for (int t = 0; t <= CITERS; t++) {
        float* Sp_cur = (t & 1) ? S_pB : S_pA;
        float* Ss_cur = (t & 1) ? S_sB : S_sA;
        float* Sp_nxt = (t & 1) ? S_pA : S_pB;
        float* Ss_nxt = (t & 1) ? S_sA : S_sB;
        ln_slots_q_kernel<<<CBS, blk, 0, stream>>>(slots, ln_g, ln_b, wqbb, Pq, qwb, qb0b);
        dots_kernel<<<gridBN, blk, 0, stream>>>(KVX, Sp_cur, Ss_cur, G2b, gb1b, qwb, qb0b, attnb);
        attn_moments_kernel<<<CBS, blk, 0, stream>>>(attnb, Sp_nxt, Ss_nxt);
        if (t < CITERS) {
            hipMemsetAsync(Wacc, 0, (size_t)CBS * CD * sizeof(float), stream);
            vsum_kernel<<<gridBN, blk, 0, stream>>>(KVX + CD, Sp_cur, Ss_cur, G2b, gb1b, attnb, Wacc);
            rowgemmG_kernel<<<dim3(CBS, 3*CD/128, 2), dim3(128), 0, stream>>>(
                Wacc, Pg, bgv, giRaw, slots, gru_whh, gru_bhh, ghRaw, 3 * CD, CD);
            gate_ln_kernel<<<CBS, blk, 0, stream>>>(giRaw, ghRaw, slots,
                mlp_ln_g, mlp_ln_b, snewb, sMb);
            rowgemm_kernel<<<dim3(CBS, 4*CD/128), dim3(128), 0, stream>>>(sMb, mlp_w1, mlp_b1,
                h1b, 4 * CD, CD, 1, nullptr, nullptr);
            rowgemm_kernel<<<dim3(CBS, CD/128), dim3(128), 0, stream>>>(h1b, mlp_w2, nullptr,
                slots, CD, 4 * CD, 0, snewb, mlp_b2);
        }
    }
    // out0 = slots @ fin_w + fin_b
    rowgemm_kernel<<<dim3(CBS, CD/128), dim3(128), 0, stream>>>(slots, fin_w, fin_b,
        out0, CD, CD, 0, nullptr, nullptr);
}

// Round 3
// 747.470 us; speedup vs baseline: 1.3759x; 1.0527x over previous
//
#include <hip/hip_runtime.h>

// ---------------- problem constants ----------------
constexpr int CB   = 8;      // batch
constexpr int CN   = 1369;   // tokens (37*37)
constexpr int CDIN = 768;
constexpr int CS   = 7;      // slots
constexpr int CD   = 256;
constexpr int CITERS = 3;
constexpr int CRES = 37;
constexpr float CSIGMA = 5.0f;
constexpr int CBS = CB * CS;        // 56
constexpr int CBN = CB * CN;        // 10952 rows for initial mlp
constexpr int CKV = 2 * CD;         // interleaved KX|VX row stride
constexpr float LNEPS = 1e-5f;
constexpr float ATTN_EPS = 1e-8f;

typedef unsigned short u16;
typedef short bs8 __attribute__((ext_vector_type(8)));   // 8 bf16 (bit pattern in shorts)
typedef float f4 __attribute__((ext_vector_type(4)));

// ---------------- helpers ----------------
__device__ __forceinline__ float ag_x(int n) { return -1.f + (float)(n % CRES) * (2.f / 36.f); }
__device__ __forceinline__ float ag_y(int n) { return -1.f + (float)(n / CRES) * (2.f / 36.f); }

__device__ __forceinline__ u16 bf_rne(float f) {
    unsigned u = __float_as_uint(f);
    return (u16)((u + 0x7FFFu + ((u >> 16) & 1u)) >> 16);
}
__device__ __forceinline__ float bf_to_f(u16 h) { return __uint_as_float(((unsigned)h) << 16); }

__device__ __forceinline__ void split2b(float v, u16& h, u16& m) {
    h = bf_rne(v);
    m = bf_rne(v - bf_to_f(h));
}

// async global->LDS, 16B per lane (dest = wave-uniform base + lane*16)
__device__ __forceinline__ void async16(const u16* g, u16* l) {
    __builtin_amdgcn_global_load_lds(
        (const __attribute__((address_space(1))) unsigned int*)g,
        (__attribute__((address_space(3))) unsigned int*)l, 16, 0, 0);
}

// 256-thread block sum
__device__ __forceinline__ float block_reduce_sum(float v, float* sbuf) {
    #pragma unroll
    for (int off = 32; off > 0; off >>= 1) v += __shfl_down(v, off, 64);
    if ((threadIdx.x & 63) == 0) sbuf[threadIdx.x >> 6] = v;
    __syncthreads();
    if (threadIdx.x == 0) sbuf[0] = sbuf[0] + sbuf[1] + sbuf[2] + sbuf[3];
    __syncthreads();
    float r = sbuf[0];
    __syncthreads();
    return r;
}

// ---------------- layernorm -> split-2 bf16 planes ----------------
__global__ __launch_bounds__(256) void ln_planes_kernel(const float* __restrict__ in,
        u16* __restrict__ Yh, u16* __restrict__ Ym,
        const float* __restrict__ g, const float* __restrict__ b, int d) {
    __shared__ float sbuf[8];
    int row = blockIdx.x;
    const float* x = in + (size_t)row * d;
    float s = 0.f;
    for (int i = threadIdx.x; i < d; i += 256) s += x[i];
    float mean = block_reduce_sum(s, sbuf) / d;
    float v = 0.f;
    for (int i = threadIdx.x; i < d; i += 256) { float t = x[i] - mean; v += t * t; }
    float var = block_reduce_sum(v, sbuf) / d;
    float rstd = rsqrtf(var + LNEPS);
    for (int i = threadIdx.x; i < d; i += 256) {
        float y = (x[i] - mean) * rstd * g[i] + b[i];
        u16 h, m; split2b(y, h, m);
        Yh[(size_t)row * d + i] = h;
        Ym[(size_t)row * d + i] = m;
    }
}

// ---------------- transpose fp32 W[K][N] -> 2 bf16 planes Wt[N][K] ----------------
__global__ __launch_bounds__(256) void transpose_split2_kernel(const float* __restrict__ W,
        u16* __restrict__ Th, u16* __restrict__ Tm, int K, int N) {
    __shared__ float tile[32][33];
    int nb = blockIdx.x * 32, kb = blockIdx.y * 32;
    int tx = threadIdx.x & 31, ty = threadIdx.x >> 5;   // ty 0..7
    #pragma unroll
    for (int i = 0; i < 32; i += 8)
        tile[ty + i][tx] = W[(size_t)(kb + ty + i) * N + nb + tx];
    __syncthreads();
    #pragma unroll
    for (int i = 0; i < 32; i += 8) {
        float v = tile[tx][ty + i];
        u16 h, m; split2b(v, h, m);
        size_t idx = (size_t)(nb + ty + i) * K + kb + tx;
        Th[idx] = h; Tm[idx] = m;
    }
}

// ---------------- fp32 transpose W[K][N] -> T[N][K] ----------------
__global__ __launch_bounds__(256) void transpose32_kernel(const float* __restrict__ W,
        float* __restrict__ T, int K, int N) {
    __shared__ float tile[32][33];
    int nb = blockIdx.x * 32, kb = blockIdx.y * 32;
    int tx = threadIdx.x & 31, ty = threadIdx.x >> 5;
    #pragma unroll
    for (int i = 0; i < 32; i += 8)
        tile[ty + i][tx] = W[(size_t)(kb + ty + i) * N + nb + tx];
    __syncthreads();
    #pragma unroll
    for (int i = 0; i < 32; i += 8)
        T[(size_t)(nb + ty + i) * K + kb + tx] = tile[tx][ty + i];
}

// ---------------- P[k][n] = sum_j A[k][j]*B[j][n], A [256][256], B [256][N] ----------------
__global__ __launch_bounds__(256) void wprodN_kernel(const float* __restrict__ A,
        const float* __restrict__ B, float* __restrict__ P, int N) {
    __shared__ float arow[CD];
    int k = blockIdx.x;
    arow[threadIdx.x] = A[k * CD + threadIdx.x];
    __syncthreads();
    int n = blockIdx.y * 256 + threadIdx.x;
    if (n >= N) return;
    float acc = 0.f;
    for (int j = 0; j < CD; j++) acc += arow[j] * B[(size_t)j * N + n];
    P[(size_t)k * N + n] = acc;
}

// G2[g][n] = sum_j g_w[g][j]*f_w1[j][n];  gb1[n] = sum_j g_b[j]*f_w1[j][n] + f_b1[n]
__global__ __launch_bounds__(256) void g2_kernel(const float* __restrict__ g_w,
        const float* __restrict__ g_b, const float* __restrict__ f_w1,
        const float* __restrict__ f_b1, float* __restrict__ G2, float* __restrict__ gb1) {
    int n = threadIdx.x;
    float a0 = 0.f, a1 = 0.f, ab = 0.f;
    for (int j = 0; j < CD; j++) {
        float w = f_w1[j * CD + n];
        a0 += g_w[j] * w;
        a1 += g_w[CD + j] * w;
        ab += g_b[j] * w;
    }
    G2[n] = a0; G2[CD + n] = a1; gb1[n] = ab + f_b1[n];
}

// bg[n] = sum_c f_b2[c]*wih[c][n] + bih[n]   (N=768)
__global__ __launch_bounds__(256) void bg_kernel(const float* __restrict__ f_b2,
        const float* __restrict__ wih, const float* __restrict__ bih,
        float* __restrict__ bg, int N) {
    int n = blockIdx.x * 256 + threadIdx.x;
    if (n >= N) return;
    float s = bih[n];
    for (int c = 0; c < CD; c++) s += f_b2[c] * wih[(size_t)c * N + n];
    bg[n] = s;
}

// wqb[j] = sum_c Wq[j][c] * f_b2[c]
__global__ __launch_bounds__(256) void wqb_kernel(const float* __restrict__ Wq,
        const float* __restrict__ f_b2, float* __restrict__ wqb) {
    int j = threadIdx.x;
    float s = 0.f;
    for (int c = 0; c < CD; c++) s += Wq[j * CD + c] * f_b2[c];
    wqb[j] = s;
}

// ---------------- bf16x3 plane GEMM, global_load_lds, BM=64 x BN=128 ----------------
// A planes Ah/Am [M][K], B planes Bh/Bm [N][K]; K%32==0, N%128==0.
// Round-1 proven 2-barrier structure (stage -> barrier -> ds_read+MFMA -> barrier),
// but BM=64: 24 KB LDS, 2x the grid -> ~4 blocks/CU so inter-block TLP hides the
// per-step vmcnt drain (grid coverage was the limiter at BM=128).
// XOR chunk swizzle c' = c ^ (r&3), applied as inverse-permuted global source on the
// write side + same XOR on the ds_read side (guideline 21).
// Bijective XCD swizzle (requires nwg%8==0; all our grids satisfy): consecutive
// logical tiles (sharing A-rows) land on one XCD's L2.
__global__ __launch_bounds__(256)
void hgemm2(const u16* __restrict__ Ah, const u16* __restrict__ Am,
            const u16* __restrict__ Bh, const u16* __restrict__ Bm,
            int M, int N, int K, const float* __restrict__ bias, int relu,
            float* __restrict__ Cf, u16* __restrict__ Ch, u16* __restrict__ Cm) {
    __shared__ u16 smem[12288];   // 24 KB: Ah[0:2048) Am[2048:4096) Bh[4096:8192) Bm[8192:12288)
    const int tid = threadIdx.x;

    int bx = blockIdx.x, by = blockIdx.y;
    {
        int gx = gridDim.x;
        int nwg = gx * gridDim.y;
        if (!(nwg & 7)) {               // XCD-aware swizzle (m157/m204 bijective form)
            int bid = by * gx + bx;
            int cpx = nwg >> 3;
            int s = (bid & 7) * cpx + (bid >> 3);
            bx = s % gx; by = s / gx;
        }
    }
    const int m0 = by * 64, n0 = bx * 128;
    const int w = tid >> 6, lane = tid & 63;
    const int wm = w & 1, wn = w >> 1;
    const int l15 = lane & 15, l4 = lane >> 4;

    // 6 staging issues/thread/k-step (16B chunks): i0=Ah, i1=Am, i2/3=Bh, i4/5=Bm
    const u16* srcp[6];
    int dsto[6];
    #pragma unroll
    for (int i = 0; i < 6; i++) {
        const u16* bp; int row, r, c;
        if (i < 2) {                       // A planes: 64 rows x 4 chunks = 256
            int qq = tid;
            r = qq >> 2;
            c = (qq & 3) ^ (r & 3);        // inverse swizzle on source
            bp = (i == 0) ? Ah : Am;
            row = m0 + r; row = row < M ? row : M - 1;
            dsto[i] = i * 2048 + w * 512;
        } else {                           // B planes: 128 rows x 4 chunks = 512 (2 issues)
            int ii = i - 2;                // 0..3
            int plane = ii >> 1;           // 0:Bh 1:Bm
            int qq = (ii & 1) * 256 + tid; // 0..511
            r = qq >> 2;
            c = (qq & 3) ^ (r & 3);
            bp = plane ? Bm : Bh;
            row = n0 + r;
            dsto[i] = 4096 + plane * 4096 + (ii & 1) * 2048 + w * 512;
        }
        srcp[i] = bp + (size_t)row * K + c * 8;
    }

    f4 acc[2][4];
    #pragma unroll
    for (int i = 0; i < 2; i++)
        #pragma unroll
        for (int j = 0; j < 4; j++) acc[i][j] = (f4){0.f, 0.f, 0.f, 0.f};

    const int cx8 = (l4 ^ (l15 & 3)) * 8;     // swizzled k-chunk for fragment reads

    for (int k0 = 0; k0 < K; k0 += 32) {
        #pragma unroll
        for (int i = 0; i < 6; i++) async16(srcp[i] + k0, smem + dsto[i]);
        __syncthreads();
        bs8 ah[2], am[2], bh[4], bm[4];
        #pragma unroll
        for (int f = 0; f < 2; f++) {
            int oa = (wm * 32 + f * 16 + l15) * 32 + cx8;
            ah[f] = *(const bs8*)(smem + oa);
            am[f] = *(const bs8*)(smem + 2048 + oa);
        }
        #pragma unroll
        for (int f = 0; f < 4; f++) {
            int ob = (wn * 64 + f * 16 + l15) * 32 + cx8;
            bh[f] = *(const bs8*)(smem + 4096 + ob);
            bm[f] = *(const bs8*)(smem + 8192 + ob);
        }
        #pragma unroll
        for (int mf = 0; mf < 2; mf++)
            #pragma unroll
            for (int nf = 0; nf < 4; nf++) {
                acc[mf][nf] = __builtin_amdgcn_mfma_f32_16x16x32_bf16(am[mf], bh[nf], acc[mf][nf], 0, 0, 0);
                acc[mf][nf] = __builtin_amdgcn_mfma_f32_16x16x32_bf16(ah[mf], bm[nf], acc[mf][nf], 0, 0, 0);
                acc[mf][nf] = __builtin_amdgcn_mfma_f32_16x16x32_bf16(ah[mf], bh[nf], acc[mf][nf], 0, 0, 0);
            }
        __syncthreads();
    }

    #pragma unroll
    for (int mf = 0; mf < 2; mf++)
        #pragma unroll
        for (int i = 0; i < 4; i++) {
            int grow = m0 + wm * 32 + mf * 16 + l4 * 4 + i;
            if (grow < M) {
                #pragma unroll
                for (int nf = 0; nf < 4; nf++) {
                    int col = n0 + wn * 64 + nf * 16 + l15;
                    float v = acc[mf][nf][i] + (bias ? bias[col] : 0.f);
                    if (relu) v = fmaxf(v, 0.f);
                    if (Cf) Cf[(size_t)grow * N + col] = v;
                    else {
                        u16 h, m; split2b(v, h, m);
                        Ch[(size_t)grow * N + col] = h;
                        Cm[(size_t)grow * N + col] = m;
                    }
                }
            }
        }
}

// ---------------- thin fp32 row-GEMV ----------------
__global__ __launch_bounds__(128) void rowgemm_kernel(const float* __restrict__ A,
        const float* __restrict__ W, const float* __restrict__ bias,
        float* __restrict__ C, int N, int K, int relu,
        const float* __restrict__ resid, const float* __restrict__ resb) {
    __shared__ float sA[1024];
    int r = blockIdx.x;
    int c = blockIdx.y * 128 + threadIdx.x;
    for (int i = threadIdx.x; i < K; i += 128) sA[i] = A[(size_t)r * K + i];
    __syncthreads();
    float a0 = 0.f, a1 = 0.f, a2 = 0.f, a3 = 0.f;
    #pragma unroll 4
    for (int k = 0; k < K; k += 4) {
        a0 += sA[k]     * W[(size_t)k * N + c];
        a1 += sA[k + 1] * W[(size_t)(k + 1) * N + c];
        a2 += sA[k + 2] * W[(size_t)(k + 2) * N + c];
        a3 += sA[k + 3] * W[(size_t)(k + 3) * N + c];
    }
    float v = (a0 + a1) + (a2 + a3) + (bias ? bias[c] : 0.f);
    if (relu) v = fmaxf(v, 0.f);
    if (resid) v += resid[(size_t)r * N + c] + resb[c];
    C[(size_t)r * N + c] = v;
}

// gi/gh pair in one launch via blockIdx.z; z==0 rows scaled by sc0[r] (1/m0 fold)
__global__ __launch_bounds__(128) void rowgemmG_kernel(
        const float* __restrict__ A0, const float* __restrict__ W0,
        const float* __restrict__ b0, float* __restrict__ C0,
        const float* __restrict__ A1, const float* __restrict__ W1,
        const float* __restrict__ b1, float* __restrict__ C1,
        const float* __restrict__ sc0, int N, int K) {
    __shared__ float sA[256];
    const float* A = blockIdx.z ? A1 : A0;
    const float* W = blockIdx.z ? W1 : W0;
    const float* B = blockIdx.z ? b1 : b0;
    float* C = blockIdx.z ? C1 : C0;
    int r = blockIdx.x;
    int c = blockIdx.y * 128 + threadIdx.x;
    float scl = blockIdx.z ? 1.f : sc0[r];
    for (int i = threadIdx.x; i < K; i += 128) sA[i] = A[(size_t)r * K + i] * scl;
    __syncthreads();
    float a0 = 0.f, a1 = 0.f, a2 = 0.f, a3 = 0.f;
    #pragma unroll 4
    for (int k = 0; k < K; k += 4) {
        a0 += sA[k]     * W[(size_t)k * N + c];
        a1 += sA[k + 1] * W[(size_t)(k + 1) * N + c];
        a2 += sA[k + 2] * W[(size_t)(k + 2) * N + c];
        a3 += sA[k + 3] * W[(size_t)(k + 3) * N + c];
    }
    C[(size_t)r * N + c] = (a0 + a1) + (a2 + a3) + B[c];
}

// ---------------- small kernels ----------------
__global__ __launch_bounds__(256) void init_kernel(const float* __restrict__ slots_init_p,
        const float* __restrict__ S_s0, const float* __restrict__ S_p0,
        float* __restrict__ slots, float* __restrict__ S_s, float* __restrict__ S_p) {
    int bs = blockIdx.x, t = threadIdx.x;
    int s = bs % CS;
    slots[bs * CD + t] = slots_init_p[s * CD + t];
    if (t < 2) { S_s[bs * 2 + t] = S_s0[s * 2 + t]; S_p[bs * 2 + t] = S_p0[s * 2 + t]; }
}

// LN(slots) + qb0 + qw = sn @ Pq (fused GEMV)
__global__ __launch_bounds__(256) void ln_slots_q_kernel(const float* __restrict__ slots,
        const float* __restrict__ ln_g, const float* __restrict__ ln_b,
        const float* __restrict__ wqb, const float* __restrict__ Pq,
        float* __restrict__ qwb, float* __restrict__ qb0) {
    __shared__ float sbuf[8];
    __shared__ float sN[CD];
    int row = blockIdx.x, t = threadIdx.x;
    float x = slots[row * CD + t];
    float mean = block_reduce_sum(x, sbuf) / CD;
    float d0 = x - mean;
    float var = block_reduce_sum(d0 * d0, sbuf) / CD;
    float sn = d0 * rsqrtf(var + LNEPS) * ln_g[t] + ln_b[t];
    sN[t] = sn;
    float qb = block_reduce_sum(sn * wqb[t], sbuf);
    if (t == 0) qb0[row] = qb;
    __syncthreads();
    float acc = 0.f;
    #pragma unroll 4
    for (int k = 0; k < CD; k++) acc += sN[k] * Pq[(size_t)k * CD + t];
    qwb[row * CD + t] = acc;
}

// dots + softmax-over-slots + (optional) vsum fused.
// Softmax computed on ALL lanes via butterfly shfl_xor (bit-identical tree to the
// old shfl_down reduce on lane 0). If Wacc != null, accumulates UNNORMALIZED
// Wacc[bs][k] += attn_u * relu(VX + ...); the 1/m0 normalization is folded into
// rowgemmG's A-stage (attn_moments provides inv0).
__global__ __launch_bounds__(256) void dotsv_kernel(const float* __restrict__ KVX,
        const float* __restrict__ S_p, const float* __restrict__ S_s,
        const float* __restrict__ G2, const float* __restrict__ gb1,
        const float* __restrict__ qw, const float* __restrict__ qb0,
        float* __restrict__ attn, float* __restrict__ Wacc) {
    __shared__ float sred[4 * CD];
    int b = blockIdx.x;
    int w = threadIdx.x >> 6, l = threadIdx.x & 63;
    int k4 = l * 4;
    float4 g0 = *(const float4*)(G2 + k4);
    float4 g1 = *(const float4*)(G2 + CD + k4);
    float4 gb = *(const float4*)(gb1 + k4);
    float4 qwv[CS]; float px[CS], py[CS], ix[CS], iy[CS], q0[CS];
    #pragma unroll
    for (int s = 0; s < CS; s++) {
        int bs = b * CS + s;
        qwv[s] = *(const float4*)(qw + bs * CD + k4);
        px[s] = S_p[2 * bs]; py[s] = S_p[2 * bs + 1];
        ix[s] = 1.f / (S_s[2 * bs] * CSIGMA); iy[s] = 1.f / (S_s[2 * bs + 1] * CSIGMA);
        q0[s] = qb0[bs];
    }
    float4 acc[CS];
    #pragma unroll
    for (int s = 0; s < CS; s++) acc[s] = make_float4(0.f, 0.f, 0.f, 0.f);
    int nbase = blockIdx.y * 32 + w * 8;
    #pragma unroll 2
    for (int i = 0; i < 8; i++) {
        int n = nbase + i;
        int nc = n < CN ? n : CN - 1;
        const float* rowp = KVX + (size_t)(b * CN + nc) * CKV;
        float4 kx = *(const float4*)(rowp + k4);
        float ax = ag_x(nc), ay = ag_y(nc);
        float dsv[CS];
        #pragma unroll
        for (int s = 0; s < CS; s++) {
            float r0 = (ax - px[s]) * ix[s];
            float r1 = (ay - py[s]) * iy[s];
            float v0 = fmaxf(kx.x + r0 * g0.x + r1 * g1.x + gb.x, 0.f);
            float v1 = fmaxf(kx.y + r0 * g0.y + r1 * g1.y + gb.y, 0.f);
            float v2 = fmaxf(kx.z + r0 * g0.z + r1 * g1.z + gb.z, 0.f);
            float v3 = fmaxf(kx.w + r0 * g0.w + r1 * g1.w + gb.w, 0.f);
            float d = v0 * qwv[s].x + v1 * qwv[s].y + v2 * qwv[s].z + v3 * qwv[s].w;
            #pragma unroll
            for (int off = 32; off > 0; off >>= 1) d += __shfl_xor(d, off, 64);
            dsv[s] = 0.0625f * (d + q0[s]);
        }
        float mx = -1e30f;
        #pragma unroll
        for (int s = 0; s < CS; s++) mx = fmaxf(mx, dsv[s]);
        float sum = 0.f;
        #pragma unroll
        for (int s = 0; s < CS; s++) { dsv[s] = __expf(dsv[s] - mx); sum += dsv[s]; }
        float inv = 1.f / sum;
        #pragma unroll
        for (int s = 0; s < CS; s++) dsv[s] = dsv[s] * inv + ATTN_EPS;
        if (l == 0 && n < CN) {
            #pragma unroll
            for (int s = 0; s < CS; s++)
                attn[(size_t)(b * CS + s) * CN + n] = dsv[s];
        }
        if (Wacc && n < CN) {
            float4 vx = *(const float4*)(rowp + CD + k4);
            #pragma unroll
            for (int s = 0; s < CS; s++) {
                float r0 = (ax - px[s]) * ix[s];
                float r1 = (ay - py[s]) * iy[s];
                float a = dsv[s];
                acc[s].x += a * fmaxf(vx.x + r0 * g0.x + r1 * g1.x + gb.x, 0.f);
                acc[s].y += a * fmaxf(vx.y + r0 * g0.y + r1 * g1.y + gb.y, 0.f);
                acc[s].z += a * fmaxf(vx.z + r0 * g0.z + r1 * g1.z + gb.z, 0.f);
                acc[s].w += a * fmaxf(vx.w + r0 * g0.w + r1 * g1.w + gb.w, 0.f);
            }
        }
    }
    if (Wacc) {
        for (int s = 0; s < CS; s++) {
            ((float4*)sred)[w * 64 + l] = acc[s];
            __syncthreads();
            if (threadIdx.x < CD) {
                float v = sred[threadIdx.x] + sred[CD + threadIdx.x]
                        + sred[2 * CD + threadIdx.x] + sred[3 * CD + threadIdx.x];
                atomicAdd(&Wacc[(size_t)(b * CS + s) * CD + threadIdx.x], v);
            }
            __syncthreads();
        }
    }
}

__global__ __launch_bounds__(256) void attn_moments_kernel(float* __restrict__ u,
        float* __restrict__ S_p, float* __restrict__ S_s, float* __restrict__ inv0) {
    __shared__ float sbuf[8];
    int bs = blockIdx.x;
    float* up = u + (size_t)bs * CN;
    float m0 = 0, m1x = 0, m1y = 0, m2x = 0, m2y = 0;
    for (int n = threadIdx.x; n < CN; n += 256) {
        float uu = up[n];
        float ax = ag_x(n), ay = ag_y(n);
        m0 += uu; m1x += uu * ax; m1y += uu * ay; m2x += uu * ax * ax; m2y += uu * ay * ay;
    }
    m0  = block_reduce_sum(m0, sbuf);
    m1x = block_reduce_sum(m1x, sbuf);
    m1y = block_reduce_sum(m1y, sbuf);
    m2x = block_reduce_sum(m2x, sbuf);
    m2y = block_reduce_sum(m2y, sbuf);
    float px = m1x / m0, py = m1y / m0;
    float inv = 1.f / m0;
    if (threadIdx.x == 0) {
        S_p[2 * bs] = px; S_p[2 * bs + 1] = py;
        S_s[2 * bs]     = sqrtf(fmaxf(m2x / m0 - px * px, 0.f));
        S_s[2 * bs + 1] = sqrtf(fmaxf(m2y / m0 - py * py, 0.f));
        inv0[bs] = inv;
    }
    for (int n = threadIdx.x; n < CN; n += 256) up[n] = up[n] * inv;
}

// gates + LN (biases already folded into giRaw/ghRaw)
__global__ __launch_bounds__(256) void gate_ln_kernel(const float* __restrict__ giRaw,
        const float* __restrict__ ghRaw, const float* __restrict__ slots,
        const float* __restrict__ mg, const float* __restrict__ mb,
        float* __restrict__ snewb, float* __restrict__ sMb) {
    __shared__ float sbuf[8];
    int row = blockIdx.x, t = threadIdx.x;
    float gi0 = giRaw[row * 3 * CD + t];
    float gi1 = giRaw[row * 3 * CD + CD + t];
    float gi2 = giRaw[row * 3 * CD + 2 * CD + t];
    float gh0 = ghRaw[row * 3 * CD + t];
    float gh1 = ghRaw[row * 3 * CD + CD + t];
    float gh2 = ghRaw[row * 3 * CD + 2 * CD + t];
    float r = 1.f / (1.f + expf(-(gi0 + gh0)));
    float z = 1.f / (1.f + expf(-(gi1 + gh1)));
    float nn = tanhf(gi2 + r * gh2);
    float snew = (1.f - z) * nn + z * slots[row * CD + t];
    snewb[row * CD + t] = snew;
    float mean = block_reduce_sum(snew, sbuf) / CD;
    float dv = snew - mean;
    float var = block_reduce_sum(dv * dv, sbuf) / CD;
    sMb[row * CD + t] = dv * rsqrtf(var + LNEPS) * mg[t] + mb[t];
}

// ---------------- launcher ----------------
extern "C" void kernel_launch(void* const* d_in, const int* in_sizes, int n_in,
                              void* d_out, int out_size, void* d_ws, size_t ws_size,
                              hipStream_t stream) {
    (void)in_sizes; (void)n_in; (void)out_size;
    const float* inputs       = (const float*)d_in[0];
    const float* slots_init_p = (const float*)d_in[1];
    const float* S_s0         = (const float*)d_in[2];
    const float* S_p0         = (const float*)d_in[3];
    const float* im_ln1_g = (const float*)d_in[4];
    const float* im_ln1_b = (const float*)d_in[5];
    const float* im_w1    = (const float*)d_in[6];
    const float* im_b1    = (const float*)d_in[7];
    const float* im_w2    = (const float*)d_in[8];
    const float* im_b2    = (const float*)d_in[9];
    const float* im_ln2_g = (const float*)d_in[10];
    const float* im_ln2_b = (const float*)d_in[11];
    const float* Wq  = (const float*)d_in[12];
    const float* Wk  = (const float*)d_in[13];
    const float* Wv  = (const float*)d_in[14];
    const float* g_w = (const float*)d_in[15];
    const float* g_b = (const float*)d_in[16];
    const float* f_w1 = (const float*)d_in[17];
    const float* f_b1 = (const float*)d_in[18];
    const float* f_w2 = (const float*)d_in[19];
    const float* f_b2 = (const float*)d_in[20];
    const float* ln_g = (const float*)d_in[21];
    const float* ln_b = (const float*)d_in[22];
    const float* gru_wih = (const float*)d_in[23];
    const float* gru_whh = (const float*)d_in[24];
    const float* gru_bih = (const float*)d_in[25];
    const float* gru_bhh = (const float*)d_in[26];
    const float* mlp_ln_g = (const float*)d_in[27];
    const float* mlp_ln_b = (const float*)d_in[28];
    const float* mlp_w1 = (const float*)d_in[29];
    const float* mlp_b1 = (const float*)d_in[30];
    const float* mlp_w2 = (const float*)d_in[31];
    const float* mlp_b2 = (const float*)d_in[32];
    const float* fin_w = (const float*)d_in[33];
    const float* fin_b = (const float*)d_in[34];

    char* base = (char*)d_ws;
    size_t off = 0;
    auto take = [&](size_t bytes) { void* p = base + off; off += (bytes + 255) & ~(size_t)255; return p; };

    float* R1 = (float*)take((size_t)CBN * CDIN * 4);  // xln planes -> xD | xDn planes
    float* R2 = (float*)take((size_t)CBN * CDIN * 4);  // X1 planes -> KVX
    u16* w1th = (u16*)take((size_t)CDIN * CDIN * 2);
    u16* w1tm = (u16*)take((size_t)CDIN * CDIN * 2);
    u16* w2th = (u16*)take((size_t)CDIN * CD * 2);
    u16* w2tm = (u16*)take((size_t)CDIN * CD * 2);
    float* Pk   = (float*)take((size_t)CD * CD * 4);
    float* Pv   = (float*)take((size_t)CD * CD * 4);
    u16* kvth = (u16*)take((size_t)CKV * CD * 2);      // [512][256]: PkT | PvT
    u16* kvtm = (u16*)take((size_t)CKV * CD * 2);
    float* G2b  = (float*)take((size_t)2 * CD * 4);
    float* gb1b = (float*)take((size_t)CD * 4);
    float* fw2T = (float*)take((size_t)CD * CD * 4);
    float* Pq   = (float*)take((size_t)CD * CD * 4);
    float* Pg   = (float*)take((size_t)CD * 3 * CD * 4);
    float* bgv  = (float*)take((size_t)3 * CD * 4);
    float* wqbb = (float*)take((size_t)CD * 4);
    float* qwb   = (float*)take((size_t)CBS * CD * 4);
    float* qb0b  = (float*)take((size_t)CBS * 4);
    float* inv0b = (float*)take((size_t)CBS * 4);
    float* Wacc  = (float*)take((size_t)CBS * CD * 4);
    float* giRaw = (float*)take((size_t)CBS * 3 * CD * 4);
    float* ghRaw = (float*)take((size_t)CBS * 3 * CD * 4);
    float* snewb = (float*)take((size_t)CBS * CD * 4);
    float* sMb   = (float*)take((size_t)CBS * CD * 4);
    float* h1b   = (float*)take((size_t)CBS * 4 * CD * 4);
    float* S_pA  = (float*)take((size_t)CBS * 2 * 4);
    float* S_sA  = (float*)take((size_t)CBS * 2 * 4);
    float* S_pB  = (float*)take((size_t)CBS * 2 * 4);
    float* S_sB  = (float*)take((size_t)CBS * 2 * 4);
    float* slots = (float*)take((size_t)CBS * CD * 4);
    if (ws_size < off) return;

    // plane/buffer aliasing (lifetimes disjoint):
    u16* xlnh = (u16*)R1;                                  // [CBN][768] planes
    u16* xlnm = xlnh + (size_t)CBN * CDIN;
    u16* X1h  = (u16*)R2;                                  // [CBN][768] planes
    u16* X1m  = X1h + (size_t)CBN * CDIN;
    float* xD = R1;                                        // [CBN][256] fp32 (xln dead)
    u16* xDnh = (u16*)(R1 + (size_t)CBN * CD);             // [CBN][256] planes
    u16* xDnm = xDnh + (size_t)CBN * CD;
    float* KVX = R2;                                       // [CBN][512] fp32 (X1 dead)

    float* out0 = (float*)d_out;            // [CBS,CD]
    float* attnb = out0 + CBS * CD;         // [CBS,CN]

    dim3 blk(256);
    const int gM = (CBN + 63) / 64;         // 172 M-tiles (BM=64)
    dim3 gridBN(CB, (CN + 31) / 32);        // 8 x 43

    // ---- weight prep ----
    transpose_split2_kernel<<<dim3(CDIN/32, CDIN/32), blk, 0, stream>>>(im_w1, w1th, w1tm, CDIN, CDIN);
    transpose_split2_kernel<<<dim3(CD/32,   CDIN/32), blk, 0, stream>>>(im_w2, w2th, w2tm, CDIN, CD);
    wprodN_kernel<<<dim3(CD, 1), blk, 0, stream>>>(Wk, f_w1, Pk, CD);
    wprodN_kernel<<<dim3(CD, 1), blk, 0, stream>>>(Wv, f_w1, Pv, CD);
    transpose_split2_kernel<<<dim3(CD/32, CD/32), blk, 0, stream>>>(Pk, kvth, kvtm, CD, CD);
    transpose_split2_kernel<<<dim3(CD/32, CD/32), blk, 0, stream>>>(Pv,
        kvth + (size_t)CD * CD, kvtm + (size_t)CD * CD, CD, CD);
    g2_kernel<<<1, blk, 0, stream>>>(g_w, g_b, f_w1, f_b1, G2b, gb1b);
    transpose32_kernel<<<dim3(CD/32, CD/32), blk, 0, stream>>>(f_w2, fw2T, CD, CD);
    wprodN_kernel<<<dim3(CD, 1), blk, 0, stream>>>(Wq, fw2T, Pq, CD);
    wprodN_kernel<<<dim3(CD, 3), blk, 0, stream>>>(f_w2, gru_wih, Pg, 3 * CD);
    bg_kernel<<<3, blk, 0, stream>>>(f_b2, gru_wih, gru_bih, bgv, 3 * CD);
    wqb_kernel<<<1, blk, 0, stream>>>(Wq, f_b2, wqbb);

    // ---- initial mlp (planes end-to-end) ----
    ln_planes_kernel<<<CBN, blk, 0, stream>>>(inputs, xlnh, xlnm, im_ln1_g, im_ln1_b, CDIN);
    hgemm2<<<dim3(CDIN/128, gM), blk, 0, stream>>>(xlnh, xlnm, w1th, w1tm,
        CBN, CDIN, CDIN, im_b1, 1, nullptr, X1h, X1m);
    hgemm2<<<dim3(CD/128, gM), blk, 0, stream>>>(X1h, X1m, w2th, w2tm,
        CBN, CD, CDIN, im_b2, 0, xD, nullptr, nullptr);
    ln_planes_kernel<<<CBN, blk, 0, stream>>>(xD, xDnh, xDnm, im_ln2_g, im_ln2_b, CD);
    hgemm2<<<dim3(CKV/128, gM), blk, 0, stream>>>(xDnh, xDnm, kvth, kvtm,
        CBN, CKV, CD, nullptr, 0, KVX, nullptr, nullptr);
    init_kernel<<<CBS, blk, 0, stream>>>(slots_init_p, S_s0, S_p0, slots, S_sA, S_pA);

    for (int t = 0; t <= CITERS; t++) {
        float* Sp_cur = (t & 1) ? S_pB : S_pA;
        float* Ss_cur = (t & 1) ? S_sB : S_sA;
        float* Sp_nxt = (t & 1) ? S_pA : S_pB;
        float* Ss_nxt = (t & 1) ? S_sA : S_sB;
        ln_slots_q_kernel<<<CBS, blk, 0, stream>>>(slots, ln_g, ln_b, wqbb, Pq, qwb, qb0b);
        if (t < CITERS) {
            hipMemsetAsync(Wacc, 0, (size_t)CBS * CD * sizeof(float), stream);
            dotsv_kernel<<<gridBN, blk, 0, stream>>>(KVX, Sp_cur, Ss_cur, G2b, gb1b,
                qwb, qb0b, attnb, Wacc);
        } else {
            dotsv_kernel<<<gridBN, blk, 0, stream>>>(KVX, Sp_cur, Ss_cur, G2b, gb1b,
                qwb, qb0b, attnb, nullptr);
        }
        attn_moments_kernel<<<CBS, blk, 0, stream>>>(attnb, Sp_nxt, Ss_nxt, inv0b);
        if (t < CITERS) {
            rowgemmG_kernel<<<dim3(CBS, 3*CD/128, 2), dim3(128), 0, stream>>>(
                Wacc, Pg, bgv, giRaw, slots, gru_whh, gru_bhh, ghRaw, inv0b, 3 * CD, CD);
            gate_ln_kernel<<<CBS, blk, 0, stream>>>(giRaw, ghRaw, slots,
                mlp_ln_g, mlp_ln_b, snewb, sMb);
            rowgemm_kernel<<<dim3(CBS, 4*CD/128), dim3(128), 0, stream>>>(sMb, mlp_w1, mlp_b1,
                h1b, 4 * CD, CD, 1, nullptr, nullptr);
            rowgemm_kernel<<<dim3(CBS, CD/128), dim3(128), 0, stream>>>(h1b, mlp_w2, nullptr,
                slots, CD, 4 * CD, 0, snewb, mlp_b2);
        }
    }
    // out0 = slots @ fin_w + fin_b
    rowgemm_kernel<<<dim3(CBS, CD/128), dim3(128), 0, stream>>>(slots, fin_w, fin_b,
        out0, CD, CD, 0, nullptr, nullptr);
}

// Round 4
// 720.834 us; speedup vs baseline: 1.4267x; 1.0370x over previous
//
#include <hip/hip_runtime.h>

// ---------------- problem constants ----------------
constexpr int CB   = 8;      // batch
constexpr int CN   = 1369;   // tokens (37*37)
constexpr int CDIN = 768;
constexpr int CS   = 7;      // slots
constexpr int CD   = 256;
constexpr int CITERS = 3;
constexpr int CRES = 37;
constexpr float CSIGMA = 5.0f;
constexpr int CBS = CB * CS;        // 56
constexpr int CBN = CB * CN;        // 10952 rows for initial mlp
constexpr int CKV = 2 * CD;         // interleaved KX|VX row stride
constexpr float LNEPS = 1e-5f;
constexpr float ATTN_EPS = 1e-8f;

typedef unsigned short u16;
typedef short bs8 __attribute__((ext_vector_type(8)));   // 8 bf16 (bit pattern in shorts)
typedef float f4 __attribute__((ext_vector_type(4)));

// ---------------- helpers ----------------
__device__ __forceinline__ float ag_x(int n) { return -1.f + (float)(n % CRES) * (2.f / 36.f); }
__device__ __forceinline__ float ag_y(int n) { return -1.f + (float)(n / CRES) * (2.f / 36.f); }

__device__ __forceinline__ u16 bf_rne(float f) {
    unsigned u = __float_as_uint(f);
    return (u16)((u + 0x7FFFu + ((u >> 16) & 1u)) >> 16);
}
__device__ __forceinline__ float bf_to_f(u16 h) { return __uint_as_float(((unsigned)h) << 16); }

__device__ __forceinline__ void split2b(float v, u16& h, u16& m) {
    h = bf_rne(v);
    m = bf_rne(v - bf_to_f(h));
}

// async global->LDS, 16B per lane (dest = wave-uniform base + lane*16)
__device__ __forceinline__ void async16(const u16* g, u16* l) {
    __builtin_amdgcn_global_load_lds(
        (const __attribute__((address_space(1))) unsigned int*)g,
        (__attribute__((address_space(3))) unsigned int*)l, 16, 0, 0);
}

// 256-thread block sum
__device__ __forceinline__ float block_reduce_sum(float v, float* sbuf) {
    #pragma unroll
    for (int off = 32; off > 0; off >>= 1) v += __shfl_down(v, off, 64);
    if ((threadIdx.x & 63) == 0) sbuf[threadIdx.x >> 6] = v;
    __syncthreads();
    if (threadIdx.x == 0) sbuf[0] = sbuf[0] + sbuf[1] + sbuf[2] + sbuf[3];
    __syncthreads();
    float r = sbuf[0];
    __syncthreads();
    return r;
}

// ---------------- layernorm -> split-2 bf16 planes (single-pass, d in {256,768}) ----------------
__global__ __launch_bounds__(256) void ln_planes_kernel(const float* __restrict__ in,
        u16* __restrict__ Yh, u16* __restrict__ Ym,
        const float* __restrict__ g, const float* __restrict__ b, int d) {
    __shared__ float sbuf[8];
    int row = blockIdx.x, t = threadIdx.x;
    const float* x = in + (size_t)row * d;
    float v0 = x[t], v1 = 0.f, v2 = 0.f;
    if (d > 256) { v1 = x[t + 256]; v2 = x[t + 512]; }
    float mean = block_reduce_sum(v0 + v1 + v2, sbuf) / d;
    float d0 = v0 - mean, d1 = v1 - mean, d2 = v2 - mean;
    float pv = (d > 256) ? (d0 * d0 + d1 * d1 + d2 * d2) : (d0 * d0);
    float var = block_reduce_sum(pv, sbuf) / d;
    float rstd = rsqrtf(var + LNEPS);
    {
        float y = d0 * rstd * g[t] + b[t];
        u16 h, m; split2b(y, h, m);
        Yh[(size_t)row * d + t] = h; Ym[(size_t)row * d + t] = m;
    }
    if (d > 256) {
        float y1 = d1 * rstd * g[t + 256] + b[t + 256];
        u16 h, m; split2b(y1, h, m);
        Yh[(size_t)row * d + t + 256] = h; Ym[(size_t)row * d + t + 256] = m;
        float y2 = d2 * rstd * g[t + 512] + b[t + 512];
        split2b(y2, h, m);
        Yh[(size_t)row * d + t + 512] = h; Ym[(size_t)row * d + t + 512] = m;
    }
}

// ---------------- transpose fp32 W[K][N] -> 2 bf16 planes Wt[N][K] ----------------
__global__ __launch_bounds__(256) void transpose_split2_kernel(const float* __restrict__ W,
        u16* __restrict__ Th, u16* __restrict__ Tm, int K, int N) {
    __shared__ float tile[32][33];
    int nb = blockIdx.x * 32, kb = blockIdx.y * 32;
    int tx = threadIdx.x & 31, ty = threadIdx.x >> 5;   // ty 0..7
    #pragma unroll
    for (int i = 0; i < 32; i += 8)
        tile[ty + i][tx] = W[(size_t)(kb + ty + i) * N + nb + tx];
    __syncthreads();
    #pragma unroll
    for (int i = 0; i < 32; i += 8) {
        float v = tile[tx][ty + i];
        u16 h, m; split2b(v, h, m);
        size_t idx = (size_t)(nb + ty + i) * K + kb + tx;
        Th[idx] = h; Tm[idx] = m;
    }
}

// ---------------- fp32 transpose W[K][N] -> T[N][K] ----------------
__global__ __launch_bounds__(256) void transpose32_kernel(const float* __restrict__ W,
        float* __restrict__ T, int K, int N) {
    __shared__ float tile[32][33];
    int nb = blockIdx.x * 32, kb = blockIdx.y * 32;
    int tx = threadIdx.x & 31, ty = threadIdx.x >> 5;
    #pragma unroll
    for (int i = 0; i < 32; i += 8)
        tile[ty + i][tx] = W[(size_t)(kb + ty + i) * N + nb + tx];
    __syncthreads();
    #pragma unroll
    for (int i = 0; i < 32; i += 8)
        T[(size_t)(nb + ty + i) * K + kb + tx] = tile[tx][ty + i];
}

// ---------------- P[k][n] = sum_j A[k][j]*B[j][n], A [256][256], B [256][N] ----------------
__global__ __launch_bounds__(256) void wprodN_kernel(const float* __restrict__ A,
        const float* __restrict__ B, float* __restrict__ P, int N) {
    __shared__ float arow[CD];
    int k = blockIdx.x;
    arow[threadIdx.x] = A[k * CD + threadIdx.x];
    __syncthreads();
    int n = blockIdx.y * 256 + threadIdx.x;
    if (n >= N) return;
    float acc = 0.f;
    for (int j = 0; j < CD; j++) acc += arow[j] * B[(size_t)j * N + n];
    P[(size_t)k * N + n] = acc;
}

// G2[g][n] = sum_j g_w[g][j]*f_w1[j][n];  gb1[n] = sum_j g_b[j]*f_w1[j][n] + f_b1[n]
__global__ __launch_bounds__(256) void g2_kernel(const float* __restrict__ g_w,
        const float* __restrict__ g_b, const float* __restrict__ f_w1,
        const float* __restrict__ f_b1, float* __restrict__ G2, float* __restrict__ gb1) {
    int n = threadIdx.x;
    float a0 = 0.f, a1 = 0.f, ab = 0.f;
    for (int j = 0; j < CD; j++) {
        float w = f_w1[j * CD + n];
        a0 += g_w[j] * w;
        a1 += g_w[CD + j] * w;
        ab += g_b[j] * w;
    }
    G2[n] = a0; G2[CD + n] = a1; gb1[n] = ab + f_b1[n];
}

// bg[n] = sum_c f_b2[c]*wih[c][n] + bih[n]   (N=768)
__global__ __launch_bounds__(256) void bg_kernel(const float* __restrict__ f_b2,
        const float* __restrict__ wih, const float* __restrict__ bih,
        float* __restrict__ bg, int N) {
    int n = blockIdx.x * 256 + threadIdx.x;
    if (n >= N) return;
    float s = bih[n];
    for (int c = 0; c < CD; c++) s += f_b2[c] * wih[(size_t)c * N + n];
    bg[n] = s;
}

// wqb[j] = sum_c Wq[j][c] * f_b2[c]
__global__ __launch_bounds__(256) void wqb_kernel(const float* __restrict__ Wq,
        const float* __restrict__ f_b2, float* __restrict__ wqb) {
    int j = threadIdx.x;
    float s = 0.f;
    for (int c = 0; c < CD; c++) s += Wq[j * CD + c] * f_b2[c];
    wqb[j] = s;
}

// ---------------- bf16x3 plane GEMM, BM=64 x BN=128, counted-vmcnt 2-phase pipeline ----------------
// A planes Ah/Am [M][K], B planes Bh/Bm [N][K]; K%64==0, N%128==0.
// LDS double-buffer 2 x 24 KB. Per K-step: issue next tile's 6 global_load_lds into nxt,
// s_waitcnt vmcnt(6) (cur's 6 loads done; prefetch stays in flight - NO drain),
// raw s_barrier, ds_read cur + MFMA (reads consumed before 2nd barrier via lgkmcnt),
// raw s_barrier (all done reading cur before it's restaged). T3+T4 minimum pipeline.
// XOR chunk swizzle c' = c ^ (r&3) via inverse-permuted global source + XOR'd ds_read.
// Bijective XCD swizzle (nwg%8==0 for all our grids) for L2 panel locality.
__global__ __launch_bounds__(256)
void hgemm2(const u16* __restrict__ Ah, const u16* __restrict__ Am,
            const u16* __restrict__ Bh, const u16* __restrict__ Bm,
            int M, int N, int K, const float* __restrict__ bias, int relu,
            float* __restrict__ Cf, u16* __restrict__ Ch, u16* __restrict__ Cm) {
    __shared__ u16 smem[2][12288];   // 2 x 24 KB
    const int tid = threadIdx.x;

    int bx = blockIdx.x, by = blockIdx.y;
    {
        int gx = gridDim.x;
        int nwg = gx * gridDim.y;
        if (!(nwg & 7)) {               // XCD-aware swizzle (bijective, nwg%8==0)
            int bid = by * gx + bx;
            int cpx = nwg >> 3;
            int s = (bid & 7) * cpx + (bid >> 3);
            bx = s % gx; by = s / gx;
        }
    }
    const int m0 = by * 64, n0 = bx * 128;
    const int w = tid >> 6, lane = tid & 63;
    const int wm = w & 1, wn = w >> 1;
    const int l15 = lane & 15, l4 = lane >> 4;

    // 6 staging issues/thread/k-step (16B chunks): i0=Ah, i1=Am, i2/3=Bh, i4/5=Bm
    const u16* srcp[6];
    int dsto[6];
    #pragma unroll
    for (int i = 0; i < 6; i++) {
        const u16* bp; int row, r, c;
        if (i < 2) {                       // A planes: 64 rows x 4 chunks = 256
            int qq = tid;
            r = qq >> 2;
            c = (qq & 3) ^ (r & 3);        // inverse swizzle on source
            bp = (i == 0) ? Ah : Am;
            row = m0 + r; row = row < M ? row : M - 1;
            dsto[i] = i * 2048 + w * 512;
        } else {                           // B planes: 128 rows x 4 chunks = 512 (2 issues)
            int ii = i - 2;                // 0..3
            int plane = ii >> 1;           // 0:Bh 1:Bm
            int qq = (ii & 1) * 256 + tid; // 0..511
            r = qq >> 2;
            c = (qq & 3) ^ (r & 3);
            bp = plane ? Bm : Bh;
            row = n0 + r;
            dsto[i] = 4096 + plane * 4096 + (ii & 1) * 2048 + w * 512;
        }
        srcp[i] = bp + (size_t)row * K + c * 8;
    }

    f4 acc[2][4];
    #pragma unroll
    for (int i = 0; i < 2; i++)
        #pragma unroll
        for (int j = 0; j < 4; j++) acc[i][j] = (f4){0.f, 0.f, 0.f, 0.f};

    const int cx8 = (l4 ^ (l15 & 3)) * 8;     // swizzled k-chunk for fragment reads

    // prologue: stage tile 0 into buf0, full drain once
    #pragma unroll
    for (int i = 0; i < 6; i++) async16(srcp[i], &smem[0][dsto[i]]);
    __syncthreads();

    u16* cur = &smem[0][0];
    u16* nxt = &smem[1][0];

    for (int k0 = 0; k0 < K; k0 += 32) {
        if (k0 + 32 < K) {
            #pragma unroll
            for (int i = 0; i < 6; i++) async16(srcp[i] + k0 + 32, nxt + dsto[i]);
            asm volatile("s_waitcnt vmcnt(6)" ::: "memory");   // cur's loads done; 6 stay in flight
        } else {
            asm volatile("s_waitcnt vmcnt(0)" ::: "memory");
        }
        __builtin_amdgcn_s_barrier();        // all threads' cur loads landed
        bs8 ah[2], am[2], bh[4], bm[4];
        #pragma unroll
        for (int f = 0; f < 2; f++) {
            int oa = (wm * 32 + f * 16 + l15) * 32 + cx8;
            ah[f] = *(const bs8*)(cur + oa);
            am[f] = *(const bs8*)(cur + 2048 + oa);
        }
        #pragma unroll
        for (int f = 0; f < 4; f++) {
            int ob = (wn * 64 + f * 16 + l15) * 32 + cx8;
            bh[f] = *(const bs8*)(cur + 4096 + ob);
            bm[f] = *(const bs8*)(cur + 8192 + ob);
        }
        #pragma unroll
        for (int mf = 0; mf < 2; mf++)
            #pragma unroll
            for (int nf = 0; nf < 4; nf++) {
                acc[mf][nf] = __builtin_amdgcn_mfma_f32_16x16x32_bf16(am[mf], bh[nf], acc[mf][nf], 0, 0, 0);
                acc[mf][nf] = __builtin_amdgcn_mfma_f32_16x16x32_bf16(ah[mf], bm[nf], acc[mf][nf], 0, 0, 0);
                acc[mf][nf] = __builtin_amdgcn_mfma_f32_16x16x32_bf16(ah[mf], bh[nf], acc[mf][nf], 0, 0, 0);
            }
        asm volatile("" ::: "memory");       // keep LDS reads/issues ordered vs barrier
        __builtin_amdgcn_s_barrier();        // all done reading cur (no vmcnt drain!)
        u16* t_ = cur; cur = nxt; nxt = t_;
    }

    #pragma unroll
    for (int mf = 0; mf < 2; mf++)
        #pragma unroll
        for (int i = 0; i < 4; i++) {
            int grow = m0 + wm * 32 + mf * 16 + l4 * 4 + i;
            if (grow < M) {
                #pragma unroll
                for (int nf = 0; nf < 4; nf++) {
                    int col = n0 + wn * 64 + nf * 16 + l15;
                    float v = acc[mf][nf][i] + (bias ? bias[col] : 0.f);
                    if (relu) v = fmaxf(v, 0.f);
                    if (Cf) Cf[(size_t)grow * N + col] = v;
                    else {
                        u16 h, m; split2b(v, h, m);
                        Ch[(size_t)grow * N + col] = h;
                        Cm[(size_t)grow * N + col] = m;
                    }
                }
            }
        }
}

// ---------------- thin fp32 row-GEMV ----------------
__global__ __launch_bounds__(128) void rowgemm_kernel(const float* __restrict__ A,
        const float* __restrict__ W, const float* __restrict__ bias,
        float* __restrict__ C, int N, int K, int relu,
        const float* __restrict__ resid, const float* __restrict__ resb) {
    __shared__ float sA[1024];
    int r = blockIdx.x;
    int c = blockIdx.y * 128 + threadIdx.x;
    for (int i = threadIdx.x; i < K; i += 128) sA[i] = A[(size_t)r * K + i];
    __syncthreads();
    float a0 = 0.f, a1 = 0.f, a2 = 0.f, a3 = 0.f;
    #pragma unroll 4
    for (int k = 0; k < K; k += 4) {
        a0 += sA[k]     * W[(size_t)k * N + c];
        a1 += sA[k + 1] * W[(size_t)(k + 1) * N + c];
        a2 += sA[k + 2] * W[(size_t)(k + 2) * N + c];
        a3 += sA[k + 3] * W[(size_t)(k + 3) * N + c];
    }
    float v = (a0 + a1) + (a2 + a3) + (bias ? bias[c] : 0.f);
    if (relu) v = fmaxf(v, 0.f);
    if (resid) v += resid[(size_t)r * N + c] + resb[c];
    C[(size_t)r * N + c] = v;
}

// gi/gh pair in one launch via blockIdx.z; z==0 rows scaled by sc0[r] (1/m0 fold)
__global__ __launch_bounds__(128) void rowgemmG_kernel(
        const float* __restrict__ A0, const float* __restrict__ W0,
        const float* __restrict__ b0, float* __restrict__ C0,
        const float* __restrict__ A1, const float* __restrict__ W1,
        const float* __restrict__ b1, float* __restrict__ C1,
        const float* __restrict__ sc0, int N, int K) {
    __shared__ float sA[256];
    const float* A = blockIdx.z ? A1 : A0;
    const float* W = blockIdx.z ? W1 : W0;
    const float* B = blockIdx.z ? b1 : b0;
    float* C = blockIdx.z ? C1 : C0;
    int r = blockIdx.x;
    int c = blockIdx.y * 128 + threadIdx.x;
    float scl = blockIdx.z ? 1.f : sc0[r];
    for (int i = threadIdx.x; i < K; i += 128) sA[i] = A[(size_t)r * K + i] * scl;
    __syncthreads();
    float a0 = 0.f, a1 = 0.f, a2 = 0.f, a3 = 0.f;
    #pragma unroll 4
    for (int k = 0; k < K; k += 4) {
        a0 += sA[k]     * W[(size_t)k * N + c];
        a1 += sA[k + 1] * W[(size_t)(k + 1) * N + c];
        a2 += sA[k + 2] * W[(size_t)(k + 2) * N + c];
        a3 += sA[k + 3] * W[(size_t)(k + 3) * N + c];
    }
    C[(size_t)r * N + c] = (a0 + a1) + (a2 + a3) + B[c];
}

// ---------------- small kernels ----------------
__global__ __launch_bounds__(256) void init_kernel(const float* __restrict__ slots_init_p,
        const float* __restrict__ S_s0, const float* __restrict__ S_p0,
        float* __restrict__ slots, float* __restrict__ S_s, float* __restrict__ S_p) {
    int bs = blockIdx.x, t = threadIdx.x;
    int s = bs % CS;
    slots[bs * CD + t] = slots_init_p[s * CD + t];
    if (t < 2) { S_s[bs * 2 + t] = S_s0[s * 2 + t]; S_p[bs * 2 + t] = S_p0[s * 2 + t]; }
}

// LN(slots) + qb0 + qw = sn @ Pq (fused GEMV)
__global__ __launch_bounds__(256) void ln_slots_q_kernel(const float* __restrict__ slots,
        const float* __restrict__ ln_g, const float* __restrict__ ln_b,
        const float* __restrict__ wqb, const float* __restrict__ Pq,
        float* __restrict__ qwb, float* __restrict__ qb0) {
    __shared__ float sbuf[8];
    __shared__ float sN[CD];
    int row = blockIdx.x, t = threadIdx.x;
    float x = slots[row * CD + t];
    float mean = block_reduce_sum(x, sbuf) / CD;
    float d0 = x - mean;
    float var = block_reduce_sum(d0 * d0, sbuf) / CD;
    float sn = d0 * rsqrtf(var + LNEPS) * ln_g[t] + ln_b[t];
    sN[t] = sn;
    float qb = block_reduce_sum(sn * wqb[t], sbuf);
    if (t == 0) qb0[row] = qb;
    __syncthreads();
    float acc = 0.f;
    #pragma unroll 4
    for (int k = 0; k < CD; k++) acc += sN[k] * Pq[(size_t)k * CD + t];
    qwb[row * CD + t] = acc;
}

// dots + softmax-over-slots + (optional) vsum fused.
__global__ __launch_bounds__(256) void dotsv_kernel(const float* __restrict__ KVX,
        const float* __restrict__ S_p, const float* __restrict__ S_s,
        const float* __restrict__ G2, const float* __restrict__ gb1,
        const float* __restrict__ qw, const float* __restrict__ qb0,
        float* __restrict__ attn, float* __restrict__ Wacc) {
    __shared__ float sred[4 * CD];
    int b = blockIdx.x;
    int w = threadIdx.x >> 6, l = threadIdx.x & 63;
    int k4 = l * 4;
    float4 g0 = *(const float4*)(G2 + k4);
    float4 g1 = *(const float4*)(G2 + CD + k4);
    float4 gb = *(const float4*)(gb1 + k4);
    float4 qwv[CS]; float px[CS], py[CS], ix[CS], iy[CS], q0[CS];
    #pragma unroll
    for (int s = 0; s < CS; s++) {
        int bs = b * CS + s;
        qwv[s] = *(const float4*)(qw + bs * CD + k4);
        px[s] = S_p[2 * bs]; py[s] = S_p[2 * bs + 1];
        ix[s] = 1.f / (S_s[2 * bs] * CSIGMA); iy[s] = 1.f / (S_s[2 * bs + 1] * CSIGMA);
        q0[s] = qb0[bs];
    }
    float4 acc[CS];
    #pragma unroll
    for (int s = 0; s < CS; s++) acc[s] = make_float4(0.f, 0.f, 0.f, 0.f);
    int nbase = blockIdx.y * 32 + w * 8;
    #pragma unroll 2
    for (int i = 0; i < 8; i++) {
        int n = nbase + i;
        int nc = n < CN ? n : CN - 1;
        const float* rowp = KVX + (size_t)(b * CN + nc) * CKV;
        float4 kx = *(const float4*)(rowp + k4);
        float ax = ag_x(nc), ay = ag_y(nc);
        float dsv[CS];
        #pragma unroll
        for (int s = 0; s < CS; s++) {
            float r0 = (ax - px[s]) * ix[s];
            float r1 = (ay - py[s]) * iy[s];
            float v0 = fmaxf(kx.x + r0 * g0.x + r1 * g1.x + gb.x, 0.f);
            float v1 = fmaxf(kx.y + r0 * g0.y + r1 * g1.y + gb.y, 0.f);
            float v2 = fmaxf(kx.z + r0 * g0.z + r1 * g1.z + gb.z, 0.f);
            float v3 = fmaxf(kx.w + r0 * g0.w + r1 * g1.w + gb.w, 0.f);
            float d = v0 * qwv[s].x + v1 * qwv[s].y + v2 * qwv[s].z + v3 * qwv[s].w;
            #pragma unroll
            for (int off = 32; off > 0; off >>= 1) d += __shfl_xor(d, off, 64);
            dsv[s] = 0.0625f * (d + q0[s]);
        }
        float mx = -1e30f;
        #pragma unroll
        for (int s = 0; s < CS; s++) mx = fmaxf(mx, dsv[s]);
        float sum = 0.f;
        #pragma unroll
        for (int s = 0; s < CS; s++) { dsv[s] = __expf(dsv[s] - mx); sum += dsv[s]; }
        float inv = 1.f / sum;
        #pragma unroll
        for (int s = 0; s < CS; s++) dsv[s] = dsv[s] * inv + ATTN_EPS;
        if (l == 0 && n < CN) {
            #pragma unroll
            for (int s = 0; s < CS; s++)
                attn[(size_t)(b * CS + s) * CN + n] = dsv[s];
        }
        if (Wacc && n < CN) {
            float4 vx = *(const float4*)(rowp + CD + k4);
            #pragma unroll
            for (int s = 0; s < CS; s++) {
                float r0 = (ax - px[s]) * ix[s];
                float r1 = (ay - py[s]) * iy[s];
                float a = dsv[s];
                acc[s].x += a * fmaxf(vx.x + r0 * g0.x + r1 * g1.x + gb.x, 0.f);
                acc[s].y += a * fmaxf(vx.y + r0 * g0.y + r1 * g1.y + gb.y, 0.f);
                acc[s].z += a * fmaxf(vx.z + r0 * g0.z + r1 * g1.z + gb.z, 0.f);
                acc[s].w += a * fmaxf(vx.w + r0 * g0.w + r1 * g1.w + gb.w, 0.f);
            }
        }
    }
    if (Wacc) {
        for (int s = 0; s < CS; s++) {
            ((float4*)sred)[w * 64 + l] = acc[s];
            __syncthreads();
            if (threadIdx.x < CD) {
                float v = sred[threadIdx.x] + sred[CD + threadIdx.x]
                        + sred[2 * CD + threadIdx.x] + sred[3 * CD + threadIdx.x];
                atomicAdd(&Wacc[(size_t)(b * CS + s) * CD + threadIdx.x], v);
            }
            __syncthreads();
        }
    }
}

// moments; normalized-attn writeback only when writeNorm (final iter - intermediate
// attn buffers are fully overwritten by the next dotsv)
__global__ __launch_bounds__(256) void attn_moments_kernel(float* __restrict__ u,
        float* __restrict__ S_p, float* __restrict__ S_s, float* __restrict__ inv0,
        int writeNorm) {
    __shared__ float sbuf[8];
    int bs = blockIdx.x;
    float* up = u + (size_t)bs * CN;
    float m0 = 0, m1x = 0, m1y = 0, m2x = 0, m2y = 0;
    for (int n = threadIdx.x; n < CN; n += 256) {
        float uu = up[n];
        float ax = ag_x(n), ay = ag_y(n);
        m0 += uu; m1x += uu * ax; m1y += uu * ay; m2x += uu * ax * ax; m2y += uu * ay * ay;
    }
    m0  = block_reduce_sum(m0, sbuf);
    m1x = block_reduce_sum(m1x, sbuf);
    m1y = block_reduce_sum(m1y, sbuf);
    m2x = block_reduce_sum(m2x, sbuf);
    m2y = block_reduce_sum(m2y, sbuf);
    float px = m1x / m0, py = m1y / m0;
    float inv = 1.f / m0;
    if (threadIdx.x == 0) {
        S_p[2 * bs] = px; S_p[2 * bs + 1] = py;
        S_s[2 * bs]     = sqrtf(fmaxf(m2x / m0 - px * px, 0.f));
        S_s[2 * bs + 1] = sqrtf(fmaxf(m2y / m0 - py * py, 0.f));
        inv0[bs] = inv;
    }
    if (writeNorm)
        for (int n = threadIdx.x; n < CN; n += 256) up[n] = up[n] * inv;
}

// gates + LN (biases already folded into giRaw/ghRaw)
__global__ __launch_bounds__(256) void gate_ln_kernel(const float* __restrict__ giRaw,
        const float* __restrict__ ghRaw, const float* __restrict__ slots,
        const float* __restrict__ mg, const float* __restrict__ mb,
        float* __restrict__ snewb, float* __restrict__ sMb) {
    __shared__ float sbuf[8];
    int row = blockIdx.x, t = threadIdx.x;
    float gi0 = giRaw[row * 3 * CD + t];
    float gi1 = giRaw[row * 3 * CD + CD + t];
    float gi2 = giRaw[row * 3 * CD + 2 * CD + t];
    float gh0 = ghRaw[row * 3 * CD + t];
    float gh1 = ghRaw[row * 3 * CD + CD + t];
    float gh2 = ghRaw[row * 3 * CD + 2 * CD + t];
    float r = 1.f / (1.f + expf(-(gi0 + gh0)));
    float z = 1.f / (1.f + expf(-(gi1 + gh1)));
    float nn = tanhf(gi2 + r * gh2);
    float snew = (1.f - z) * nn + z * slots[row * CD + t];
    snewb[row * CD + t] = snew;
    float mean = block_reduce_sum(snew, sbuf) / CD;
    float dv = snew - mean;
    float var = block_reduce_sum(dv * dv, sbuf) / CD;
    sMb[row * CD + t] = dv * rsqrtf(var + LNEPS) * mg[t] + mb[t];
}

// ---------------- launcher ----------------
extern "C" void kernel_launch(void* const* d_in, const int* in_sizes, int n_in,
                              void* d_out, int out_size, void* d_ws, size_t ws_size,
                              hipStream_t stream) {
    (void)in_sizes; (void)n_in; (void)out_size;
    const float* inputs       = (const float*)d_in[0];
    const float* slots_init_p = (const float*)d_in[1];
    const float* S_s0         = (const float*)d_in[2];
    const float* S_p0         = (const float*)d_in[3];
    const float* im_ln1_g = (const float*)d_in[4];
    const float* im_ln1_b = (const float*)d_in[5];
    const float* im_w1    = (const float*)d_in[6];
    const float* im_b1    = (const float*)d_in[7];
    const float* im_w2    = (const float*)d_in[8];
    const float* im_b2    = (const float*)d_in[9];
    const float* im_ln2_g = (const float*)d_in[10];
    const float* im_ln2_b = (const float*)d_in[11];
    const float* Wq  = (const float*)d_in[12];
    const float* Wk  = (const float*)d_in[13];
    const float* Wv  = (const float*)d_in[14];
    const float* g_w = (const float*)d_in[15];
    const float* g_b = (const float*)d_in[16];
    const float* f_w1 = (const float*)d_in[17];
    const float* f_b1 = (const float*)d_in[18];
    const float* f_w2 = (const float*)d_in[19];
    const float* f_b2 = (const float*)d_in[20];
    const float* ln_g = (const float*)d_in[21];
    const float* ln_b = (const float*)d_in[22];
    const float* gru_wih = (const float*)d_in[23];
    const float* gru_whh = (const float*)d_in[24];
    const float* gru_bih = (const float*)d_in[25];
    const float* gru_bhh = (const float*)d_in[26];
    const float* mlp_ln_g = (const float*)d_in[27];
    const float* mlp_ln_b = (const float*)d_in[28];
    const float* mlp_w1 = (const float*)d_in[29];
    const float* mlp_b1 = (const float*)d_in[30];
    const float* mlp_w2 = (const float*)d_in[31];
    const float* mlp_b2 = (const float*)d_in[32];
    const float* fin_w = (const float*)d_in[33];
    const float* fin_b = (const float*)d_in[34];

    char* base = (char*)d_ws;
    size_t off = 0;
    auto take = [&](size_t bytes) { void* p = base + off; off += (bytes + 255) & ~(size_t)255; return p; };

    float* R1 = (float*)take((size_t)CBN * CDIN * 4);  // xln planes -> xD | xDn planes
    float* R2 = (float*)take((size_t)CBN * CDIN * 4);  // X1 planes -> KVX
    u16* w1th = (u16*)take((size_t)CDIN * CDIN * 2);
    u16* w1tm = (u16*)take((size_t)CDIN * CDIN * 2);
    u16* w2th = (u16*)take((size_t)CDIN * CD * 2);
    u16* w2tm = (u16*)take((size_t)CDIN * CD * 2);
    float* Pk   = (float*)take((size_t)CD * CD * 4);
    float* Pv   = (float*)take((size_t)CD * CD * 4);
    u16* kvth = (u16*)take((size_t)CKV * CD * 2);      // [512][256]: PkT | PvT
    u16* kvtm = (u16*)take((size_t)CKV * CD * 2);
    float* G2b  = (float*)take((size_t)2 * CD * 4);
    float* gb1b = (float*)take((size_t)CD * 4);
    float* fw2T = (float*)take((size_t)CD * CD * 4);
    float* Pq   = (float*)take((size_t)CD * CD * 4);
    float* Pg   = (float*)take((size_t)CD * 3 * CD * 4);
    float* bgv  = (float*)take((size_t)3 * CD * 4);
    float* wqbb = (float*)take((size_t)CD * 4);
    float* qwb   = (float*)take((size_t)CBS * CD * 4);
    float* qb0b  = (float*)take((size_t)CBS * 4);
    float* inv0b = (float*)take((size_t)CBS * 4);
    float* Wacc  = (float*)take((size_t)CBS * CD * 4);
    float* giRaw = (float*)take((size_t)CBS * 3 * CD * 4);
    float* ghRaw = (float*)take((size_t)CBS * 3 * CD * 4);
    float* snewb = (float*)take((size_t)CBS * CD * 4);
    float* sMb   = (float*)take((size_t)CBS * CD * 4);
    float* h1b   = (float*)take((size_t)CBS * 4 * CD * 4);
    float* S_pA  = (float*)take((size_t)CBS * 2 * 4);
    float* S_sA  = (float*)take((size_t)CBS * 2 * 4);
    float* S_pB  = (float*)take((size_t)CBS * 2 * 4);
    float* S_sB  = (float*)take((size_t)CBS * 2 * 4);
    float* slots = (float*)take((size_t)CBS * CD * 4);
    if (ws_size < off) return;

    // plane/buffer aliasing (lifetimes disjoint):
    u16* xlnh = (u16*)R1;                                  // [CBN][768] planes
    u16* xlnm = xlnh + (size_t)CBN * CDIN;
    u16* X1h  = (u16*)R2;                                  // [CBN][768] planes
    u16* X1m  = X1h + (size_t)CBN * CDIN;
    float* xD = R1;                                        // [CBN][256] fp32 (xln dead)
    u16* xDnh = (u16*)(R1 + (size_t)CBN * CD);             // [CBN][256] planes
    u16* xDnm = xDnh + (size_t)CBN * CD;
    float* KVX = R2;                                       // [CBN][512] fp32 (X1 dead)

    float* out0 = (float*)d_out;            // [CBS,CD]
    float* attnb = out0 + CBS * CD;         // [CBS,CN]

    dim3 blk(256);
    const int gM = (CBN + 63) / 64;         // 172 M-tiles (BM=64)
    dim3 gridBN(CB, (CN + 31) / 32);        // 8 x 43

    // ---- weight prep ----
    transpose_split2_kernel<<<dim3(CDIN/32, CDIN/32), blk, 0, stream>>>(im_w1, w1th, w1tm, CDIN, CDIN);
    transpose_split2_kernel<<<dim3(CD/32,   CDIN/32), blk, 0, stream>>>(im_w2, w2th, w2tm, CDIN, CD);
    wprodN_kernel<<<dim3(CD, 1), blk, 0, stream>>>(Wk, f_w1, Pk, CD);
    wprodN_kernel<<<dim3(CD, 1), blk, 0, stream>>>(Wv, f_w1, Pv, CD);
    transpose_split2_kernel<<<dim3(CD/32, CD/32), blk, 0, stream>>>(Pk, kvth, kvtm, CD, CD);
    transpose_split2_kernel<<<dim3(CD/32, CD/32), blk, 0, stream>>>(Pv,
        kvth + (size_t)CD * CD, kvtm + (size_t)CD * CD, CD, CD);
    g2_kernel<<<1, blk, 0, stream>>>(g_w, g_b, f_w1, f_b1, G2b, gb1b);
    transpose32_kernel<<<dim3(CD/32, CD/32), blk, 0, stream>>>(f_w2, fw2T, CD, CD);
    wprodN_kernel<<<dim3(CD, 1), blk, 0, stream>>>(Wq, fw2T, Pq, CD);
    wprodN_kernel<<<dim3(CD, 3), blk, 0, stream>>>(f_w2, gru_wih, Pg, 3 * CD);
    bg_kernel<<<3, blk, 0, stream>>>(f_b2, gru_wih, gru_bih, bgv, 3 * CD);
    wqb_kernel<<<1, blk, 0, stream>>>(Wq, f_b2, wqbb);

    // ---- initial mlp (planes end-to-end) ----
    ln_planes_kernel<<<CBN, blk, 0, stream>>>(inputs, xlnh, xlnm, im_ln1_g, im_ln1_b, CDIN);
    hgemm2<<<dim3(CDIN/128, gM), blk, 0, stream>>>(xlnh, xlnm, w1th, w1tm,
        CBN, CDIN, CDIN, im_b1, 1, nullptr, X1h, X1m);
    hgemm2<<<dim3(CD/128, gM), blk, 0, stream>>>(X1h, X1m, w2th, w2tm,
        CBN, CD, CDIN, im_b2, 0, xD, nullptr, nullptr);
    ln_planes_kernel<<<CBN, blk, 0, stream>>>(xD, xDnh, xDnm, im_ln2_g, im_ln2_b, CD);
    hgemm2<<<dim3(CKV/128, gM), blk, 0, stream>>>(xDnh, xDnm, kvth, kvtm,
        CBN, CKV, CD, nullptr, 0, KVX, nullptr, nullptr);
    init_kernel<<<CBS, blk, 0, stream>>>(slots_init_p, S_s0, S_p0, slots, S_sA, S_pA);

    for (int t = 0; t <= CITERS; t++) {
        float* Sp_cur = (t & 1) ? S_pB : S_pA;
        float* Ss_cur = (t & 1) ? S_sB : S_sA;
        float* Sp_nxt = (t & 1) ? S_pA : S_pB;
        float* Ss_nxt = (t & 1) ? S_sA : S_sB;
        ln_slots_q_kernel<<<CBS, blk, 0, stream>>>(slots, ln_g, ln_b, wqbb, Pq, qwb, qb0b);
        if (t < CITERS) {
            hipMemsetAsync(Wacc, 0, (size_t)CBS * CD * sizeof(float), stream);
            dotsv_kernel<<<gridBN, blk, 0, stream>>>(KVX, Sp_cur, Ss_cur, G2b, gb1b,
                qwb, qb0b, attnb, Wacc);
        } else {
            dotsv_kernel<<<gridBN, blk, 0, stream>>>(KVX, Sp_cur, Ss_cur, G2b, gb1b,
                qwb, qb0b, attnb, nullptr);
        }
        attn_moments_kernel<<<CBS, blk, 0, stream>>>(attnb, Sp_nxt, Ss_nxt, inv0b,
            t == CITERS ? 1 : 0);
        if (t < CITERS) {
            rowgemmG_kernel<<<dim3(CBS, 3*CD/128, 2), dim3(128), 0, stream>>>(
                Wacc, Pg, bgv, giRaw, slots, gru_whh, gru_bhh, ghRaw, inv0b, 3 * CD, CD);
            gate_ln_kernel<<<CBS, blk, 0, stream>>>(giRaw, ghRaw, slots,
                mlp_ln_g, mlp_ln_b, snewb, sMb);
            rowgemm_kernel<<<dim3(CBS, 4*CD/128), dim3(128), 0, stream>>>(sMb, mlp_w1, mlp_b1,
                h1b, 4 * CD, CD, 1, nullptr, nullptr);
            rowgemm_kernel<<<dim3(CBS, CD/128), dim3(128), 0, stream>>>(h1b, mlp_w2, nullptr,
                slots, CD, 4 * CD, 0, snewb, mlp_b2);
        }
    }
    // out0 = slots @ fin_w + fin_b
    rowgemm_kernel<<<dim3(CBS, CD/128), dim3(128), 0, stream>>>(slots, fin_w, fin_b,
        out0, CD, CD, 0, nullptr, nullptr);
}

// Round 5
// 668.067 us; speedup vs baseline: 1.5394x; 1.0790x over previous
//
#include <hip/hip_runtime.h>

// ---------------- problem constants ----------------
constexpr int CB   = 8;      // batch
constexpr int CN   = 1369;   // tokens (37*37)
constexpr int CDIN = 768;
constexpr int CS   = 7;      // slots
constexpr int CD   = 256;
constexpr int CITERS = 3;
constexpr int CRES = 37;
constexpr float CSIGMA = 5.0f;
constexpr int CBS = CB * CS;        // 56
constexpr int CBN = CB * CN;        // 10952 rows for initial mlp
constexpr int CKV = 2 * CD;         // interleaved KX|VX row stride
constexpr float LNEPS = 1e-5f;
constexpr float ATTN_EPS = 1e-8f;

typedef unsigned short u16;
typedef short bs8 __attribute__((ext_vector_type(8)));   // 8 bf16 (bit pattern in shorts)
typedef float f4 __attribute__((ext_vector_type(4)));

// ---------------- helpers ----------------
__device__ __forceinline__ float ag_x(int n) { return -1.f + (float)(n % CRES) * (2.f / 36.f); }
__device__ __forceinline__ float ag_y(int n) { return -1.f + (float)(n / CRES) * (2.f / 36.f); }

__device__ __forceinline__ u16 bf_rne(float f) {
    unsigned u = __float_as_uint(f);
    return (u16)((u + 0x7FFFu + ((u >> 16) & 1u)) >> 16);
}
__device__ __forceinline__ float bf_to_f(u16 h) { return __uint_as_float(((unsigned)h) << 16); }

__device__ __forceinline__ void split2b(float v, u16& h, u16& m) {
    h = bf_rne(v);
    m = bf_rne(v - bf_to_f(h));
}

// async global->LDS, 16B per lane (dest = wave-uniform base + lane*16)
__device__ __forceinline__ void async16(const u16* g, u16* l) {
    __builtin_amdgcn_global_load_lds(
        (const __attribute__((address_space(1))) unsigned int*)g,
        (__attribute__((address_space(3))) unsigned int*)l, 16, 0, 0);
}

// 256-thread block sum
__device__ __forceinline__ float block_reduce_sum(float v, float* sbuf) {
    #pragma unroll
    for (int off = 32; off > 0; off >>= 1) v += __shfl_down(v, off, 64);
    if ((threadIdx.x & 63) == 0) sbuf[threadIdx.x >> 6] = v;
    __syncthreads();
    if (threadIdx.x == 0) sbuf[0] = sbuf[0] + sbuf[1] + sbuf[2] + sbuf[3];
    __syncthreads();
    float r = sbuf[0];
    __syncthreads();
    return r;
}

// ---------------- layernorm -> split-2 bf16 planes (single-pass, d in {256,768}) ----------------
__global__ __launch_bounds__(256) void ln_planes_kernel(const float* __restrict__ in,
        u16* __restrict__ Yh, u16* __restrict__ Ym,
        const float* __restrict__ g, const float* __restrict__ b, int d) {
    __shared__ float sbuf[8];
    int row = blockIdx.x, t = threadIdx.x;
    const float* x = in + (size_t)row * d;
    float v0 = x[t], v1 = 0.f, v2 = 0.f;
    if (d > 256) { v1 = x[t + 256]; v2 = x[t + 512]; }
    float mean = block_reduce_sum(v0 + v1 + v2, sbuf) / d;
    float d0 = v0 - mean, d1 = v1 - mean, d2 = v2 - mean;
    float pv = (d > 256) ? (d0 * d0 + d1 * d1 + d2 * d2) : (d0 * d0);
    float var = block_reduce_sum(pv, sbuf) / d;
    float rstd = rsqrtf(var + LNEPS);
    {
        float y = d0 * rstd * g[t] + b[t];
        u16 h, m; split2b(y, h, m);
        Yh[(size_t)row * d + t] = h; Ym[(size_t)row * d + t] = m;
    }
    if (d > 256) {
        float y1 = d1 * rstd * g[t + 256] + b[t + 256];
        u16 h, m; split2b(y1, h, m);
        Yh[(size_t)row * d + t + 256] = h; Ym[(size_t)row * d + t + 256] = m;
        float y2 = d2 * rstd * g[t + 512] + b[t + 512];
        split2b(y2, h, m);
        Yh[(size_t)row * d + t + 512] = h; Ym[(size_t)row * d + t + 512] = m;
    }
}

// ---------------- transpose fp32 W[K][N] -> 2 bf16 planes Wt[N][K] ----------------
__global__ __launch_bounds__(256) void transpose_split2_kernel(const float* __restrict__ W,
        u16* __restrict__ Th, u16* __restrict__ Tm, int K, int N) {
    __shared__ float tile[32][33];
    int nb = blockIdx.x * 32, kb = blockIdx.y * 32;
    int tx = threadIdx.x & 31, ty = threadIdx.x >> 5;   // ty 0..7
    #pragma unroll
    for (int i = 0; i < 32; i += 8)
        tile[ty + i][tx] = W[(size_t)(kb + ty + i) * N + nb + tx];
    __syncthreads();
    #pragma unroll
    for (int i = 0; i < 32; i += 8) {
        float v = tile[tx][ty + i];
        u16 h, m; split2b(v, h, m);
        size_t idx = (size_t)(nb + ty + i) * K + kb + tx;
        Th[idx] = h; Tm[idx] = m;
    }
}

// ---------------- PT planes: Th/Tm[n][k] = split2b( sum_j A[k][j]*B[j][n] ), all [256][256] ----------------
// Same dot order as wprodN (j sequential) then split2b -> bit-identical to wprodN+transpose_split2.
__global__ __launch_bounds__(256) void wprodT_kernel(const float* __restrict__ A,
        const float* __restrict__ B, u16* __restrict__ Th, u16* __restrict__ Tm) {
    __shared__ float arow[CD];
    int k = blockIdx.x;
    arow[threadIdx.x] = A[k * CD + threadIdx.x];
    __syncthreads();
    int n = threadIdx.x;
    float acc = 0.f;
    for (int j = 0; j < CD; j++) acc += arow[j] * B[(size_t)j * CD + n];
    u16 h, m; split2b(acc, h, m);
    Th[(size_t)n * CD + k] = h;
    Tm[(size_t)n * CD + k] = m;
}

// Pq[k][n] = sum_c Wq[k][c] * f_w2[n][c]  (c sequential - bit-identical to old transpose path)
__global__ __launch_bounds__(256) void wprodPq_kernel(const float* __restrict__ Wq,
        const float* __restrict__ f_w2, float* __restrict__ Pq) {
    __shared__ float arow[CD];
    int k = blockIdx.x;
    arow[threadIdx.x] = Wq[k * CD + threadIdx.x];
    __syncthreads();
    int n = threadIdx.x;
    float acc = 0.f;
    for (int c = 0; c < CD; c++) acc += arow[c] * f_w2[(size_t)n * CD + c];
    Pq[(size_t)k * CD + n] = acc;
}

// ---------------- P[k][n] = sum_j A[k][j]*B[j][n], A [256][256], B [256][N] ----------------
__global__ __launch_bounds__(256) void wprodN_kernel(const float* __restrict__ A,
        const float* __restrict__ B, float* __restrict__ P, int N) {
    __shared__ float arow[CD];
    int k = blockIdx.x;
    arow[threadIdx.x] = A[k * CD + threadIdx.x];
    __syncthreads();
    int n = blockIdx.y * 256 + threadIdx.x;
    if (n >= N) return;
    float acc = 0.f;
    for (int j = 0; j < CD; j++) acc += arow[j] * B[(size_t)j * N + n];
    P[(size_t)k * N + n] = acc;
}

// G2[g][n] = sum_j g_w[g][j]*f_w1[j][n];  gb1[n] = sum_j g_b[j]*f_w1[j][n] + f_b1[n]
__global__ __launch_bounds__(256) void g2_kernel(const float* __restrict__ g_w,
        const float* __restrict__ g_b, const float* __restrict__ f_w1,
        const float* __restrict__ f_b1, float* __restrict__ G2, float* __restrict__ gb1) {
    int n = threadIdx.x;
    float a0 = 0.f, a1 = 0.f, ab = 0.f;
    for (int j = 0; j < CD; j++) {
        float w = f_w1[j * CD + n];
        a0 += g_w[j] * w;
        a1 += g_w[CD + j] * w;
        ab += g_b[j] * w;
    }
    G2[n] = a0; G2[CD + n] = a1; gb1[n] = ab + f_b1[n];
}

// bg[n] = sum_c f_b2[c]*wih[c][n] + bih[n]   (N=768)
__global__ __launch_bounds__(256) void bg_kernel(const float* __restrict__ f_b2,
        const float* __restrict__ wih, const float* __restrict__ bih,
        float* __restrict__ bg, int N) {
    int n = blockIdx.x * 256 + threadIdx.x;
    if (n >= N) return;
    float s = bih[n];
    for (int c = 0; c < CD; c++) s += f_b2[c] * wih[(size_t)c * N + n];
    bg[n] = s;
}

// wqb[j] = sum_c Wq[j][c] * f_b2[c]
__global__ __launch_bounds__(256) void wqb_kernel(const float* __restrict__ Wq,
        const float* __restrict__ f_b2, float* __restrict__ wqb) {
    int j = threadIdx.x;
    float s = 0.f;
    for (int c = 0; c < CD; c++) s += Wq[j * CD + c] * f_b2[c];
    wqb[j] = s;
}

// ---------------- bf16x3 plane GEMM, BM=64 x BN(template), counted-vmcnt 2-phase pipeline ----------------
// A planes Ah/Am [M][K], B planes Bh/Bm [N][K]; K%64==0, N%BN==0.
// LDS double-buffer. Per K-step: issue next tile's NI global_load_lds into nxt,
// s_waitcnt vmcnt(NI) (cur's loads done; prefetch stays in flight - NO drain),
// raw s_barrier, ds_read cur + MFMA, raw s_barrier. T3+T4 minimum pipeline.
// XOR chunk swizzle c' = c ^ (r&3) via inverse-permuted global source + XOR'd ds_read.
// Bijective XCD swizzle (nwg%8==0 for all our grids) for L2 panel locality.
// BN=128: 24KB/buf (3 blocks/CU cap); BN=64: 16KB/buf (5 cap) - for small-N coverage.
template<int BN>
__global__ __launch_bounds__(256)
void hgemm2(const u16* __restrict__ Ah, const u16* __restrict__ Am,
            const u16* __restrict__ Bh, const u16* __restrict__ Bm,
            int M, int N, int K, const float* __restrict__ bias, int relu,
            float* __restrict__ Cf, u16* __restrict__ Ch, u16* __restrict__ Cm) {
    constexpr int BP = BN * 32;            // u16 per B plane
    constexpr int SB = 4096 + 2 * BP;      // u16 per LDS buffer
    constexpr int NI = 2 + 2 * (BN / 64);  // staging issues per k-step: 6 or 4
    constexpr int NF = BN / 32;            // B frags per wave: 4 or 2
    constexpr int PP = BN / 64;            // issues per B plane: 2 or 1
    __shared__ u16 smem[2][SB];
    const int tid = threadIdx.x;

    int bx = blockIdx.x, by = blockIdx.y;
    {
        int gx = gridDim.x;
        int nwg = gx * gridDim.y;
        if (!(nwg & 7)) {               // XCD-aware swizzle (bijective, nwg%8==0)
            int bid = by * gx + bx;
            int cpx = nwg >> 3;
            int s = (bid & 7) * cpx + (bid >> 3);
            bx = s % gx; by = s / gx;
        }
    }
    const int m0 = by * 64, n0 = bx * BN;
    const int w = tid >> 6, lane = tid & 63;
    const int wm = w & 1, wn = w >> 1;
    const int l15 = lane & 15, l4 = lane >> 4;

    // staging map: i0=Ah, i1=Am, then B planes (PP issues each)
    const u16* srcp[NI];
    int dsto[NI];
    #pragma unroll
    for (int i = 0; i < NI; i++) {
        const u16* bp; int row, r, c;
        if (i < 2) {                       // A planes: 64 rows x 4 chunks = 256
            int qq = tid;
            r = qq >> 2;
            c = (qq & 3) ^ (r & 3);        // inverse swizzle on source
            bp = (i == 0) ? Ah : Am;
            row = m0 + r; row = row < M ? row : M - 1;
            dsto[i] = i * 2048 + w * 512;
        } else {                           // B planes: BN rows x 4 chunks
            int ii = i - 2;
            int plane = ii / PP;           // 0:Bh 1:Bm
            int sub = ii % PP;
            int qq = sub * 256 + tid;
            r = qq >> 2;
            c = (qq & 3) ^ (r & 3);
            bp = plane ? Bm : Bh;
            row = n0 + r;
            dsto[i] = 4096 + plane * BP + sub * 2048 + w * 512;
        }
        srcp[i] = bp + (size_t)row * K + c * 8;
    }

    f4 acc[2][NF];
    #pragma unroll
    for (int i = 0; i < 2; i++)
        #pragma unroll
        for (int j = 0; j < NF; j++) acc[i][j] = (f4){0.f, 0.f, 0.f, 0.f};

    const int cx8 = (l4 ^ (l15 & 3)) * 8;     // swizzled k-chunk for fragment reads

    // prologue: stage tile 0 into buf0, full drain once
    #pragma unroll
    for (int i = 0; i < NI; i++) async16(srcp[i], &smem[0][dsto[i]]);
    __syncthreads();

    u16* cur = &smem[0][0];
    u16* nxt = &smem[1][0];

    for (int k0 = 0; k0 < K; k0 += 32) {
        if (k0 + 32 < K) {
            #pragma unroll
            for (int i = 0; i < NI; i++) async16(srcp[i] + k0 + 32, nxt + dsto[i]);
            if constexpr (BN == 128)
                asm volatile("s_waitcnt vmcnt(6)" ::: "memory");
            else
                asm volatile("s_waitcnt vmcnt(4)" ::: "memory");
        } else {
            asm volatile("s_waitcnt vmcnt(0)" ::: "memory");
        }
        __builtin_amdgcn_s_barrier();        // all threads' cur loads landed
        bs8 ah[2], am[2], bh[NF], bm[NF];
        #pragma unroll
        for (int f = 0; f < 2; f++) {
            int oa = (wm * 32 + f * 16 + l15) * 32 + cx8;
            ah[f] = *(const bs8*)(cur + oa);
            am[f] = *(const bs8*)(cur + 2048 + oa);
        }
        #pragma unroll
        for (int f = 0; f < NF; f++) {
            int ob = (wn * (NF * 16) + f * 16 + l15) * 32 + cx8;
            bh[f] = *(const bs8*)(cur + 4096 + ob);
            bm[f] = *(const bs8*)(cur + 4096 + BP + ob);
        }
        #pragma unroll
        for (int mf = 0; mf < 2; mf++)
            #pragma unroll
            for (int nf = 0; nf < NF; nf++) {
                acc[mf][nf] = __builtin_amdgcn_mfma_f32_16x16x32_bf16(am[mf], bh[nf], acc[mf][nf], 0, 0, 0);
                acc[mf][nf] = __builtin_amdgcn_mfma_f32_16x16x32_bf16(ah[mf], bm[nf], acc[mf][nf], 0, 0, 0);
                acc[mf][nf] = __builtin_amdgcn_mfma_f32_16x16x32_bf16(ah[mf], bh[nf], acc[mf][nf], 0, 0, 0);
            }
        asm volatile("" ::: "memory");       // keep LDS reads/issues ordered vs barrier
        __builtin_amdgcn_s_barrier();        // all done reading cur (no vmcnt drain!)
        u16* t_ = cur; cur = nxt; nxt = t_;
    }

    #pragma unroll
    for (int mf = 0; mf < 2; mf++)
        #pragma unroll
        for (int i = 0; i < 4; i++) {
            int grow = m0 + wm * 32 + mf * 16 + l4 * 4 + i;
            if (grow < M) {
                #pragma unroll
                for (int nf = 0; nf < NF; nf++) {
                    int col = n0 + wn * (NF * 16) + nf * 16 + l15;
                    float v = acc[mf][nf][i] + (bias ? bias[col] : 0.f);
                    if (relu) v = fmaxf(v, 0.f);
                    if (Cf) Cf[(size_t)grow * N + col] = v;
                    else {
                        u16 h, m; split2b(v, h, m);
                        Ch[(size_t)grow * N + col] = h;
                        Cm[(size_t)grow * N + col] = m;
                    }
                }
            }
        }
}

// ---------------- thin fp32 row-GEMV ----------------
__global__ __launch_bounds__(128) void rowgemm_kernel(const float* __restrict__ A,
        const float* __restrict__ W, const float* __restrict__ bias,
        float* __restrict__ C, int N, int K, int relu,
        const float* __restrict__ resid, const float* __restrict__ resb) {
    __shared__ float sA[1024];
    int r = blockIdx.x;
    int c = blockIdx.y * 128 + threadIdx.x;
    for (int i = threadIdx.x; i < K; i += 128) sA[i] = A[(size_t)r * K + i];
    __syncthreads();
    float a0 = 0.f, a1 = 0.f, a2 = 0.f, a3 = 0.f;
    #pragma unroll 4
    for (int k = 0; k < K; k += 4) {
        a0 += sA[k]     * W[(size_t)k * N + c];
        a1 += sA[k + 1] * W[(size_t)(k + 1) * N + c];
        a2 += sA[k + 2] * W[(size_t)(k + 2) * N + c];
        a3 += sA[k + 3] * W[(size_t)(k + 3) * N + c];
    }
    float v = (a0 + a1) + (a2 + a3) + (bias ? bias[c] : 0.f);
    if (relu) v = fmaxf(v, 0.f);
    if (resid) v += resid[(size_t)r * N + c] + resb[c];
    C[(size_t)r * N + c] = v;
}

// gi/gh pair in one launch via blockIdx.z; z==0 rows scaled by sc0[r] (1/m0 fold)
__global__ __launch_bounds__(128) void rowgemmG_kernel(
        const float* __restrict__ A0, const float* __restrict__ W0,
        const float* __restrict__ b0, float* __restrict__ C0,
        const float* __restrict__ A1, const float* __restrict__ W1,
        const float* __restrict__ b1, float* __restrict__ C1,
        const float* __restrict__ sc0, int N, int K) {
    __shared__ float sA[256];
    const float* A = blockIdx.z ? A1 : A0;
    const float* W = blockIdx.z ? W1 : W0;
    const float* B = blockIdx.z ? b1 : b0;
    float* C = blockIdx.z ? C1 : C0;
    int r = blockIdx.x;
    int c = blockIdx.y * 128 + threadIdx.x;
    float scl = blockIdx.z ? 1.f : sc0[r];
    for (int i = threadIdx.x; i < K; i += 128) sA[i] = A[(size_t)r * K + i] * scl;
    __syncthreads();
    float a0 = 0.f, a1 = 0.f, a2 = 0.f, a3 = 0.f;
    #pragma unroll 4
    for (int k = 0; k < K; k += 4) {
        a0 += sA[k]     * W[(size_t)k * N + c];
        a1 += sA[k + 1] * W[(size_t)(k + 1) * N + c];
        a2 += sA[k + 2] * W[(size_t)(k + 2) * N + c];
        a3 += sA[k + 3] * W[(size_t)(k + 3) * N + c];
    }
    C[(size_t)r * N + c] = (a0 + a1) + (a2 + a3) + B[c];
}

// ---------------- small kernels ----------------
__global__ __launch_bounds__(256) void init_kernel(const float* __restrict__ slots_init_p,
        const float* __restrict__ S_s0, const float* __restrict__ S_p0,
        float* __restrict__ slots, float* __restrict__ S_s, float* __restrict__ S_p) {
    int bs = blockIdx.x, t = threadIdx.x;
    int s = bs % CS;
    slots[bs * CD + t] = slots_init_p[s * CD + t];
    if (t < 2) { S_s[bs * 2 + t] = S_s0[s * 2 + t]; S_p[bs * 2 + t] = S_p0[s * 2 + t]; }
}

// LN(slots) + qb0 + qw = sn @ Pq (fused GEMV)
__global__ __launch_bounds__(256) void ln_slots_q_kernel(const float* __restrict__ slots,
        const float* __restrict__ ln_g, const float* __restrict__ ln_b,
        const float* __restrict__ wqb, const float* __restrict__ Pq,
        float* __restrict__ qwb, float* __restrict__ qb0) {
    __shared__ float sbuf[8];
    __shared__ float sN[CD];
    int row = blockIdx.x, t = threadIdx.x;
    float x = slots[row * CD + t];
    float mean = block_reduce_sum(x, sbuf) / CD;
    float d0 = x - mean;
    float var = block_reduce_sum(d0 * d0, sbuf) / CD;
    float sn = d0 * rsqrtf(var + LNEPS) * ln_g[t] + ln_b[t];
    sN[t] = sn;
    float qb = block_reduce_sum(sn * wqb[t], sbuf);
    if (t == 0) qb0[row] = qb;
    __syncthreads();
    float acc = 0.f;
    #pragma unroll 4
    for (int k = 0; k < CD; k++) acc += sN[k] * Pq[(size_t)k * CD + t];
    qwb[row * CD + t] = acc;
}

// dots + softmax-over-slots + (optional) vsum fused. Grid (CB, 86): 16 n per block
// (4 per wave) for 2.7 blocks/CU coverage - per-(b,s,n) math identical to before.
__global__ __launch_bounds__(256) void dotsv_kernel(const float* __restrict__ KVX,
        const float* __restrict__ S_p, const float* __restrict__ S_s,
        const float* __restrict__ G2, const float* __restrict__ gb1,
        const float* __restrict__ qw, const float* __restrict__ qb0,
        float* __restrict__ attn, float* __restrict__ Wacc) {
    __shared__ float sred[4 * CD];
    int b = blockIdx.x;
    int w = threadIdx.x >> 6, l = threadIdx.x & 63;
    int k4 = l * 4;
    float4 g0 = *(const float4*)(G2 + k4);
    float4 g1 = *(const float4*)(G2 + CD + k4);
    float4 gb = *(const float4*)(gb1 + k4);
    float4 qwv[CS]; float px[CS], py[CS], ix[CS], iy[CS], q0[CS];
    #pragma unroll
    for (int s = 0; s < CS; s++) {
        int bs = b * CS + s;
        qwv[s] = *(const float4*)(qw + bs * CD + k4);
        px[s] = S_p[2 * bs]; py[s] = S_p[2 * bs + 1];
        ix[s] = 1.f / (S_s[2 * bs] * CSIGMA); iy[s] = 1.f / (S_s[2 * bs + 1] * CSIGMA);
        q0[s] = qb0[bs];
    }
    float4 acc[CS];
    #pragma unroll
    for (int s = 0; s < CS; s++) acc[s] = make_float4(0.f, 0.f, 0.f, 0.f);
    int nbase = blockIdx.y * 16 + w * 4;
    #pragma unroll
    for (int i = 0; i < 4; i++) {
        int n = nbase + i;
        int nc = n < CN ? n : CN - 1;
        const float* rowp = KVX + (size_t)(b * CN + nc) * CKV;
        float4 kx = *(const float4*)(rowp + k4);
        float ax = ag_x(nc), ay = ag_y(nc);
        float dsv[CS];
        #pragma unroll
        for (int s = 0; s < CS; s++) {
            float r0 = (ax - px[s]) * ix[s];
            float r1 = (ay - py[s]) * iy[s];
            float v0 = fmaxf(kx.x + r0 * g0.x + r1 * g1.x + gb.x, 0.f);
            float v1 = fmaxf(kx.y + r0 * g0.y + r1 * g1.y + gb.y, 0.f);
            float v2 = fmaxf(kx.z + r0 * g0.z + r1 * g1.z + gb.z, 0.f);
            float v3 = fmaxf(kx.w + r0 * g0.w + r1 * g1.w + gb.w, 0.f);
            float d = v0 * qwv[s].x + v1 * qwv[s].y + v2 * qwv[s].z + v3 * qwv[s].w;
            #pragma unroll
            for (int off = 32; off > 0; off >>= 1) d += __shfl_xor(d, off, 64);
            dsv[s] = 0.0625f * (d + q0[s]);
        }
        float mx = -1e30f;
        #pragma unroll
        for (int s = 0; s < CS; s++) mx = fmaxf(mx, dsv[s]);
        float sum = 0.f;
        #pragma unroll
        for (int s = 0; s < CS; s++) { dsv[s] = __expf(dsv[s] - mx); sum += dsv[s]; }
        float inv = 1.f / sum;
        #pragma unroll
        for (int s = 0; s < CS; s++) dsv[s] = dsv[s] * inv + ATTN_EPS;
        if (l == 0 && n < CN) {
            #pragma unroll
            for (int s = 0; s < CS; s++)
                attn[(size_t)(b * CS + s) * CN + n] = dsv[s];
        }
        if (Wacc && n < CN) {
            float4 vx = *(const float4*)(rowp + CD + k4);
            #pragma unroll
            for (int s = 0; s < CS; s++) {
                float r0 = (ax - px[s]) * ix[s];
                float r1 = (ay - py[s]) * iy[s];
                float a = dsv[s];
                acc[s].x += a * fmaxf(vx.x + r0 * g0.x + r1 * g1.x + gb.x, 0.f);
                acc[s].y += a * fmaxf(vx.y + r0 * g0.y + r1 * g1.y + gb.y, 0.f);
                acc[s].z += a * fmaxf(vx.z + r0 * g0.z + r1 * g1.z + gb.z, 0.f);
                acc[s].w += a * fmaxf(vx.w + r0 * g0.w + r1 * g1.w + gb.w, 0.f);
            }
        }
    }
    if (Wacc) {
        for (int s = 0; s < CS; s++) {
            ((float4*)sred)[w * 64 + l] = acc[s];
            __syncthreads();
            if (threadIdx.x < CD) {
                float v = sred[threadIdx.x] + sred[CD + threadIdx.x]
                        + sred[2 * CD + threadIdx.x] + sred[3 * CD + threadIdx.x];
                atomicAdd(&Wacc[(size_t)(b * CS + s) * CD + threadIdx.x], v);
            }
            __syncthreads();
        }
    }
}

// moments; normalized-attn writeback only when writeNorm (final iter)
__global__ __launch_bounds__(256) void attn_moments_kernel(float* __restrict__ u,
        float* __restrict__ S_p, float* __restrict__ S_s, float* __restrict__ inv0,
        int writeNorm) {
    __shared__ float sbuf[8];
    int bs = blockIdx.x;
    float* up = u + (size_t)bs * CN;
    float m0 = 0, m1x = 0, m1y = 0, m2x = 0, m2y = 0;
    for (int n = threadIdx.x; n < CN; n += 256) {
        float uu = up[n];
        float ax = ag_x(n), ay = ag_y(n);
        m0 += uu; m1x += uu * ax; m1y += uu * ay; m2x += uu * ax * ax; m2y += uu * ay * ay;
    }
    m0  = block_reduce_sum(m0, sbuf);
    m1x = block_reduce_sum(m1x, sbuf);
    m1y = block_reduce_sum(m1y, sbuf);
    m2x = block_reduce_sum(m2x, sbuf);
    m2y = block_reduce_sum(m2y, sbuf);
    float px = m1x / m0, py = m1y / m0;
    float inv = 1.f / m0;
    if (threadIdx.x == 0) {
        S_p[2 * bs] = px; S_p[2 * bs + 1] = py;
        S_s[2 * bs]     = sqrtf(fmaxf(m2x / m0 - px * px, 0.f));
        S_s[2 * bs + 1] = sqrtf(fmaxf(m2y / m0 - py * py, 0.f));
        inv0[bs] = inv;
    }
    if (writeNorm)
        for (int n = threadIdx.x; n < CN; n += 256) up[n] = up[n] * inv;
}

// gates + LN (biases already folded into giRaw/ghRaw)
__global__ __launch_bounds__(256) void gate_ln_kernel(const float* __restrict__ giRaw,
        const float* __restrict__ ghRaw, const float* __restrict__ slots,
        const float* __restrict__ mg, const float* __restrict__ mb,
        float* __restrict__ snewb, float* __restrict__ sMb) {
    __shared__ float sbuf[8];
    int row = blockIdx.x, t = threadIdx.x;
    float gi0 = giRaw[row * 3 * CD + t];
    float gi1 = giRaw[row * 3 * CD + CD + t];
    float gi2 = giRaw[row * 3 * CD + 2 * CD + t];
    float gh0 = ghRaw[row * 3 * CD + t];
    float gh1 = ghRaw[row * 3 * CD + CD + t];
    float gh2 = ghRaw[row * 3 * CD + 2 * CD + t];
    float r = 1.f / (1.f + expf(-(gi0 + gh0)));
    float z = 1.f / (1.f + expf(-(gi1 + gh1)));
    float nn = tanhf(gi2 + r * gh2);
    float snew = (1.f - z) * nn + z * slots[row * CD + t];
    snewb[row * CD + t] = snew;
    float mean = block_reduce_sum(snew, sbuf) / CD;
    float dv = snew - mean;
    float var = block_reduce_sum(dv * dv, sbuf) / CD;
    sMb[row * CD + t] = dv * rsqrtf(var + LNEPS) * mg[t] + mb[t];
}

// ---------------- launcher ----------------
extern "C" void kernel_launch(void* const* d_in, const int* in_sizes, int n_in,
                              void* d_out, int out_size, void* d_ws, size_t ws_size,
                              hipStream_t stream) {
    (void)in_sizes; (void)n_in; (void)out_size;
    const float* inputs       = (const float*)d_in[0];
    const float* slots_init_p = (const float*)d_in[1];
    const float* S_s0         = (const float*)d_in[2];
    const float* S_p0         = (const float*)d_in[3];
    const float* im_ln1_g = (const float*)d_in[4];
    const float* im_ln1_b = (const float*)d_in[5];
    const float* im_w1    = (const float*)d_in[6];
    const float* im_b1    = (const float*)d_in[7];
    const float* im_w2    = (const float*)d_in[8];
    const float* im_b2    = (const float*)d_in[9];
    const float* im_ln2_g = (const float*)d_in[10];
    const float* im_ln2_b = (const float*)d_in[11];
    const float* Wq  = (const float*)d_in[12];
    const float* Wk  = (const float*)d_in[13];
    const float* Wv  = (const float*)d_in[14];
    const float* g_w = (const float*)d_in[15];
    const float* g_b = (const float*)d_in[16];
    const float* f_w1 = (const float*)d_in[17];
    const float* f_b1 = (const float*)d_in[18];
    const float* f_w2 = (const float*)d_in[19];
    const float* f_b2 = (const float*)d_in[20];
    const float* ln_g = (const float*)d_in[21];
    const float* ln_b = (const float*)d_in[22];
    const float* gru_wih = (const float*)d_in[23];
    const float* gru_whh = (const float*)d_in[24];
    const float* gru_bih = (const float*)d_in[25];
    const float* gru_bhh = (const float*)d_in[26];
    const float* mlp_ln_g = (const float*)d_in[27];
    const float* mlp_ln_b = (const float*)d_in[28];
    const float* mlp_w1 = (const float*)d_in[29];
    const float* mlp_b1 = (const float*)d_in[30];
    const float* mlp_w2 = (const float*)d_in[31];
    const float* mlp_b2 = (const float*)d_in[32];
    const float* fin_w = (const float*)d_in[33];
    const float* fin_b = (const float*)d_in[34];

    char* base = (char*)d_ws;
    size_t off = 0;
    auto take = [&](size_t bytes) { void* p = base + off; off += (bytes + 255) & ~(size_t)255; return p; };

    float* R1 = (float*)take((size_t)CBN * CDIN * 4);  // xln planes -> xD | xDn planes
    float* R2 = (float*)take((size_t)CBN * CDIN * 4);  // X1 planes -> KVX
    u16* w1th = (u16*)take((size_t)CDIN * CDIN * 2);
    u16* w1tm = (u16*)take((size_t)CDIN * CDIN * 2);
    u16* w2th = (u16*)take((size_t)CDIN * CD * 2);
    u16* w2tm = (u16*)take((size_t)CDIN * CD * 2);
    u16* kvth = (u16*)take((size_t)CKV * CD * 2);      // [512][256]: PkT | PvT
    u16* kvtm = (u16*)take((size_t)CKV * CD * 2);
    float* G2b  = (float*)take((size_t)2 * CD * 4);
    float* gb1b = (float*)take((size_t)CD * 4);
    float* Pq   = (float*)take((size_t)CD * CD * 4);
    float* Pg   = (float*)take((size_t)CD * 3 * CD * 4);
    float* bgv  = (float*)take((size_t)3 * CD * 4);
    float* wqbb = (float*)take((size_t)CD * 4);
    float* qwb   = (float*)take((size_t)CBS * CD * 4);
    float* qb0b  = (float*)take((size_t)CBS * 4);
    float* inv0b = (float*)take((size_t)CBS * 4);
    float* Wacc  = (float*)take((size_t)CBS * CD * 4);
    float* giRaw = (float*)take((size_t)CBS * 3 * CD * 4);
    float* ghRaw = (float*)take((size_t)CBS * 3 * CD * 4);
    float* snewb = (float*)take((size_t)CBS * CD * 4);
    float* sMb   = (float*)take((size_t)CBS * CD * 4);
    float* h1b   = (float*)take((size_t)CBS * 4 * CD * 4);
    float* S_pA  = (float*)take((size_t)CBS * 2 * 4);
    float* S_sA  = (float*)take((size_t)CBS * 2 * 4);
    float* S_pB  = (float*)take((size_t)CBS * 2 * 4);
    float* S_sB  = (float*)take((size_t)CBS * 2 * 4);
    float* slots = (float*)take((size_t)CBS * CD * 4);
    if (ws_size < off) return;

    // plane/buffer aliasing (lifetimes disjoint):
    u16* xlnh = (u16*)R1;                                  // [CBN][768] planes
    u16* xlnm = xlnh + (size_t)CBN * CDIN;
    u16* X1h  = (u16*)R2;                                  // [CBN][768] planes
    u16* X1m  = X1h + (size_t)CBN * CDIN;
    float* xD = R1;                                        // [CBN][256] fp32 (xln dead)
    u16* xDnh = (u16*)(R1 + (size_t)CBN * CD);             // [CBN][256] planes
    u16* xDnm = xDnh + (size_t)CBN * CD;
    float* KVX = R2;                                       // [CBN][512] fp32 (X1 dead)

    float* out0 = (float*)d_out;            // [CBS,CD]
    float* attnb = out0 + CBS * CD;         // [CBS,CN]

    dim3 blk(256);
    const int gM = (CBN + 63) / 64;         // 172 M-tiles (BM=64)
    dim3 gridBN(CB, 86);                    // 8 x 86 (16 n per block)

    // ---- weight prep ----
    transpose_split2_kernel<<<dim3(CDIN/32, CDIN/32), blk, 0, stream>>>(im_w1, w1th, w1tm, CDIN, CDIN);
    transpose_split2_kernel<<<dim3(CD/32,   CDIN/32), blk, 0, stream>>>(im_w2, w2th, w2tm, CDIN, CD);
    wprodT_kernel<<<dim3(CD), blk, 0, stream>>>(Wk, f_w1, kvth, kvtm);
    wprodT_kernel<<<dim3(CD), blk, 0, stream>>>(Wv, f_w1,
        kvth + (size_t)CD * CD, kvtm + (size_t)CD * CD);
    g2_kernel<<<1, blk, 0, stream>>>(g_w, g_b, f_w1, f_b1, G2b, gb1b);
    wprodPq_kernel<<<dim3(CD), blk, 0, stream>>>(Wq, f_w2, Pq);
    wprodN_kernel<<<dim3(CD, 3), blk, 0, stream>>>(f_w2, gru_wih, Pg, 3 * CD);
    bg_kernel<<<3, blk, 0, stream>>>(f_b2, gru_wih, gru_bih, bgv, 3 * CD);
    wqb_kernel<<<1, blk, 0, stream>>>(Wq, f_b2, wqbb);

    // ---- initial mlp (planes end-to-end) ----
    ln_planes_kernel<<<CBN, blk, 0, stream>>>(inputs, xlnh, xlnm, im_ln1_g, im_ln1_b, CDIN);
    hgemm2<128><<<dim3(CDIN/128, gM), blk, 0, stream>>>(xlnh, xlnm, w1th, w1tm,
        CBN, CDIN, CDIN, im_b1, 1, nullptr, X1h, X1m);
    hgemm2<64><<<dim3(CD/64, gM), blk, 0, stream>>>(X1h, X1m, w2th, w2tm,
        CBN, CD, CDIN, im_b2, 0, xD, nullptr, nullptr);
    ln_planes_kernel<<<CBN, blk, 0, stream>>>(xD, xDnh, xDnm, im_ln2_g, im_ln2_b, CD);
    hgemm2<64><<<dim3(CKV/64, gM), blk, 0, stream>>>(xDnh, xDnm, kvth, kvtm,
        CBN, CKV, CD, nullptr, 0, KVX, nullptr, nullptr);
    init_kernel<<<CBS, blk, 0, stream>>>(slots_init_p, S_s0, S_p0, slots, S_sA, S_pA);

    for (int t = 0; t <= CITERS; t++) {
        float* Sp_cur = (t & 1) ? S_pB : S_pA;
        float* Ss_cur = (t & 1) ? S_sB : S_sA;
        float* Sp_nxt = (t & 1) ? S_pA : S_pB;
        float* Ss_nxt = (t & 1) ? S_sA : S_sB;
        ln_slots_q_kernel<<<CBS, blk, 0, stream>>>(slots, ln_g, ln_b, wqbb, Pq, qwb, qb0b);
        if (t < CITERS) {
            hipMemsetAsync(Wacc, 0, (size_t)CBS * CD * sizeof(float), stream);
            dotsv_kernel<<<gridBN, blk, 0, stream>>>(KVX, Sp_cur, Ss_cur, G2b, gb1b,
                qwb, qb0b, attnb, Wacc);
        } else {
            dotsv_kernel<<<gridBN, blk, 0, stream>>>(KVX, Sp_cur, Ss_cur, G2b, gb1b,
                qwb, qb0b, attnb, nullptr);
        }
        attn_moments_kernel<<<CBS, blk, 0, stream>>>(attnb, Sp_nxt, Ss_nxt, inv0b,
            t == CITERS ? 1 : 0);
        if (t < CITERS) {
            rowgemmG_kernel<<<dim3(CBS, 3*CD/128, 2), dim3(128), 0, stream>>>(
                Wacc, Pg, bgv, giRaw, slots, gru_whh, gru_bhh, ghRaw, inv0b, 3 * CD, CD);
            gate_ln_kernel<<<CBS, blk, 0, stream>>>(giRaw, ghRaw, slots,
                mlp_ln_g, mlp_ln_b, snewb, sMb);
            rowgemm_kernel<<<dim3(CBS, 4*CD/128), dim3(128), 0, stream>>>(sMb, mlp_w1, mlp_b1,
                h1b, 4 * CD, CD, 1, nullptr, nullptr);
            rowgemm_kernel<<<dim3(CBS, CD/128), dim3(128), 0, stream>>>(h1b, mlp_w2, nullptr,
                slots, CD, 4 * CD, 0, snewb, mlp_b2);
        }
    }
    // out0 = slots @ fin_w + fin_b
    rowgemm_kernel<<<dim3(CBS, CD/128), dim3(128), 0, stream>>>(slots, fin_w, fin_b,
        out0, CD, CD, 0, nullptr, nullptr);
}

// Round 6
// 665.110 us; speedup vs baseline: 1.5463x; 1.0044x over previous
//
#include <hip/hip_runtime.h>

// ---------------- problem constants ----------------
constexpr int CB   = 8;      // batch
constexpr int CN   = 1369;   // tokens (37*37)
constexpr int CDIN = 768;
constexpr int CS   = 7;      // slots
constexpr int CD   = 256;
constexpr int CITERS = 3;
constexpr int CRES = 37;
constexpr float CSIGMA = 5.0f;
constexpr int CBS = CB * CS;        // 56
constexpr int CBN = CB * CN;        // 10952 rows for initial mlp
constexpr int CKV = 2 * CD;         // interleaved KX|VX row stride
constexpr float LNEPS = 1e-5f;
constexpr float ATTN_EPS = 1e-8f;

typedef unsigned short u16;
typedef short bs8 __attribute__((ext_vector_type(8)));   // 8 bf16 (bit pattern in shorts)
typedef float f4 __attribute__((ext_vector_type(4)));

// ---------------- helpers ----------------
__device__ __forceinline__ float ag_x(int n) { return -1.f + (float)(n % CRES) * (2.f / 36.f); }
__device__ __forceinline__ float ag_y(int n) { return -1.f + (float)(n / CRES) * (2.f / 36.f); }

__device__ __forceinline__ u16 bf_rne(float f) {
    unsigned u = __float_as_uint(f);
    return (u16)((u + 0x7FFFu + ((u >> 16) & 1u)) >> 16);
}
__device__ __forceinline__ float bf_to_f(u16 h) { return __uint_as_float(((unsigned)h) << 16); }

__device__ __forceinline__ void split2b(float v, u16& h, u16& m) {
    h = bf_rne(v);
    m = bf_rne(v - bf_to_f(h));
}

// async global->LDS, 16B per lane (dest = wave-uniform base + lane*16)
__device__ __forceinline__ void async16(const u16* g, u16* l) {
    __builtin_amdgcn_global_load_lds(
        (const __attribute__((address_space(1))) unsigned int*)g,
        (__attribute__((address_space(3))) unsigned int*)l, 16, 0, 0);
}

// 256-thread block sum
__device__ __forceinline__ float block_reduce_sum(float v, float* sbuf) {
    #pragma unroll
    for (int off = 32; off > 0; off >>= 1) v += __shfl_down(v, off, 64);
    if ((threadIdx.x & 63) == 0) sbuf[threadIdx.x >> 6] = v;
    __syncthreads();
    if (threadIdx.x == 0) sbuf[0] = sbuf[0] + sbuf[1] + sbuf[2] + sbuf[3];
    __syncthreads();
    float r = sbuf[0];
    __syncthreads();
    return r;
}

// ---------------- layernorm -> split-2 bf16 planes (single-pass, d in {256,768}) ----------------
__global__ __launch_bounds__(256) void ln_planes_kernel(const float* __restrict__ in,
        u16* __restrict__ Yh, u16* __restrict__ Ym,
        const float* __restrict__ g, const float* __restrict__ b, int d) {
    __shared__ float sbuf[8];
    int row = blockIdx.x, t = threadIdx.x;
    const float* x = in + (size_t)row * d;
    float v0 = x[t], v1 = 0.f, v2 = 0.f;
    if (d > 256) { v1 = x[t + 256]; v2 = x[t + 512]; }
    float mean = block_reduce_sum(v0 + v1 + v2, sbuf) / d;
    float d0 = v0 - mean, d1 = v1 - mean, d2 = v2 - mean;
    float pv = (d > 256) ? (d0 * d0 + d1 * d1 + d2 * d2) : (d0 * d0);
    float var = block_reduce_sum(pv, sbuf) / d;
    float rstd = rsqrtf(var + LNEPS);
    {
        float y = d0 * rstd * g[t] + b[t];
        u16 h, m; split2b(y, h, m);
        Yh[(size_t)row * d + t] = h; Ym[(size_t)row * d + t] = m;
    }
    if (d > 256) {
        float y1 = d1 * rstd * g[t + 256] + b[t + 256];
        u16 h, m; split2b(y1, h, m);
        Yh[(size_t)row * d + t + 256] = h; Ym[(size_t)row * d + t + 256] = m;
        float y2 = d2 * rstd * g[t + 512] + b[t + 512];
        split2b(y2, h, m);
        Yh[(size_t)row * d + t + 512] = h; Ym[(size_t)row * d + t + 512] = m;
    }
}

// ---------------- transpose fp32 W[K][N] -> 2 bf16 planes Wt[N][K] ----------------
__global__ __launch_bounds__(256) void transpose_split2_kernel(const float* __restrict__ W,
        u16* __restrict__ Th, u16* __restrict__ Tm, int K, int N) {
    __shared__ float tile[32][33];
    int nb = blockIdx.x * 32, kb = blockIdx.y * 32;
    int tx = threadIdx.x & 31, ty = threadIdx.x >> 5;   // ty 0..7
    #pragma unroll
    for (int i = 0; i < 32; i += 8)
        tile[ty + i][tx] = W[(size_t)(kb + ty + i) * N + nb + tx];
    __syncthreads();
    #pragma unroll
    for (int i = 0; i < 32; i += 8) {
        float v = tile[tx][ty + i];
        u16 h, m; split2b(v, h, m);
        size_t idx = (size_t)(nb + ty + i) * K + kb + tx;
        Th[idx] = h; Tm[idx] = m;
    }
}

// ---------------- PT planes: Th/Tm[n][k] = split2b( sum_j A[k][j]*B[j][n] ), all [256][256] ----------------
__global__ __launch_bounds__(256) void wprodT_kernel(const float* __restrict__ A,
        const float* __restrict__ B, u16* __restrict__ Th, u16* __restrict__ Tm) {
    __shared__ float arow[CD];
    int k = blockIdx.x;
    arow[threadIdx.x] = A[k * CD + threadIdx.x];
    __syncthreads();
    int n = threadIdx.x;
    float acc = 0.f;
    for (int j = 0; j < CD; j++) acc += arow[j] * B[(size_t)j * CD + n];
    u16 h, m; split2b(acc, h, m);
    Th[(size_t)n * CD + k] = h;
    Tm[(size_t)n * CD + k] = m;
}

// Pq[k][n] = sum_c Wq[k][c] * f_w2[n][c]
__global__ __launch_bounds__(256) void wprodPq_kernel(const float* __restrict__ Wq,
        const float* __restrict__ f_w2, float* __restrict__ Pq) {
    __shared__ float arow[CD];
    int k = blockIdx.x;
    arow[threadIdx.x] = Wq[k * CD + threadIdx.x];
    __syncthreads();
    int n = threadIdx.x;
    float acc = 0.f;
    for (int c = 0; c < CD; c++) acc += arow[c] * f_w2[(size_t)n * CD + c];
    Pq[(size_t)k * CD + n] = acc;
}

// ---------------- P[k][n] = sum_j A[k][j]*B[j][n], A [256][256], B [256][N] ----------------
__global__ __launch_bounds__(256) void wprodN_kernel(const float* __restrict__ A,
        const float* __restrict__ B, float* __restrict__ P, int N) {
    __shared__ float arow[CD];
    int k = blockIdx.x;
    arow[threadIdx.x] = A[k * CD + threadIdx.x];
    __syncthreads();
    int n = blockIdx.y * 256 + threadIdx.x;
    if (n >= N) return;
    float acc = 0.f;
    for (int j = 0; j < CD; j++) acc += arow[j] * B[(size_t)j * N + n];
    P[(size_t)k * N + n] = acc;
}

// G2[g][n] = sum_j g_w[g][j]*f_w1[j][n];  gb1[n] = sum_j g_b[j]*f_w1[j][n] + f_b1[n]
__global__ __launch_bounds__(256) void g2_kernel(const float* __restrict__ g_w,
        const float* __restrict__ g_b, const float* __restrict__ f_w1,
        const float* __restrict__ f_b1, float* __restrict__ G2, float* __restrict__ gb1) {
    int n = threadIdx.x;
    float a0 = 0.f, a1 = 0.f, ab = 0.f;
    for (int j = 0; j < CD; j++) {
        float w = f_w1[j * CD + n];
        a0 += g_w[j] * w;
        a1 += g_w[CD + j] * w;
        ab += g_b[j] * w;
    }
    G2[n] = a0; G2[CD + n] = a1; gb1[n] = ab + f_b1[n];
}

// bg[n] = sum_c f_b2[c]*wih[c][n] + bih[n]   (N=768)
__global__ __launch_bounds__(256) void bg_kernel(const float* __restrict__ f_b2,
        const float* __restrict__ wih, const float* __restrict__ bih,
        float* __restrict__ bg, int N) {
    int n = blockIdx.x * 256 + threadIdx.x;
    if (n >= N) return;
    float s = bih[n];
    for (int c = 0; c < CD; c++) s += f_b2[c] * wih[(size_t)c * N + n];
    bg[n] = s;
}

// wqb[j] = sum_c Wq[j][c] * f_b2[c]
__global__ __launch_bounds__(256) void wqb_kernel(const float* __restrict__ Wq,
        const float* __restrict__ f_b2, float* __restrict__ wqb) {
    int j = threadIdx.x;
    float s = 0.f;
    for (int c = 0; c < CD; c++) s += Wq[j * CD + c] * f_b2[c];
    wqb[j] = s;
}

// ---------------- bf16x3 plane GEMM, BM=64 x BN(template), counted-vmcnt 2-phase pipeline ----------------
// A planes Ah/Am [M][K], B planes Bh/Bm [N][K]; K%64==0, N%BN==0.
// LDS double-buffer. Per K-step: issue next tile's NI global_load_lds into nxt,
// s_waitcnt vmcnt(NI) (cur's loads done; prefetch stays in flight - NO drain),
// raw s_barrier, ds_read cur + MFMA, raw s_barrier. T3+T4 minimum pipeline.
// LDS slot swizzle: slot = chunk ^ swz(r), swz(r) = (r ^ (r>>2)) & 3.
//   Bank math: row stride 64B -> bank_group = 16*(r&1) + 4*slot; reader slot
//   l4 ^ (l15&3) ^ (l15>>2) makes (r&1, slot) cover all 8 groups twice per 16 lanes
//   -> 2 lanes/bank (free, m136). Old swz=r&3 left a 4-way conflict (4.75M PMC).
// Applied as inverse-permuted global source (write side, guideline 21) + XOR'd ds_read.
// Bijective XCD swizzle (nwg%8==0 for all our grids) for L2 panel locality.
template<int BN>
__global__ __launch_bounds__(256)
void hgemm2(const u16* __restrict__ Ah, const u16* __restrict__ Am,
            const u16* __restrict__ Bh, const u16* __restrict__ Bm,
            int M, int N, int K, const float* __restrict__ bias, int relu,
            float* __restrict__ Cf, u16* __restrict__ Ch, u16* __restrict__ Cm) {
    constexpr int BP = BN * 32;            // u16 per B plane
    constexpr int SB = 4096 + 2 * BP;      // u16 per LDS buffer
    constexpr int NI = 2 + 2 * (BN / 64);  // staging issues per k-step: 6 or 4
    constexpr int NF = BN / 32;            // B frags per wave: 4 or 2
    constexpr int PP = BN / 64;            // issues per B plane: 2 or 1
    __shared__ u16 smem[2][SB];
    const int tid = threadIdx.x;

    int bx = blockIdx.x, by = blockIdx.y;
    {
        int gx = gridDim.x;
        int nwg = gx * gridDim.y;
        if (!(nwg & 7)) {               // XCD-aware swizzle (bijective, nwg%8==0)
            int bid = by * gx + bx;
            int cpx = nwg >> 3;
            int s = (bid & 7) * cpx + (bid >> 3);
            bx = s % gx; by = s / gx;
        }
    }
    const int m0 = by * 64, n0 = bx * BN;
    const int w = tid >> 6, lane = tid & 63;
    const int wm = w & 1, wn = w >> 1;
    const int l15 = lane & 15, l4 = lane >> 4;

    // staging map: i0=Ah, i1=Am, then B planes (PP issues each)
    const u16* srcp[NI];
    int dsto[NI];
    #pragma unroll
    for (int i = 0; i < NI; i++) {
        const u16* bp; int row, r, c;
        if (i < 2) {                       // A planes: 64 rows x 4 chunks = 256
            int qq = tid;
            r = qq >> 2;
            c = (qq & 3) ^ ((r ^ (r >> 2)) & 3);   // inverse swizzle on source
            bp = (i == 0) ? Ah : Am;
            row = m0 + r; row = row < M ? row : M - 1;
            dsto[i] = i * 2048 + w * 512;
        } else {                           // B planes: BN rows x 4 chunks
            int ii = i - 2;
            int plane = ii / PP;           // 0:Bh 1:Bm
            int sub = ii % PP;
            int qq = sub * 256 + tid;
            r = qq >> 2;
            c = (qq & 3) ^ ((r ^ (r >> 2)) & 3);
            bp = plane ? Bm : Bh;
            row = n0 + r;
            dsto[i] = 4096 + plane * BP + sub * 2048 + w * 512;
        }
        srcp[i] = bp + (size_t)row * K + c * 8;
    }

    f4 acc[2][NF];
    #pragma unroll
    for (int i = 0; i < 2; i++)
        #pragma unroll
        for (int j = 0; j < NF; j++) acc[i][j] = (f4){0.f, 0.f, 0.f, 0.f};

    // swizzled k-chunk slot for fragment reads: l4 ^ swz(row), row in-tile
    // row&3 = l15&3, (row>>2)&3 = (l15>>2)&3 (tile row base multiple of 16)
    const int cx8 = (l4 ^ (l15 & 3) ^ ((l15 >> 2) & 3)) * 8;

    // prologue: stage tile 0 into buf0, full drain once
    #pragma unroll
    for (int i = 0; i < NI; i++) async16(srcp[i], &smem[0][dsto[i]]);
    __syncthreads();

    u16* cur = &smem[0][0];
    u16* nxt = &smem[1][0];

    for (int k0 = 0; k0 < K; k0 += 32) {
        if (k0 + 32 < K) {
            #pragma unroll
            for (int i = 0; i < NI; i++) async16(srcp[i] + k0 + 32, nxt + dsto[i]);
            if constexpr (BN == 128)
                asm volatile("s_waitcnt vmcnt(6)" ::: "memory");
            else
                asm volatile("s_waitcnt vmcnt(4)" ::: "memory");
        } else {
            asm volatile("s_waitcnt vmcnt(0)" ::: "memory");
        }
        __builtin_amdgcn_s_barrier();        // all threads' cur loads landed
        bs8 ah[2], am[2], bh[NF], bm[NF];
        #pragma unroll
        for (int f = 0; f < 2; f++) {
            int oa = (wm * 32 + f * 16 + l15) * 32 + cx8;
            ah[f] = *(const bs8*)(cur + oa);
            am[f] = *(const bs8*)(cur + 2048 + oa);
        }
        #pragma unroll
        for (int f = 0; f < NF; f++) {
            int ob = (wn * (NF * 16) + f * 16 + l15) * 32 + cx8;
            bh[f] = *(const bs8*)(cur + 4096 + ob);
            bm[f] = *(const bs8*)(cur + 4096 + BP + ob);
        }
        #pragma unroll
        for (int mf = 0; mf < 2; mf++)
            #pragma unroll
            for (int nf = 0; nf < NF; nf++) {
                acc[mf][nf] = __builtin_amdgcn_mfma_f32_16x16x32_bf16(am[mf], bh[nf], acc[mf][nf], 0, 0, 0);
                acc[mf][nf] = __builtin_amdgcn_mfma_f32_16x16x32_bf16(ah[mf], bm[nf], acc[mf][nf], 0, 0, 0);
                acc[mf][nf] = __builtin_amdgcn_mfma_f32_16x16x32_bf16(ah[mf], bh[nf], acc[mf][nf], 0, 0, 0);
            }
        asm volatile("" ::: "memory");       // keep LDS reads/issues ordered vs barrier
        __builtin_amdgcn_s_barrier();        // all done reading cur (no vmcnt drain!)
        u16* t_ = cur; cur = nxt; nxt = t_;
    }

    #pragma unroll
    for (int mf = 0; mf < 2; mf++)
        #pragma unroll
        for (int i = 0; i < 4; i++) {
            int grow = m0 + wm * 32 + mf * 16 + l4 * 4 + i;
            if (grow < M) {
                #pragma unroll
                for (int nf = 0; nf < NF; nf++) {
                    int col = n0 + wn * (NF * 16) + nf * 16 + l15;
                    float v = acc[mf][nf][i] + (bias ? bias[col] : 0.f);
                    if (relu) v = fmaxf(v, 0.f);
                    if (Cf) Cf[(size_t)grow * N + col] = v;
                    else {
                        u16 h, m; split2b(v, h, m);
                        Ch[(size_t)grow * N + col] = h;
                        Cm[(size_t)grow * N + col] = m;
                    }
                }
            }
        }
}

// ---------------- thin fp32 row-GEMV ----------------
__global__ __launch_bounds__(128) void rowgemm_kernel(const float* __restrict__ A,
        const float* __restrict__ W, const float* __restrict__ bias,
        float* __restrict__ C, int N, int K, int relu,
        const float* __restrict__ resid, const float* __restrict__ resb) {
    __shared__ float sA[1024];
    int r = blockIdx.x;
    int c = blockIdx.y * 128 + threadIdx.x;
    for (int i = threadIdx.x; i < K; i += 128) sA[i] = A[(size_t)r * K + i];
    __syncthreads();
    float a0 = 0.f, a1 = 0.f, a2 = 0.f, a3 = 0.f;
    #pragma unroll 4
    for (int k = 0; k < K; k += 4) {
        a0 += sA[k]     * W[(size_t)k * N + c];
        a1 += sA[k + 1] * W[(size_t)(k + 1) * N + c];
        a2 += sA[k + 2] * W[(size_t)(k + 2) * N + c];
        a3 += sA[k + 3] * W[(size_t)(k + 3) * N + c];
    }
    float v = (a0 + a1) + (a2 + a3) + (bias ? bias[c] : 0.f);
    if (relu) v = fmaxf(v, 0.f);
    if (resid) v += resid[(size_t)r * N + c] + resb[c];
    C[(size_t)r * N + c] = v;
}

// gi/gh pair in one launch via blockIdx.z; z==0 rows scaled by sc0[r] (1/m0 fold)
__global__ __launch_bounds__(128) void rowgemmG_kernel(
        const float* __restrict__ A0, const float* __restrict__ W0,
        const float* __restrict__ b0, float* __restrict__ C0,
        const float* __restrict__ A1, const float* __restrict__ W1,
        const float* __restrict__ b1, float* __restrict__ C1,
        const float* __restrict__ sc0, int N, int K) {
    __shared__ float sA[256];
    const float* A = blockIdx.z ? A1 : A0;
    const float* W = blockIdx.z ? W1 : W0;
    const float* B = blockIdx.z ? b1 : b0;
    float* C = blockIdx.z ? C1 : C0;
    int r = blockIdx.x;
    int c = blockIdx.y * 128 + threadIdx.x;
    float scl = blockIdx.z ? 1.f : sc0[r];
    for (int i = threadIdx.x; i < K; i += 128) sA[i] = A[(size_t)r * K + i] * scl;
    __syncthreads();
    float a0 = 0.f, a1 = 0.f, a2 = 0.f, a3 = 0.f;
    #pragma unroll 4
    for (int k = 0; k < K; k += 4) {
        a0 += sA[k]     * W[(size_t)k * N + c];
        a1 += sA[k + 1] * W[(size_t)(k + 1) * N + c];
        a2 += sA[k + 2] * W[(size_t)(k + 2) * N + c];
        a3 += sA[k + 3] * W[(size_t)(k + 3) * N + c];
    }
    C[(size_t)r * N + c] = (a0 + a1) + (a2 + a3) + B[c];
}

// ---------------- small kernels ----------------
__global__ __launch_bounds__(256) void init_kernel(const float* __restrict__ slots_init_p,
        const float* __restrict__ S_s0, const float* __restrict__ S_p0,
        float* __restrict__ slots, float* __restrict__ S_s, float* __restrict__ S_p) {
    int bs = blockIdx.x, t = threadIdx.x;
    int s = bs % CS;
    slots[bs * CD + t] = slots_init_p[s * CD + t];
    if (t < 2) { S_s[bs * 2 + t] = S_s0[s * 2 + t]; S_p[bs * 2 + t] = S_p0[s * 2 + t]; }
}

// LN(slots) + qb0 + qw = sn @ Pq (fused GEMV)
__global__ __launch_bounds__(256) void ln_slots_q_kernel(const float* __restrict__ slots,
        const float* __restrict__ ln_g, const float* __restrict__ ln_b,
        const float* __restrict__ wqb, const float* __restrict__ Pq,
        float* __restrict__ qwb, float* __restrict__ qb0) {
    __shared__ float sbuf[8];
    __shared__ float sN[CD];
    int row = blockIdx.x, t = threadIdx.x;
    float x = slots[row * CD + t];
    float mean = block_reduce_sum(x, sbuf) / CD;
    float d0 = x - mean;
    float var = block_reduce_sum(d0 * d0, sbuf) / CD;
    float sn = d0 * rsqrtf(var + LNEPS) * ln_g[t] + ln_b[t];
    sN[t] = sn;
    float qb = block_reduce_sum(sn * wqb[t], sbuf);
    if (t == 0) qb0[row] = qb;
    __syncthreads();
    float acc = 0.f;
    #pragma unroll 4
    for (int k = 0; k < CD; k++) acc += sN[k] * Pq[(size_t)k * CD + t];
    qwb[row * CD + t] = acc;
}

// dots + softmax-over-slots + (optional) vsum fused. Grid (CB, 86): 16 n per block.
__global__ __launch_bounds__(256) void dotsv_kernel(const float* __restrict__ KVX,
        const float* __restrict__ S_p, const float* __restrict__ S_s,
        const float* __restrict__ G2, const float* __restrict__ gb1,
        const float* __restrict__ qw, const float* __restrict__ qb0,
        float* __restrict__ attn, float* __restrict__ Wacc) {
    __shared__ float sred[4 * CD];
    int b = blockIdx.x;
    int w = threadIdx.x >> 6, l = threadIdx.x & 63;
    int k4 = l * 4;
    float4 g0 = *(const float4*)(G2 + k4);
    float4 g1 = *(const float4*)(G2 + CD + k4);
    float4 gb = *(const float4*)(gb1 + k4);
    float4 qwv[CS]; float px[CS], py[CS], ix[CS], iy[CS], q0[CS];
    #pragma unroll
    for (int s = 0; s < CS; s++) {
        int bs = b * CS + s;
        qwv[s] = *(const float4*)(qw + bs * CD + k4);
        px[s] = S_p[2 * bs]; py[s] = S_p[2 * bs + 1];
        ix[s] = 1.f / (S_s[2 * bs] * CSIGMA); iy[s] = 1.f / (S_s[2 * bs + 1] * CSIGMA);
        q0[s] = qb0[bs];
    }
    float4 acc[CS];
    #pragma unroll
    for (int s = 0; s < CS; s++) acc[s] = make_float4(0.f, 0.f, 0.f, 0.f);
    int nbase = blockIdx.y * 16 + w * 4;
    #pragma unroll
    for (int i = 0; i < 4; i++) {
        int n = nbase + i;
        int nc = n < CN ? n : CN - 1;
        const float* rowp = KVX + (size_t)(b * CN + nc) * CKV;
        float4 kx = *(const float4*)(rowp + k4);
        float ax = ag_x(nc), ay = ag_y(nc);
        float dsv[CS];
        #pragma unroll
        for (int s = 0; s < CS; s++) {
            float r0 = (ax - px[s]) * ix[s];
            float r1 = (ay - py[s]) * iy[s];
            float v0 = fmaxf(kx.x + r0 * g0.x + r1 * g1.x + gb.x, 0.f);
            float v1 = fmaxf(kx.y + r0 * g0.y + r1 * g1.y + gb.y, 0.f);
            float v2 = fmaxf(kx.z + r0 * g0.z + r1 * g1.z + gb.z, 0.f);
            float v3 = fmaxf(kx.w + r0 * g0.w + r1 * g1.w + gb.w, 0.f);
            float d = v0 * qwv[s].x + v1 * qwv[s].y + v2 * qwv[s].z + v3 * qwv[s].w;
            #pragma unroll
            for (int off = 32; off > 0; off >>= 1) d += __shfl_xor(d, off, 64);
            dsv[s] = 0.0625f * (d + q0[s]);
        }
        float mx = -1e30f;
        #pragma unroll
        for (int s = 0; s < CS; s++) mx = fmaxf(mx, dsv[s]);
        float sum = 0.f;
        #pragma unroll
        for (int s = 0; s < CS; s++) { dsv[s] = __expf(dsv[s] - mx); sum += dsv[s]; }
        float inv = 1.f / sum;
        #pragma unroll
        for (int s = 0; s < CS; s++) dsv[s] = dsv[s] * inv + ATTN_EPS;
        if (l == 0 && n < CN) {
            #pragma unroll
            for (int s = 0; s < CS; s++)
                attn[(size_t)(b * CS + s) * CN + n] = dsv[s];
        }
        if (Wacc && n < CN) {
            float4 vx = *(const float4*)(rowp + CD + k4);
            #pragma unroll
            for (int s = 0; s < CS; s++) {
                float r0 = (ax - px[s]) * ix[s];
                float r1 = (ay - py[s]) * iy[s];
                float a = dsv[s];
                acc[s].x += a * fmaxf(vx.x + r0 * g0.x + r1 * g1.x + gb.x, 0.f);
                acc[s].y += a * fmaxf(vx.y + r0 * g0.y + r1 * g1.y + gb.y, 0.f);
                acc[s].z += a * fmaxf(vx.z + r0 * g0.z + r1 * g1.z + gb.z, 0.f);
                acc[s].w += a * fmaxf(vx.w + r0 * g0.w + r1 * g1.w + gb.w, 0.f);
            }
        }
    }
    if (Wacc) {
        for (int s = 0; s < CS; s++) {
            ((float4*)sred)[w * 64 + l] = acc[s];
            __syncthreads();
            if (threadIdx.x < CD) {
                float v = sred[threadIdx.x] + sred[CD + threadIdx.x]
                        + sred[2 * CD + threadIdx.x] + sred[3 * CD + threadIdx.x];
                atomicAdd(&Wacc[(size_t)(b * CS + s) * CD + threadIdx.x], v);
            }
            __syncthreads();
        }
    }
}

// moments; normalized-attn writeback only when writeNorm (final iter)
__global__ __launch_bounds__(256) void attn_moments_kernel(float* __restrict__ u,
        float* __restrict__ S_p, float* __restrict__ S_s, float* __restrict__ inv0,
        int writeNorm) {
    __shared__ float sbuf[8];
    int bs = blockIdx.x;
    float* up = u + (size_t)bs * CN;
    float m0 = 0, m1x = 0, m1y = 0, m2x = 0, m2y = 0;
    for (int n = threadIdx.x; n < CN; n += 256) {
        float uu = up[n];
        float ax = ag_x(n), ay = ag_y(n);
        m0 += uu; m1x += uu * ax; m1y += uu * ay; m2x += uu * ax * ax; m2y += uu * ay * ay;
    }
    m0  = block_reduce_sum(m0, sbuf);
    m1x = block_reduce_sum(m1x, sbuf);
    m1y = block_reduce_sum(m1y, sbuf);
    m2x = block_reduce_sum(m2x, sbuf);
    m2y = block_reduce_sum(m2y, sbuf);
    float px = m1x / m0, py = m1y / m0;
    float inv = 1.f / m0;
    if (threadIdx.x == 0) {
        S_p[2 * bs] = px; S_p[2 * bs + 1] = py;
        S_s[2 * bs]     = sqrtf(fmaxf(m2x / m0 - px * px, 0.f));
        S_s[2 * bs + 1] = sqrtf(fmaxf(m2y / m0 - py * py, 0.f));
        inv0[bs] = inv;
    }
    if (writeNorm)
        for (int n = threadIdx.x; n < CN; n += 256) up[n] = up[n] * inv;
}

// gates + LN (biases already folded into giRaw/ghRaw)
__global__ __launch_bounds__(256) void gate_ln_kernel(const float* __restrict__ giRaw,
        const float* __restrict__ ghRaw, const float* __restrict__ slots,
        const float* __restrict__ mg, const float* __restrict__ mb,
        float* __restrict__ snewb, float* __restrict__ sMb) {
    __shared__ float sbuf[8];
    int row = blockIdx.x, t = threadIdx.x;
    float gi0 = giRaw[row * 3 * CD + t];
    float gi1 = giRaw[row * 3 * CD + CD + t];
    float gi2 = giRaw[row * 3 * CD + 2 * CD + t];
    float gh0 = ghRaw[row * 3 * CD + t];
    float gh1 = ghRaw[row * 3 * CD + CD + t];
    float gh2 = ghRaw[row * 3 * CD + 2 * CD + t];
    float r = 1.f / (1.f + expf(-(gi0 + gh0)));
    float z = 1.f / (1.f + expf(-(gi1 + gh1)));
    float nn = tanhf(gi2 + r * gh2);
    float snew = (1.f - z) * nn + z * slots[row * CD + t];
    snewb[row * CD + t] = snew;
    float mean = block_reduce_sum(snew, sbuf) / CD;
    float dv = snew - mean;
    float var = block_reduce_sum(dv * dv, sbuf) / CD;
    sMb[row * CD + t] = dv * rsqrtf(var + LNEPS) * mg[t] + mb[t];
}

// ---------------- launcher ----------------
extern "C" void kernel_launch(void* const* d_in, const int* in_sizes, int n_in,
                              void* d_out, int out_size, void* d_ws, size_t ws_size,
                              hipStream_t stream) {
    (void)in_sizes; (void)n_in; (void)out_size;
    const float* inputs       = (const float*)d_in[0];
    const float* slots_init_p = (const float*)d_in[1];
    const float* S_s0         = (const float*)d_in[2];
    const float* S_p0         = (const float*)d_in[3];
    const float* im_ln1_g = (const float*)d_in[4];
    const float* im_ln1_b = (const float*)d_in[5];
    const float* im_w1    = (const float*)d_in[6];
    const float* im_b1    = (const float*)d_in[7];
    const float* im_w2    = (const float*)d_in[8];
    const float* im_b2    = (const float*)d_in[9];
    const float* im_ln2_g = (const float*)d_in[10];
    const float* im_ln2_b = (const float*)d_in[11];
    const float* Wq  = (const float*)d_in[12];
    const float* Wk  = (const float*)d_in[13];
    const float* Wv  = (const float*)d_in[14];
    const float* g_w = (const float*)d_in[15];
    const float* g_b = (const float*)d_in[16];
    const float* f_w1 = (const float*)d_in[17];
    const float* f_b1 = (const float*)d_in[18];
    const float* f_w2 = (const float*)d_in[19];
    const float* f_b2 = (const float*)d_in[20];
    const float* ln_g = (const float*)d_in[21];
    const float* ln_b = (const float*)d_in[22];
    const float* gru_wih = (const float*)d_in[23];
    const float* gru_whh = (const float*)d_in[24];
    const float* gru_bih = (const float*)d_in[25];
    const float* gru_bhh = (const float*)d_in[26];
    const float* mlp_ln_g = (const float*)d_in[27];
    const float* mlp_ln_b = (const float*)d_in[28];
    const float* mlp_w1 = (const float*)d_in[29];
    const float* mlp_b1 = (const float*)d_in[30];
    const float* mlp_w2 = (const float*)d_in[31];
    const float* mlp_b2 = (const float*)d_in[32];
    const float* fin_w = (const float*)d_in[33];
    const float* fin_b = (const float*)d_in[34];

    char* base = (char*)d_ws;
    size_t off = 0;
    auto take = [&](size_t bytes) { void* p = base + off; off += (bytes + 255) & ~(size_t)255; return p; };

    float* R1 = (float*)take((size_t)CBN * CDIN * 4);  // xln planes -> xD | xDn planes
    float* R2 = (float*)take((size_t)CBN * CDIN * 4);  // X1 planes -> KVX
    u16* w1th = (u16*)take((size_t)CDIN * CDIN * 2);
    u16* w1tm = (u16*)take((size_t)CDIN * CDIN * 2);
    u16* w2th = (u16*)take((size_t)CDIN * CD * 2);
    u16* w2tm = (u16*)take((size_t)CDIN * CD * 2);
    u16* kvth = (u16*)take((size_t)CKV * CD * 2);      // [512][256]: PkT | PvT
    u16* kvtm = (u16*)take((size_t)CKV * CD * 2);
    float* G2b  = (float*)take((size_t)2 * CD * 4);
    float* gb1b = (float*)take((size_t)CD * 4);
    float* Pq   = (float*)take((size_t)CD * CD * 4);
    float* Pg   = (float*)take((size_t)CD * 3 * CD * 4);
    float* bgv  = (float*)take((size_t)3 * CD * 4);
    float* wqbb = (float*)take((size_t)CD * 4);
    float* qwb   = (float*)take((size_t)CBS * CD * 4);
    float* qb0b  = (float*)take((size_t)CBS * 4);
    float* inv0b = (float*)take((size_t)CBS * 4);
    float* Wacc  = (float*)take((size_t)CBS * CD * 4);
    float* giRaw = (float*)take((size_t)CBS * 3 * CD * 4);
    float* ghRaw = (float*)take((size_t)CBS * 3 * CD * 4);
    float* snewb = (float*)take((size_t)CBS * CD * 4);
    float* sMb   = (float*)take((size_t)CBS * CD * 4);
    float* h1b   = (float*)take((size_t)CBS * 4 * CD * 4);
    float* S_pA  = (float*)take((size_t)CBS * 2 * 4);
    float* S_sA  = (float*)take((size_t)CBS * 2 * 4);
    float* S_pB  = (float*)take((size_t)CBS * 2 * 4);
    float* S_sB  = (float*)take((size_t)CBS * 2 * 4);
    float* slots = (float*)take((size_t)CBS * CD * 4);
    if (ws_size < off) return;

    // plane/buffer aliasing (lifetimes disjoint):
    u16* xlnh = (u16*)R1;                                  // [CBN][768] planes
    u16* xlnm = xlnh + (size_t)CBN * CDIN;
    u16* X1h  = (u16*)R2;                                  // [CBN][768] planes
    u16* X1m  = X1h + (size_t)CBN * CDIN;
    float* xD = R1;                                        // [CBN][256] fp32 (xln dead)
    u16* xDnh = (u16*)(R1 + (size_t)CBN * CD);             // [CBN][256] planes
    u16* xDnm = xDnh + (size_t)CBN * CD;
    float* KVX = R2;                                       // [CBN][512] fp32 (X1 dead)

    float* out0 = (float*)d_out;            // [CBS,CD]
    float* attnb = out0 + CBS * CD;         // [CBS,CN]

    dim3 blk(256);
    const int gM = (CBN + 63) / 64;         // 172 M-tiles (BM=64)
    dim3 gridBN(CB, 86);                    // 8 x 86 (16 n per block)

    // ---- weight prep ----
    transpose_split2_kernel<<<dim3(CDIN/32, CDIN/32), blk, 0, stream>>>(im_w1, w1th, w1tm, CDIN, CDIN);
    transpose_split2_kernel<<<dim3(CD/32,   CDIN/32), blk, 0, stream>>>(im_w2, w2th, w2tm, CDIN, CD);
    wprodT_kernel<<<dim3(CD), blk, 0, stream>>>(Wk, f_w1, kvth, kvtm);
    wprodT_kernel<<<dim3(CD), blk, 0, stream>>>(Wv, f_w1,
        kvth + (size_t)CD * CD, kvtm + (size_t)CD * CD);
    g2_kernel<<<1, blk, 0, stream>>>(g_w, g_b, f_w1, f_b1, G2b, gb1b);
    wprodPq_kernel<<<dim3(CD), blk, 0, stream>>>(Wq, f_w2, Pq);
    wprodN_kernel<<<dim3(CD, 3), blk, 0, stream>>>(f_w2, gru_wih, Pg, 3 * CD);
    bg_kernel<<<3, blk, 0, stream>>>(f_b2, gru_wih, gru_bih, bgv, 3 * CD);
    wqb_kernel<<<1, blk, 0, stream>>>(Wq, f_b2, wqbb);

    // ---- initial mlp (planes end-to-end) ----
    ln_planes_kernel<<<CBN, blk, 0, stream>>>(inputs, xlnh, xlnm, im_ln1_g, im_ln1_b, CDIN);
    hgemm2<128><<<dim3(CDIN/128, gM), blk, 0, stream>>>(xlnh, xlnm, w1th, w1tm,
        CBN, CDIN, CDIN, im_b1, 1, nullptr, X1h, X1m);
    hgemm2<64><<<dim3(CD/64, gM), blk, 0, stream>>>(X1h, X1m, w2th, w2tm,
        CBN, CD, CDIN, im_b2, 0, xD, nullptr, nullptr);
    ln_planes_kernel<<<CBN, blk, 0, stream>>>(xD, xDnh, xDnm, im_ln2_g, im_ln2_b, CD);
    hgemm2<64><<<dim3(CKV/64, gM), blk, 0, stream>>>(xDnh, xDnm, kvth, kvtm,
        CBN, CKV, CD, nullptr, 0, KVX, nullptr, nullptr);
    init_kernel<<<CBS, blk, 0, stream>>>(slots_init_p, S_s0, S_p0, slots, S_sA, S_pA);

    for (int t = 0; t <= CITERS; t++) {
        float* Sp_cur = (t & 1) ? S_pB : S_pA;
        float* Ss_cur = (t & 1) ? S_sB : S_sA;
        float* Sp_nxt = (t & 1) ? S_pA : S_pB;
        float* Ss_nxt = (t & 1) ? S_sA : S_sB;
        ln_slots_q_kernel<<<CBS, blk, 0, stream>>>(slots, ln_g, ln_b, wqbb, Pq, qwb, qb0b);
        if (t < CITERS) {
            hipMemsetAsync(Wacc, 0, (size_t)CBS * CD * sizeof(float), stream);
            dotsv_kernel<<<gridBN, blk, 0, stream>>>(KVX, Sp_cur, Ss_cur, G2b, gb1b,
                qwb, qb0b, attnb, Wacc);
        } else {
            dotsv_kernel<<<gridBN, blk, 0, stream>>>(KVX, Sp_cur, Ss_cur, G2b, gb1b,
                qwb, qb0b, attnb, nullptr);
        }
        attn_moments_kernel<<<CBS, blk, 0, stream>>>(attnb, Sp_nxt, Ss_nxt, inv0b,
            t == CITERS ? 1 : 0);
        if (t < CITERS) {
            rowgemmG_kernel<<<dim3(CBS, 3*CD/128, 2), dim3(128), 0, stream>>>(
                Wacc, Pg, bgv, giRaw, slots, gru_whh, gru_bhh, ghRaw, inv0b, 3 * CD, CD);
            gate_ln_kernel<<<CBS, blk, 0, stream>>>(giRaw, ghRaw, slots,
                mlp_ln_g, mlp_ln_b, snewb, sMb);
            rowgemm_kernel<<<dim3(CBS, 4*CD/128), dim3(128), 0, stream>>>(sMb, mlp_w1, mlp_b1,
                h1b, 4 * CD, CD, 1, nullptr, nullptr);
            rowgemm_kernel<<<dim3(CBS, CD/128), dim3(128), 0, stream>>>(h1b, mlp_w2, nullptr,
                slots, CD, 4 * CD, 0, snewb, mlp_b2);
        }
    }
    // out0 = slots @ fin_w + fin_b
    rowgemm_kernel<<<dim3(CBS, CD/128), dim3(128), 0, stream>>>(slots, fin_w, fin_b,
        out0, CD, CD, 0, nullptr, nullptr);
}

// Round 7
// 661.433 us; speedup vs baseline: 1.5549x; 1.0056x over previous
//
#include <hip/hip_runtime.h>

// ---------------- problem constants ----------------
constexpr int CB   = 8;      // batch
constexpr int CN   = 1369;   // tokens (37*37)
constexpr int CDIN = 768;
constexpr int CS   = 7;      // slots
constexpr int CD   = 256;
constexpr int CITERS = 3;
constexpr int CRES = 37;
constexpr float CSIGMA = 5.0f;
constexpr int CBS = CB * CS;        // 56
constexpr int CBN = CB * CN;        // 10952 rows for initial mlp
constexpr int CKV = 2 * CD;         // interleaved KX|VX row stride
constexpr float LNEPS = 1e-5f;
constexpr float ATTN_EPS = 1e-8f;

typedef unsigned short u16;
typedef short bs8 __attribute__((ext_vector_type(8)));   // 8 bf16 (bit pattern in shorts)
typedef float f4 __attribute__((ext_vector_type(4)));

// ---------------- helpers ----------------
__device__ __forceinline__ float ag_x(int n) { return -1.f + (float)(n % CRES) * (2.f / 36.f); }
__device__ __forceinline__ float ag_y(int n) { return -1.f + (float)(n / CRES) * (2.f / 36.f); }

__device__ __forceinline__ u16 bf_rne(float f) {
    unsigned u = __float_as_uint(f);
    return (u16)((u + 0x7FFFu + ((u >> 16) & 1u)) >> 16);
}
__device__ __forceinline__ float bf_to_f(u16 h) { return __uint_as_float(((unsigned)h) << 16); }

__device__ __forceinline__ void split2b(float v, u16& h, u16& m) {
    h = bf_rne(v);
    m = bf_rne(v - bf_to_f(h));
}

// async global->LDS, 16B per lane (dest = wave-uniform base + lane*16)
__device__ __forceinline__ void async16(const u16* g, u16* l) {
    __builtin_amdgcn_global_load_lds(
        (const __attribute__((address_space(1))) unsigned int*)g,
        (__attribute__((address_space(3))) unsigned int*)l, 16, 0, 0);
}

// 256-thread block sum
__device__ __forceinline__ float block_reduce_sum(float v, float* sbuf) {
    #pragma unroll
    for (int off = 32; off > 0; off >>= 1) v += __shfl_down(v, off, 64);
    if ((threadIdx.x & 63) == 0) sbuf[threadIdx.x >> 6] = v;
    __syncthreads();
    if (threadIdx.x == 0) sbuf[0] = sbuf[0] + sbuf[1] + sbuf[2] + sbuf[3];
    __syncthreads();
    float r = sbuf[0];
    __syncthreads();
    return r;
}

// ---------------- layernorm -> split-2 bf16 planes (single-pass, d in {256,768}) ----------------
__global__ __launch_bounds__(256) void ln_planes_kernel(const float* __restrict__ in,
        u16* __restrict__ Yh, u16* __restrict__ Ym,
        const float* __restrict__ g, const float* __restrict__ b, int d) {
    __shared__ float sbuf[8];
    int row = blockIdx.x, t = threadIdx.x;
    const float* x = in + (size_t)row * d;
    float v0 = x[t], v1 = 0.f, v2 = 0.f;
    if (d > 256) { v1 = x[t + 256]; v2 = x[t + 512]; }
    float mean = block_reduce_sum(v0 + v1 + v2, sbuf) / d;
    float d0 = v0 - mean, d1 = v1 - mean, d2 = v2 - mean;
    float pv = (d > 256) ? (d0 * d0 + d1 * d1 + d2 * d2) : (d0 * d0);
    float var = block_reduce_sum(pv, sbuf) / d;
    float rstd = rsqrtf(var + LNEPS);
    {
        float y = d0 * rstd * g[t] + b[t];
        u16 h, m; split2b(y, h, m);
        Yh[(size_t)row * d + t] = h; Ym[(size_t)row * d + t] = m;
    }
    if (d > 256) {
        float y1 = d1 * rstd * g[t + 256] + b[t + 256];
        u16 h, m; split2b(y1, h, m);
        Yh[(size_t)row * d + t + 256] = h; Ym[(size_t)row * d + t + 256] = m;
        float y2 = d2 * rstd * g[t + 512] + b[t + 512];
        split2b(y2, h, m);
        Yh[(size_t)row * d + t + 512] = h; Ym[(size_t)row * d + t + 512] = m;
    }
}

// ---------------- transpose fp32 W[K][N] -> 2 bf16 planes Wt[N][K] ----------------
__global__ __launch_bounds__(256) void transpose_split2_kernel(const float* __restrict__ W,
        u16* __restrict__ Th, u16* __restrict__ Tm, int K, int N) {
    __shared__ float tile[32][33];
    int nb = blockIdx.x * 32, kb = blockIdx.y * 32;
    int tx = threadIdx.x & 31, ty = threadIdx.x >> 5;   // ty 0..7
    #pragma unroll
    for (int i = 0; i < 32; i += 8)
        tile[ty + i][tx] = W[(size_t)(kb + ty + i) * N + nb + tx];
    __syncthreads();
    #pragma unroll
    for (int i = 0; i < 32; i += 8) {
        float v = tile[tx][ty + i];
        u16 h, m; split2b(v, h, m);
        size_t idx = (size_t)(nb + ty + i) * K + kb + tx;
        Th[idx] = h; Tm[idx] = m;
    }
}

// ---------------- PT planes: Th/Tm[n][k] = split2b( sum_j A[k][j]*B[j][n] ), all [256][256] ----------------
__global__ __launch_bounds__(256) void wprodT_kernel(const float* __restrict__ A,
        const float* __restrict__ B, u16* __restrict__ Th, u16* __restrict__ Tm) {
    __shared__ float arow[CD];
    int k = blockIdx.x;
    arow[threadIdx.x] = A[k * CD + threadIdx.x];
    __syncthreads();
    int n = threadIdx.x;
    float acc = 0.f;
    for (int j = 0; j < CD; j++) acc += arow[j] * B[(size_t)j * CD + n];
    u16 h, m; split2b(acc, h, m);
    Th[(size_t)n * CD + k] = h;
    Tm[(size_t)n * CD + k] = m;
}

// Pq[k][n] = sum_c Wq[k][c] * f_w2[n][c]
__global__ __launch_bounds__(256) void wprodPq_kernel(const float* __restrict__ Wq,
        const float* __restrict__ f_w2, float* __restrict__ Pq) {
    __shared__ float arow[CD];
    int k = blockIdx.x;
    arow[threadIdx.x] = Wq[k * CD + threadIdx.x];
    __syncthreads();
    int n = threadIdx.x;
    float acc = 0.f;
    for (int c = 0; c < CD; c++) acc += arow[c] * f_w2[(size_t)n * CD + c];
    Pq[(size_t)k * CD + n] = acc;
}

// ---------------- P[k][n] = sum_j A[k][j]*B[j][n], A [256][256], B [256][N] ----------------
__global__ __launch_bounds__(256) void wprodN_kernel(const float* __restrict__ A,
        const float* __restrict__ B, float* __restrict__ P, int N) {
    __shared__ float arow[CD];
    int k = blockIdx.x;
    arow[threadIdx.x] = A[k * CD + threadIdx.x];
    __syncthreads();
    int n = blockIdx.y * 256 + threadIdx.x;
    if (n >= N) return;
    float acc = 0.f;
    for (int j = 0; j < CD; j++) acc += arow[j] * B[(size_t)j * N + n];
    P[(size_t)k * N + n] = acc;
}

// fused small prep: bid 0 -> g2+gb1; bid 1..3 -> bg chunks; bid 4 -> wqb
// (per-thread code bit-identical to the previous separate kernels)
__global__ __launch_bounds__(256) void prep_small_kernel(
        const float* __restrict__ g_w, const float* __restrict__ g_b,
        const float* __restrict__ f_w1, const float* __restrict__ f_b1,
        float* __restrict__ G2, float* __restrict__ gb1,
        const float* __restrict__ f_b2, const float* __restrict__ wih,
        const float* __restrict__ bih, float* __restrict__ bg,
        const float* __restrict__ Wq, float* __restrict__ wqb) {
    int bid = blockIdx.x;
    if (bid == 0) {
        int n = threadIdx.x;
        float a0 = 0.f, a1 = 0.f, ab = 0.f;
        for (int j = 0; j < CD; j++) {
            float w = f_w1[j * CD + n];
            a0 += g_w[j] * w;
            a1 += g_w[CD + j] * w;
            ab += g_b[j] * w;
        }
        G2[n] = a0; G2[CD + n] = a1; gb1[n] = ab + f_b1[n];
    } else if (bid <= 3) {
        int n = (bid - 1) * 256 + threadIdx.x;
        float s = bih[n];
        for (int c = 0; c < CD; c++) s += f_b2[c] * wih[(size_t)c * (3 * CD) + n];
        bg[n] = s;
    } else {
        int j = threadIdx.x;
        float s = 0.f;
        for (int c = 0; c < CD; c++) s += Wq[j * CD + c] * f_b2[c];
        wqb[j] = s;
    }
}

// ---------------- bf16x3 plane GEMM, BM=64 x BN(template), depth-2 counted-vmcnt pipeline ----------------
// A planes Ah/Am [M][K], B planes Bh/Bm [N][K]; K%64==0, N%BN==0.
// 3 LDS buffers, depth-2 prefetch: at step k, stage step k+2 into buf[(k+2)%3],
// wait vmcnt(2*NI) (step k's loads done; 2 steps stay in flight), raw barrier,
// ds_read+MFMA from buf[k%3], raw barrier. Buffer k%3 is restaged at step k+1,
// strictly after the end-of-step-k barrier (all waves done reading). T3+T4.
// BN=64: 16KB/buf x3 = 48KB -> 3 blocks/CU cap and ~2 compute-steps of latency cover.
// LDS slot swizzle (2 lanes/bank on reads) via inverse-permuted global source.
// Bijective XCD swizzle (nwg%8==0 for all our grids) for L2 panel locality.
// NOTE: SQ_LDS_BANK_CONFLICT ~= 8 cyc per global_load_lds wave-issue is the
// structural LDS-write transfer time (1024B / 128B-per-cyc), not fixable.
template<int BN>
__global__ __launch_bounds__(256)
void hgemm2(const u16* __restrict__ Ah, const u16* __restrict__ Am,
            const u16* __restrict__ Bh, const u16* __restrict__ Bm,
            int M, int N, int K, const float* __restrict__ bias, int relu,
            float* __restrict__ Cf, u16* __restrict__ Ch, u16* __restrict__ Cm) {
    constexpr int BP = BN * 32;            // u16 per B plane
    constexpr int SB = 4096 + 2 * BP;      // u16 per LDS buffer
    constexpr int NI = 2 + 2 * (BN / 64);  // staging issues per k-step: 6 or 4
    constexpr int NF = BN / 32;            // B frags per wave: 4 or 2
    constexpr int PP = BN / 64;            // issues per B plane: 2 or 1
    __shared__ u16 smem[3][SB];
    const int tid = threadIdx.x;

    int bx = blockIdx.x, by = blockIdx.y;
    {
        int gx = gridDim.x;
        int nwg = gx * gridDim.y;
        if (!(nwg & 7)) {               // XCD-aware swizzle (bijective, nwg%8==0)
            int bid = by * gx + bx;
            int cpx = nwg >> 3;
            int s = (bid & 7) * cpx + (bid >> 3);
            bx = s % gx; by = s / gx;
        }
    }
    const int m0 = by * 64, n0 = bx * BN;
    const int w = tid >> 6, lane = tid & 63;
    const int wm = w & 1, wn = w >> 1;
    const int l15 = lane & 15, l4 = lane >> 4;

    // staging map: i0=Ah, i1=Am, then B planes (PP issues each)
    const u16* srcp[NI];
    int dsto[NI];
    #pragma unroll
    for (int i = 0; i < NI; i++) {
        const u16* bp; int row, r, c;
        if (i < 2) {                       // A planes: 64 rows x 4 chunks = 256
            int qq = tid;
            r = qq >> 2;
            c = (qq & 3) ^ ((r ^ (r >> 2)) & 3);   // inverse swizzle on source
            bp = (i == 0) ? Ah : Am;
            row = m0 + r; row = row < M ? row : M - 1;
            dsto[i] = i * 2048 + w * 512;
        } else {                           // B planes: BN rows x 4 chunks
            int ii = i - 2;
            int plane = ii / PP;           // 0:Bh 1:Bm
            int sub = ii % PP;
            int qq = sub * 256 + tid;
            r = qq >> 2;
            c = (qq & 3) ^ ((r ^ (r >> 2)) & 3);
            bp = plane ? Bm : Bh;
            row = n0 + r;
            dsto[i] = 4096 + plane * BP + sub * 2048 + w * 512;
        }
        srcp[i] = bp + (size_t)row * K + c * 8;
    }

    f4 acc[2][NF];
    #pragma unroll
    for (int i = 0; i < 2; i++)
        #pragma unroll
        for (int j = 0; j < NF; j++) acc[i][j] = (f4){0.f, 0.f, 0.f, 0.f};

    // swizzled k-chunk slot for fragment reads
    const int cx8 = (l4 ^ (l15 & 3) ^ ((l15 >> 2) & 3)) * 8;

    const int ns = K / 32;
    // prologue: stage steps 0 and 1
    #pragma unroll
    for (int i = 0; i < NI; i++) async16(srcp[i], &smem[0][dsto[i]]);
    #pragma unroll
    for (int i = 0; i < NI; i++) async16(srcp[i] + 32, &smem[1][dsto[i]]);

    u16* c0 = &smem[0][0];
    u16* c1 = &smem[1][0];
    u16* c2 = &smem[2][0];

    for (int k = 0; k < ns; k++) {
        if (k + 2 < ns) {
            #pragma unroll
            for (int i = 0; i < NI; i++) async16(srcp[i] + (k + 2) * 32, c2 + dsto[i]);
            if constexpr (BN == 128)
                asm volatile("s_waitcnt vmcnt(12)" ::: "memory");
            else
                asm volatile("s_waitcnt vmcnt(8)" ::: "memory");
        } else if (k + 1 < ns) {
            if constexpr (BN == 128)
                asm volatile("s_waitcnt vmcnt(6)" ::: "memory");
            else
                asm volatile("s_waitcnt vmcnt(4)" ::: "memory");
        } else {
            asm volatile("s_waitcnt vmcnt(0)" ::: "memory");
        }
        __builtin_amdgcn_s_barrier();        // all threads' step-k loads landed
        bs8 ah[2], am[2], bh[NF], bm[NF];
        #pragma unroll
        for (int f = 0; f < 2; f++) {
            int oa = (wm * 32 + f * 16 + l15) * 32 + cx8;
            ah[f] = *(const bs8*)(c0 + oa);
            am[f] = *(const bs8*)(c0 + 2048 + oa);
        }
        #pragma unroll
        for (int f = 0; f < NF; f++) {
            int ob = (wn * (NF * 16) + f * 16 + l15) * 32 + cx8;
            bh[f] = *(const bs8*)(c0 + 4096 + ob);
            bm[f] = *(const bs8*)(c0 + 4096 + BP + ob);
        }
        #pragma unroll
        for (int mf = 0; mf < 2; mf++)
            #pragma unroll
            for (int nf = 0; nf < NF; nf++) {
                acc[mf][nf] = __builtin_amdgcn_mfma_f32_16x16x32_bf16(am[mf], bh[nf], acc[mf][nf], 0, 0, 0);
                acc[mf][nf] = __builtin_amdgcn_mfma_f32_16x16x32_bf16(ah[mf], bm[nf], acc[mf][nf], 0, 0, 0);
                acc[mf][nf] = __builtin_amdgcn_mfma_f32_16x16x32_bf16(ah[mf], bh[nf], acc[mf][nf], 0, 0, 0);
            }
        asm volatile("" ::: "memory");       // keep LDS reads ordered vs barrier
        __builtin_amdgcn_s_barrier();        // all done reading c0 (no vmcnt drain!)
        u16* t_ = c0; c0 = c1; c1 = c2; c2 = t_;
    }

    #pragma unroll
    for (int mf = 0; mf < 2; mf++)
        #pragma unroll
        for (int i = 0; i < 4; i++) {
            int grow = m0 + wm * 32 + mf * 16 + l4 * 4 + i;
            if (grow < M) {
                #pragma unroll
                for (int nf = 0; nf < NF; nf++) {
                    int col = n0 + wn * (NF * 16) + nf * 16 + l15;
                    float v = acc[mf][nf][i] + (bias ? bias[col] : 0.f);
                    if (relu) v = fmaxf(v, 0.f);
                    if (Cf) Cf[(size_t)grow * N + col] = v;
                    else {
                        u16 h, m; split2b(v, h, m);
                        Ch[(size_t)grow * N + col] = h;
                        Cm[(size_t)grow * N + col] = m;
                    }
                }
            }
        }
}

// ---------------- thin fp32 row-GEMV ----------------
__global__ __launch_bounds__(128) void rowgemm_kernel(const float* __restrict__ A,
        const float* __restrict__ W, const float* __restrict__ bias,
        float* __restrict__ C, int N, int K, int relu,
        const float* __restrict__ resid, const float* __restrict__ resb) {
    __shared__ float sA[1024];
    int r = blockIdx.x;
    int c = blockIdx.y * 128 + threadIdx.x;
    for (int i = threadIdx.x; i < K; i += 128) sA[i] = A[(size_t)r * K + i];
    __syncthreads();
    float a0 = 0.f, a1 = 0.f, a2 = 0.f, a3 = 0.f;
    #pragma unroll 4
    for (int k = 0; k < K; k += 4) {
        a0 += sA[k]     * W[(size_t)k * N + c];
        a1 += sA[k + 1] * W[(size_t)(k + 1) * N + c];
        a2 += sA[k + 2] * W[(size_t)(k + 2) * N + c];
        a3 += sA[k + 3] * W[(size_t)(k + 3) * N + c];
    }
    float v = (a0 + a1) + (a2 + a3) + (bias ? bias[c] : 0.f);
    if (relu) v = fmaxf(v, 0.f);
    if (resid) v += resid[(size_t)r * N + c] + resb[c];
    C[(size_t)r * N + c] = v;
}

// gi/gh pair in one launch via blockIdx.z; z==0 rows scaled by sc0[r] (1/m0 fold)
__global__ __launch_bounds__(128) void rowgemmG_kernel(
        const float* __restrict__ A0, const float* __restrict__ W0,
        const float* __restrict__ b0, float* __restrict__ C0,
        const float* __restrict__ A1, const float* __restrict__ W1,
        const float* __restrict__ b1, float* __restrict__ C1,
        const float* __restrict__ sc0, int N, int K) {
    __shared__ float sA[256];
    const float* A = blockIdx.z ? A1 : A0;
    const float* W = blockIdx.z ? W1 : W0;
    const float* B = blockIdx.z ? b1 : b0;
    float* C = blockIdx.z ? C1 : C0;
    int r = blockIdx.x;
    int c = blockIdx.y * 128 + threadIdx.x;
    float scl = blockIdx.z ? 1.f : sc0[r];
    for (int i = threadIdx.x; i < K; i += 128) sA[i] = A[(size_t)r * K + i] * scl;
    __syncthreads();
    float a0 = 0.f, a1 = 0.f, a2 = 0.f, a3 = 0.f;
    #pragma unroll 4
    for (int k = 0; k < K; k += 4) {
        a0 += sA[k]     * W[(size_t)k * N + c];
        a1 += sA[k + 1] * W[(size_t)(k + 1) * N + c];
        a2 += sA[k + 2] * W[(size_t)(k + 2) * N + c];
        a3 += sA[k + 3] * W[(size_t)(k + 3) * N + c];
    }
    C[(size_t)r * N + c] = (a0 + a1) + (a2 + a3) + B[c];
}

// ---------------- small kernels ----------------
__global__ __launch_bounds__(256) void init_kernel(const float* __restrict__ slots_init_p,
        const float* __restrict__ S_s0, const float* __restrict__ S_p0,
        float* __restrict__ slots, float* __restrict__ S_s, float* __restrict__ S_p) {
    int bs = blockIdx.x, t = threadIdx.x;
    int s = bs % CS;
    slots[bs * CD + t] = slots_init_p[s * CD + t];
    if (t < 2) { S_s[bs * 2 + t] = S_s0[s * 2 + t]; S_p[bs * 2 + t] = S_p0[s * 2 + t]; }
}

// LN(slots) + qb0 + qw = sn @ Pq (fused GEMV)
__global__ __launch_bounds__(256) void ln_slots_q_kernel(const float* __restrict__ slots,
        const float* __restrict__ ln_g, const float* __restrict__ ln_b,
        const float* __restrict__ wqb, const float* __restrict__ Pq,
        float* __restrict__ qwb, float* __restrict__ qb0) {
    __shared__ float sbuf[8];
    __shared__ float sN[CD];
    int row = blockIdx.x, t = threadIdx.x;
    float x = slots[row * CD + t];
    float mean = block_reduce_sum(x, sbuf) / CD;
    float d0 = x - mean;
    float var = block_reduce_sum(d0 * d0, sbuf) / CD;
    float sn = d0 * rsqrtf(var + LNEPS) * ln_g[t] + ln_b[t];
    sN[t] = sn;
    float qb = block_reduce_sum(sn * wqb[t], sbuf);
    if (t == 0) qb0[row] = qb;
    __syncthreads();
    float acc = 0.f;
    #pragma unroll 4
    for (int k = 0; k < CD; k++) acc += sN[k] * Pq[(size_t)k * CD + t];
    qwb[row * CD + t] = acc;
}

// dots + softmax-over-slots + (optional) vsum fused. Grid (CB, 86): 16 n per block.
__global__ __launch_bounds__(256) void dotsv_kernel(const float* __restrict__ KVX,
        const float* __restrict__ S_p, const float* __restrict__ S_s,
        const float* __restrict__ G2, const float* __restrict__ gb1,
        const float* __restrict__ qw, const float* __restrict__ qb0,
        float* __restrict__ attn, float* __restrict__ Wacc) {
    __shared__ float sred[4 * CD];
    int b = blockIdx.x;
    int w = threadIdx.x >> 6, l = threadIdx.x & 63;
    int k4 = l * 4;
    float4 g0 = *(const float4*)(G2 + k4);
    float4 g1 = *(const float4*)(G2 + CD + k4);
    float4 gb = *(const float4*)(gb1 + k4);
    float4 qwv[CS]; float px[CS], py[CS], ix[CS], iy[CS], q0[CS];
    #pragma unroll
    for (int s = 0; s < CS; s++) {
        int bs = b * CS + s;
        qwv[s] = *(const float4*)(qw + bs * CD + k4);
        px[s] = S_p[2 * bs]; py[s] = S_p[2 * bs + 1];
        ix[s] = 1.f / (S_s[2 * bs] * CSIGMA); iy[s] = 1.f / (S_s[2 * bs + 1] * CSIGMA);
        q0[s] = qb0[bs];
    }
    float4 acc[CS];
    #pragma unroll
    for (int s = 0; s < CS; s++) acc[s] = make_float4(0.f, 0.f, 0.f, 0.f);
    int nbase = blockIdx.y * 16 + w * 4;
    #pragma unroll
    for (int i = 0; i < 4; i++) {
        int n = nbase + i;
        int nc = n < CN ? n : CN - 1;
        const float* rowp = KVX + (size_t)(b * CN + nc) * CKV;
        float4 kx = *(const float4*)(rowp + k4);
        float ax = ag_x(nc), ay = ag_y(nc);
        float dsv[CS];
        #pragma unroll
        for (int s = 0; s < CS; s++) {
            float r0 = (ax - px[s]) * ix[s];
            float r1 = (ay - py[s]) * iy[s];
            float v0 = fmaxf(kx.x + r0 * g0.x + r1 * g1.x + gb.x, 0.f);
            float v1 = fmaxf(kx.y + r0 * g0.y + r1 * g1.y + gb.y, 0.f);
            float v2 = fmaxf(kx.z + r0 * g0.z + r1 * g1.z + gb.z, 0.f);
            float v3 = fmaxf(kx.w + r0 * g0.w + r1 * g1.w + gb.w, 0.f);
            float d = v0 * qwv[s].x + v1 * qwv[s].y + v2 * qwv[s].z + v3 * qwv[s].w;
            #pragma unroll
            for (int off = 32; off > 0; off >>= 1) d += __shfl_xor(d, off, 64);
            dsv[s] = 0.0625f * (d + q0[s]);
        }
        float mx = -1e30f;
        #pragma unroll
        for (int s = 0; s < CS; s++) mx = fmaxf(mx, dsv[s]);
        float sum = 0.f;
        #pragma unroll
        for (int s = 0; s < CS; s++) { dsv[s] = __expf(dsv[s] - mx); sum += dsv[s]; }
        float inv = 1.f / sum;
        #pragma unroll
        for (int s = 0; s < CS; s++) dsv[s] = dsv[s] * inv + ATTN_EPS;
        if (l == 0 && n < CN) {
            #pragma unroll
            for (int s = 0; s < CS; s++)
                attn[(size_t)(b * CS + s) * CN + n] = dsv[s];
        }
        if (Wacc && n < CN) {
            float4 vx = *(const float4*)(rowp + CD + k4);
            #pragma unroll
            for (int s = 0; s < CS; s++) {
                float r0 = (ax - px[s]) * ix[s];
                float r1 = (ay - py[s]) * iy[s];
                float a = dsv[s];
                acc[s].x += a * fmaxf(vx.x + r0 * g0.x + r1 * g1.x + gb.x, 0.f);
                acc[s].y += a * fmaxf(vx.y + r0 * g0.y + r1 * g1.y + gb.y, 0.f);
                acc[s].z += a * fmaxf(vx.z + r0 * g0.z + r1 * g1.z + gb.z, 0.f);
                acc[s].w += a * fmaxf(vx.w + r0 * g0.w + r1 * g1.w + gb.w, 0.f);
            }
        }
    }
    if (Wacc) {
        for (int s = 0; s < CS; s++) {
            ((float4*)sred)[w * 64 + l] = acc[s];
            __syncthreads();
            if (threadIdx.x < CD) {
                float v = sred[threadIdx.x] + sred[CD + threadIdx.x]
                        + sred[2 * CD + threadIdx.x] + sred[3 * CD + threadIdx.x];
                atomicAdd(&Wacc[(size_t)(b * CS + s) * CD + threadIdx.x], v);
            }
            __syncthreads();
        }
    }
}

// moments; normalized-attn writeback only when writeNorm (final iter)
__global__ __launch_bounds__(256) void attn_moments_kernel(float* __restrict__ u,
        float* __restrict__ S_p, float* __restrict__ S_s, float* __restrict__ inv0,
        int writeNorm) {
    __shared__ float sbuf[8];
    int bs = blockIdx.x;
    float* up = u + (size_t)bs * CN;
    float m0 = 0, m1x = 0, m1y = 0, m2x = 0, m2y = 0;
    for (int n = threadIdx.x; n < CN; n += 256) {
        float uu = up[n];
        float ax = ag_x(n), ay = ag_y(n);
        m0 += uu; m1x += uu * ax; m1y += uu * ay; m2x += uu * ax * ax; m2y += uu * ay * ay;
    }
    m0  = block_reduce_sum(m0, sbuf);
    m1x = block_reduce_sum(m1x, sbuf);
    m1y = block_reduce_sum(m1y, sbuf);
    m2x = block_reduce_sum(m2x, sbuf);
    m2y = block_reduce_sum(m2y, sbuf);
    float px = m1x / m0, py = m1y / m0;
    float inv = 1.f / m0;
    if (threadIdx.x == 0) {
        S_p[2 * bs] = px; S_p[2 * bs + 1] = py;
        S_s[2 * bs]     = sqrtf(fmaxf(m2x / m0 - px * px, 0.f));
        S_s[2 * bs + 1] = sqrtf(fmaxf(m2y / m0 - py * py, 0.f));
        inv0[bs] = inv;
    }
    if (writeNorm)
        for (int n = threadIdx.x; n < CN; n += 256) up[n] = up[n] * inv;
}

// gates + LN (biases already folded into giRaw/ghRaw)
__global__ __launch_bounds__(256) void gate_ln_kernel(const float* __restrict__ giRaw,
        const float* __restrict__ ghRaw, const float* __restrict__ slots,
        const float* __restrict__ mg, const float* __restrict__ mb,
        float* __restrict__ snewb, float* __restrict__ sMb) {
    __shared__ float sbuf[8];
    int row = blockIdx.x, t = threadIdx.x;
    float gi0 = giRaw[row * 3 * CD + t];
    float gi1 = giRaw[row * 3 * CD + CD + t];
    float gi2 = giRaw[row * 3 * CD + 2 * CD + t];
    float gh0 = ghRaw[row * 3 * CD + t];
    float gh1 = ghRaw[row * 3 * CD + CD + t];
    float gh2 = ghRaw[row * 3 * CD + 2 * CD + t];
    float r = 1.f / (1.f + expf(-(gi0 + gh0)));
    float z = 1.f / (1.f + expf(-(gi1 + gh1)));
    float nn = tanhf(gi2 + r * gh2);
    float snew = (1.f - z) * nn + z * slots[row * CD + t];
    snewb[row * CD + t] = snew;
    float mean = block_reduce_sum(snew, sbuf) / CD;
    float dv = snew - mean;
    float var = block_reduce_sum(dv * dv, sbuf) / CD;
    sMb[row * CD + t] = dv * rsqrtf(var + LNEPS) * mg[t] + mb[t];
}

// ---------------- launcher ----------------
extern "C" void kernel_launch(void* const* d_in, const int* in_sizes, int n_in,
                              void* d_out, int out_size, void* d_ws, size_t ws_size,
                              hipStream_t stream) {
    (void)in_sizes; (void)n_in; (void)out_size;
    const float* inputs       = (const float*)d_in[0];
    const float* slots_init_p = (const float*)d_in[1];
    const float* S_s0         = (const float*)d_in[2];
    const float* S_p0         = (const float*)d_in[3];
    const float* im_ln1_g = (const float*)d_in[4];
    const float* im_ln1_b = (const float*)d_in[5];
    const float* im_w1    = (const float*)d_in[6];
    const float* im_b1    = (const float*)d_in[7];
    const float* im_w2    = (const float*)d_in[8];
    const float* im_b2    = (const float*)d_in[9];
    const float* im_ln2_g = (const float*)d_in[10];
    const float* im_ln2_b = (const float*)d_in[11];
    const float* Wq  = (const float*)d_in[12];
    const float* Wk  = (const float*)d_in[13];
    const float* Wv  = (const float*)d_in[14];
    const float* g_w = (const float*)d_in[15];
    const float* g_b = (const float*)d_in[16];
    const float* f_w1 = (const float*)d_in[17];
    const float* f_b1 = (const float*)d_in[18];
    const float* f_w2 = (const float*)d_in[19];
    const float* f_b2 = (const float*)d_in[20];
    const float* ln_g = (const float*)d_in[21];
    const float* ln_b = (const float*)d_in[22];
    const float* gru_wih = (const float*)d_in[23];
    const float* gru_whh = (const float*)d_in[24];
    const float* gru_bih = (const float*)d_in[25];
    const float* gru_bhh = (const float*)d_in[26];
    const float* mlp_ln_g = (const float*)d_in[27];
    const float* mlp_ln_b = (const float*)d_in[28];
    const float* mlp_w1 = (const float*)d_in[29];
    const float* mlp_b1 = (const float*)d_in[30];
    const float* mlp_w2 = (const float*)d_in[31];
    const float* mlp_b2 = (const float*)d_in[32];
    const float* fin_w = (const float*)d_in[33];
    const float* fin_b = (const float*)d_in[34];

    char* base = (char*)d_ws;
    size_t off = 0;
    auto take = [&](size_t bytes) { void* p = base + off; off += (bytes + 255) & ~(size_t)255; return p; };

    float* R1 = (float*)take((size_t)CBN * CDIN * 4);  // xln planes -> xD | xDn planes
    float* R2 = (float*)take((size_t)CBN * CDIN * 4);  // X1 planes -> KVX
    u16* w1th = (u16*)take((size_t)CDIN * CDIN * 2);
    u16* w1tm = (u16*)take((size_t)CDIN * CDIN * 2);
    u16* w2th = (u16*)take((size_t)CDIN * CD * 2);
    u16* w2tm = (u16*)take((size_t)CDIN * CD * 2);
    u16* kvth = (u16*)take((size_t)CKV * CD * 2);      // [512][256]: PkT | PvT
    u16* kvtm = (u16*)take((size_t)CKV * CD * 2);
    float* G2b  = (float*)take((size_t)2 * CD * 4);
    float* gb1b = (float*)take((size_t)CD * 4);
    float* Pq   = (float*)take((size_t)CD * CD * 4);
    float* Pg   = (float*)take((size_t)CD * 3 * CD * 4);
    float* bgv  = (float*)take((size_t)3 * CD * 4);
    float* wqbb = (float*)take((size_t)CD * 4);
    float* qwb   = (float*)take((size_t)CBS * CD * 4);
    float* qb0b  = (float*)take((size_t)CBS * 4);
    float* inv0b = (float*)take((size_t)CBS * 4);
    float* Wacc  = (float*)take((size_t)CBS * CD * 4);
    float* giRaw = (float*)take((size_t)CBS * 3 * CD * 4);
    float* ghRaw = (float*)take((size_t)CBS * 3 * CD * 4);
    float* snewb = (float*)take((size_t)CBS * CD * 4);
    float* sMb   = (float*)take((size_t)CBS * CD * 4);
    float* h1b   = (float*)take((size_t)CBS * 4 * CD * 4);
    float* S_pA  = (float*)take((size_t)CBS * 2 * 4);
    float* S_sA  = (float*)take((size_t)CBS * 2 * 4);
    float* S_pB  = (float*)take((size_t)CBS * 2 * 4);
    float* S_sB  = (float*)take((size_t)CBS * 2 * 4);
    float* slots = (float*)take((size_t)CBS * CD * 4);
    if (ws_size < off) return;

    // plane/buffer aliasing (lifetimes disjoint):
    u16* xlnh = (u16*)R1;                                  // [CBN][768] planes
    u16* xlnm = xlnh + (size_t)CBN * CDIN;
    u16* X1h  = (u16*)R2;                                  // [CBN][768] planes
    u16* X1m  = X1h + (size_t)CBN * CDIN;
    float* xD = R1;                                        // [CBN][256] fp32 (xln dead)
    u16* xDnh = (u16*)(R1 + (size_t)CBN * CD);             // [CBN][256] planes
    u16* xDnm = xDnh + (size_t)CBN * CD;
    float* KVX = R2;                                       // [CBN][512] fp32 (X1 dead)

    float* out0 = (float*)d_out;            // [CBS,CD]
    float* attnb = out0 + CBS * CD;         // [CBS,CN]

    dim3 blk(256);
    const int gM = (CBN + 63) / 64;         // 172 M-tiles (BM=64)
    dim3 gridBN(CB, 86);                    // 8 x 86 (16 n per block)

    // ---- weight prep ----
    transpose_split2_kernel<<<dim3(CDIN/32, CDIN/32), blk, 0, stream>>>(im_w1, w1th, w1tm, CDIN, CDIN);
    transpose_split2_kernel<<<dim3(CD/32,   CDIN/32), blk, 0, stream>>>(im_w2, w2th, w2tm, CDIN, CD);
    wprodT_kernel<<<dim3(CD), blk, 0, stream>>>(Wk, f_w1, kvth, kvtm);
    wprodT_kernel<<<dim3(CD), blk, 0, stream>>>(Wv, f_w1,
        kvth + (size_t)CD * CD, kvtm + (size_t)CD * CD);
    wprodPq_kernel<<<dim3(CD), blk, 0, stream>>>(Wq, f_w2, Pq);
    wprodN_kernel<<<dim3(CD, 3), blk, 0, stream>>>(f_w2, gru_wih, Pg, 3 * CD);
    prep_small_kernel<<<dim3(5), blk, 0, stream>>>(g_w, g_b, f_w1, f_b1, G2b, gb1b,
        f_b2, gru_wih, gru_bih, bgv, Wq, wqbb);

    // ---- initial mlp (planes end-to-end) ----
    ln_planes_kernel<<<CBN, blk, 0, stream>>>(inputs, xlnh, xlnm, im_ln1_g, im_ln1_b, CDIN);
    hgemm2<64><<<dim3(CDIN/64, gM), blk, 0, stream>>>(xlnh, xlnm, w1th, w1tm,
        CBN, CDIN, CDIN, im_b1, 1, nullptr, X1h, X1m);
    hgemm2<64><<<dim3(CD/64, gM), blk, 0, stream>>>(X1h, X1m, w2th, w2tm,
        CBN, CD, CDIN, im_b2, 0, xD, nullptr, nullptr);
    ln_planes_kernel<<<CBN, blk, 0, stream>>>(xD, xDnh, xDnm, im_ln2_g, im_ln2_b, CD);
    hgemm2<64><<<dim3(CKV/64, gM), blk, 0, stream>>>(xDnh, xDnm, kvth, kvtm,
        CBN, CKV, CD, nullptr, 0, KVX, nullptr, nullptr);
    init_kernel<<<CBS, blk, 0, stream>>>(slots_init_p, S_s0, S_p0, slots, S_sA, S_pA);

    for (int t = 0; t <= CITERS; t++) {
        float* Sp_cur = (t & 1) ? S_pB : S_pA;
        float* Ss_cur = (t & 1) ? S_sB : S_sA;
        float* Sp_nxt = (t & 1) ? S_pA : S_pB;
        float* Ss_nxt = (t & 1) ? S_sA : S_sB;
        ln_slots_q_kernel<<<CBS, blk, 0, stream>>>(slots, ln_g, ln_b, wqbb, Pq, qwb, qb0b);
        if (t < CITERS) {
            hipMemsetAsync(Wacc, 0, (size_t)CBS * CD * sizeof(float), stream);
            dotsv_kernel<<<gridBN, blk, 0, stream>>>(KVX, Sp_cur, Ss_cur, G2b, gb1b,
                qwb, qb0b, attnb, Wacc);
        } else {
            dotsv_kernel<<<gridBN, blk, 0, stream>>>(KVX, Sp_cur, Ss_cur, G2b, gb1b,
                qwb, qb0b, attnb, nullptr);
        }
        attn_moments_kernel<<<CBS, blk, 0, stream>>>(attnb, Sp_nxt, Ss_nxt, inv0b,
            t == CITERS ? 1 : 0);
        if (t < CITERS) {
            rowgemmG_kernel<<<dim3(CBS, 3*CD/128, 2), dim3(128), 0, stream>>>(
                Wacc, Pg, bgv, giRaw, slots, gru_whh, gru_bhh, ghRaw, inv0b, 3 * CD, CD);
            gate_ln_kernel<<<CBS, blk, 0, stream>>>(giRaw, ghRaw, slots,
                mlp_ln_g, mlp_ln_b, snewb, sMb);
            rowgemm_kernel<<<dim3(CBS, 4*CD/128), dim3(128), 0, stream>>>(sMb, mlp_w1, mlp_b1,
                h1b, 4 * CD, CD, 1, nullptr, nullptr);
            rowgemm_kernel<<<dim3(CBS, CD/128), dim3(128), 0, stream>>>(h1b, mlp_w2, nullptr,
                slots, CD, 4 * CD, 0, snewb, mlp_b2);
        }
    }
    // out0 = slots @ fin_w + fin_b
    rowgemm_kernel<<<dim3(CBS, CD/128), dim3(128), 0, stream>>>(slots, fin_w, fin_b,
        out0, CD, CD, 0, nullptr, nullptr);
}